// Round 4
// baseline (3035.735 us; speedup 1.0000x reference)
//
#include <hip/hip_runtime.h>
#include <hip/hip_bf16.h>
#include <stdint.h>

typedef __hip_bfloat16 bf16;

#define BATCH  8
#define NPG    4096
#define DIN    128
#define NH     4
#define NEDGE  262144
#define DOUTF  128
#define KORDER 4
#define NTOT   (BATCH*NPG)   // 32768
#define HD     (NH*DIN)      // 512

static __device__ __forceinline__ float b2f(bf16 v) { return __bfloat162float(v); }
static __device__ __forceinline__ float u2f(unsigned short u) {
    union { float f; unsigned int i; } c; c.i = ((unsigned int)u) << 16; return c.f;
}

// ---------------------------------------------------------------- zero
__global__ void zero_kernel(uint4* p, int n) {
    int i = blockIdx.x * 256 + threadIdx.x;
    if (i < n) p[i] = uint4{0u, 0u, 0u, 0u};
}

// ---------------------------------------------------------------- transpose (fp32)
__global__ void transpose_kernel(const float* in, float* out, int R, int C) {
    int i = blockIdx.x * 256 + threadIdx.x;
    if (i < R * C) {
        int r = i / C, c = i - r * C;
        out[c * R + r] = in[i];
    }
}

// ---------------------------------------------------------------- projection + per-head normalize
// out[n, j] = normalize_h( sum_k x[n,k] * WT[k, j] + bias[j] ), stored bf16
__global__ __launch_bounds__(512) void proj_norm_kernel(const float* __restrict__ x,
                                                        const float* __restrict__ WT,
                                                        const float* __restrict__ bias,
                                                        bf16* __restrict__ outp) {
    __shared__ float xs[8][DIN];
    __shared__ float tile[8][HD];
    __shared__ float rs[8][NH];
    int node0 = blockIdx.x * 8;
    int t = threadIdx.x;
    for (int i = t; i < 8 * DIN; i += 512) {
        int r = i >> 7, c = i & 127;
        xs[r][c] = x[(node0 + r) * DIN + c];
    }
    __syncthreads();
    float acc[8] = {0.f,0.f,0.f,0.f,0.f,0.f,0.f,0.f};
    #pragma unroll 4
    for (int k = 0; k < DIN; k += 4) {
        float w0 = WT[(k + 0) * HD + t];
        float w1 = WT[(k + 1) * HD + t];
        float w2 = WT[(k + 2) * HD + t];
        float w3 = WT[(k + 3) * HD + t];
        #pragma unroll
        for (int r = 0; r < 8; r++) {
            float4 xv = *(const float4*)&xs[r][k];
            acc[r] += xv.x * w0 + xv.y * w1 + xv.z * w2 + xv.w * w3;
        }
    }
    float bv = bias[t];
    #pragma unroll
    for (int r = 0; r < 8; r++) tile[r][t] = acc[r] + bv;
    __syncthreads();
    if (t < 32) {
        int r = t >> 2, h = t & 3;
        float s = 0.f;
        for (int dd = 0; dd < DIN; dd++) {
            int d = (dd + t) & 127;   // rotate to avoid bank conflicts
            float v = tile[r][h * DIN + d];
            s += v * v;
        }
        rs[r][h] = rsqrtf(s);
    }
    __syncthreads();
    int h = t >> 7;
    #pragma unroll
    for (int r = 0; r < 8; r++)
        outp[(node0 + r) * HD + t] = __float2bfloat16(tile[r][t] * rs[r][h]);
}

// ---------------------------------------------------------------- degree
__global__ void deg_kernel(const int* __restrict__ row, int* __restrict__ deg) {
    int e = blockIdx.x * 256 + threadIdx.x;
    if (e < NEDGE) atomicAdd(&deg[row[e]], 1);
}

__global__ void dis_kernel(const int* __restrict__ deg, float* __restrict__ dis) {
    int i = blockIdx.x * 256 + threadIdx.x;
    if (i < NTOT) {
        int d = deg[i];
        dis[i] = d > 0 ? rsqrtf((float)d) : 0.f;
    }
}

// ---------------------------------------------------------------- exclusive scan (single block)
__global__ __launch_bounds__(1024) void scan_kernel(const int* __restrict__ deg, int* __restrict__ row_ptr) {
    __shared__ int buf[1024];
    __shared__ int carry;
    int t = threadIdx.x;
    if (t == 0) carry = 0;
    __syncthreads();
    for (int base = 0; base < NTOT; base += 1024) {
        int v = deg[base + t];
        buf[t] = v;
        __syncthreads();
        for (int off = 1; off < 1024; off <<= 1) {
            int add = (t >= off) ? buf[t - off] : 0;
            __syncthreads();
            buf[t] += add;
            __syncthreads();
        }
        row_ptr[base + t] = carry + buf[t] - v;
        __syncthreads();
        if (t == 0) carry += buf[1023];
        __syncthreads();
    }
    if (t == 0) row_ptr[NTOT] = carry;
}

// ---------------------------------------------------------------- CSR scatter
__global__ void scatter_kernel(const int* __restrict__ row, const int* __restrict__ col,
                               const int* __restrict__ row_ptr, int* __restrict__ fill,
                               const float* __restrict__ dis,
                               int* __restrict__ col_idx, float* __restrict__ wcol) {
    int e = blockIdx.x * 256 + threadIdx.x;
    if (e < NEDGE) {
        int r = row[e], c = col[e];
        int pos = row_ptr[r] + atomicAdd(&fill[r], 1);
        col_idx[pos] = c;
        wcol[pos] = dis[c];
    }
}

// ---------------------------------------------------------------- ksum
__global__ __launch_bounds__(512) void ksum_kernel(const bf16* __restrict__ ks, float* __restrict__ ksum) {
    int b = blockIdx.x >> 5, chunk = blockIdx.x & 31;
    int t = threadIdx.x;
    int n0 = b * NPG + chunk * 128;
    float s = 0.f;
    for (int i = 0; i < 128; i++) s += b2f(ks[(size_t)(n0 + i) * HD + t]);
    atomicAdd(&ksum[b * HD + t], s);
}

// ---------------------------------------------------------------- den = qs . ksum + n (loop-invariant)
__global__ __launch_bounds__(256) void den_kernel(const bf16* __restrict__ qs, const float* __restrict__ ksum,
                                                  const int* __restrict__ n_nodes, float* __restrict__ den) {
    int n = blockIdx.x;
    int b = n >> 12;
    int w = threadIdx.x >> 6, lane = threadIdx.x & 63;
    int base = w * DIN;
    float p = b2f(qs[(size_t)n * HD + base + lane])      * ksum[b * HD + base + lane]
            + b2f(qs[(size_t)n * HD + base + 64 + lane]) * ksum[b * HD + base + 64 + lane];
    for (int off = 32; off > 0; off >>= 1) p += __shfl_down(p, off);
    if (lane == 0) den[n * NH + w] = p + (float)n_nodes[b];
}

// ---------------------------------------------------------------- init: cur(bf16) = acc(f32) = broadcast(x)
__global__ void init_kernel(const float* __restrict__ x, bf16* __restrict__ cur, float* __restrict__ acc) {
    int i = blockIdx.x * 256 + threadIdx.x;   // grid covers NTOT*HD
    int n = i >> 9, f = i & 511;
    float v = x[n * DIN + (f & 127)];
    cur[i] = __float2bfloat16(v);
    acc[i] = v;
}

// ---------------------------------------------------------------- kv = K^T V (+ vsum), per (b,h,chunk)
#define KVCHUNKS 16
#define NPC (NPG / KVCHUNKS)  // 256
__global__ __launch_bounds__(256) void kv_kernel(const bf16* __restrict__ ks, const bf16* __restrict__ cur,
                                                 float* __restrict__ kvT, float* __restrict__ vsum) {
    int blk = blockIdx.x;
    int chunk = blk & (KVCHUNKS - 1);
    int h = (blk >> 4) & (NH - 1);
    int b = blk >> 6;
    int t = threadIdx.x;
    int tx = t & 15, ty = t >> 4;
    __shared__ float ksh[4][DIN], vsh[4][DIN];
    float acc[8][8];
    #pragma unroll
    for (int i = 0; i < 8; i++)
        #pragma unroll
        for (int j = 0; j < 8; j++) acc[i][j] = 0.f;
    float vloc[8] = {0.f,0.f,0.f,0.f,0.f,0.f,0.f,0.f};
    int n0 = b * NPG + chunk * NPC;
    int lr = t >> 6;            // 0..3 row
    int lc = (t & 63) * 2;      // 0..126 col pair
    for (int nn = 0; nn < NPC; nn += 4) {
        {
            int node = n0 + nn + lr;
            const ushort2* kp = (const ushort2*)(ks + (size_t)node * HD + h * DIN + lc);
            const ushort2* vp = (const ushort2*)(cur + (size_t)node * HD + h * DIN + lc);
            ushort2 kk = *kp; ushort2 vv = *vp;
            ksh[lr][lc] = u2f(kk.x); ksh[lr][lc + 1] = u2f(kk.y);
            vsh[lr][lc] = u2f(vv.x); vsh[lr][lc + 1] = u2f(vv.y);
        }
        __syncthreads();
        #pragma unroll
        for (int r = 0; r < 4; r++) {
            float4 k0 = *(const float4*)&ksh[r][ty * 8];
            float4 k1 = *(const float4*)&ksh[r][ty * 8 + 4];
            float4 v0 = *(const float4*)&vsh[r][tx * 8];
            float4 v1 = *(const float4*)&vsh[r][tx * 8 + 4];
            float kd[8] = {k0.x,k0.y,k0.z,k0.w,k1.x,k1.y,k1.z,k1.w};
            float ve[8] = {v0.x,v0.y,v0.z,v0.w,v1.x,v1.y,v1.z,v1.w};
            #pragma unroll
            for (int di = 0; di < 8; di++)
                #pragma unroll
                for (int ei = 0; ei < 8; ei++)
                    acc[di][ei] += kd[di] * ve[ei];
            if (ty == 0) {
                #pragma unroll
                for (int ei = 0; ei < 8; ei++) vloc[ei] += ve[ei];
            }
        }
        __syncthreads();
    }
    float* dst = kvT + b * (DIN * HD);
    #pragma unroll
    for (int di = 0; di < 8; di++)
        #pragma unroll
        for (int ei = 0; ei < 8; ei++)
            atomicAdd(&dst[(ty * 8 + di) * HD + h * DIN + tx * 8 + ei], acc[di][ei]);
    if (ty == 0) {
        #pragma unroll
        for (int ei = 0; ei < 8; ei++)
            atomicAdd(&vsum[b * HD + h * DIN + tx * 8 + ei], vloc[ei]);
    }
}

// ---------------------------------------------------------------- GCN gather (bf16 in, bf16 out)
__global__ __launch_bounds__(128) void gcn_kernel(const bf16* __restrict__ cur, const int* __restrict__ row_ptr,
                                                  const int* __restrict__ col_idx, const float* __restrict__ wcol,
                                                  const float* __restrict__ dis, bf16* __restrict__ nxt) {
    int n = blockIdx.x;
    int t = threadIdx.x;
    int start = row_ptr[n], end = row_ptr[n + 1];
    float sx = 0.f, sy = 0.f, sz = 0.f, sw = 0.f;
    for (int j = start; j < end; j++) {
        int c = col_idx[j];
        float w = wcol[j];
        ushort4 v = *(const ushort4*)(cur + (size_t)c * HD + t * 4);
        sx += w * u2f(v.x); sy += w * u2f(v.y); sz += w * u2f(v.z); sw += w * u2f(v.w);
    }
    float dn = dis[n];
    bf16* o = nxt + (size_t)n * HD + t * 4;
    o[0] = __float2bfloat16(sx * dn);
    o[1] = __float2bfloat16(sy * dn);
    o[2] = __float2bfloat16(sz * dn);
    o[3] = __float2bfloat16(sw * dn);
}

// ---------------------------------------------------------------- attn numerator + combine + acc update
__global__ __launch_bounds__(512) void attn_kernel(const bf16* __restrict__ qs, const float* __restrict__ kvT,
                                                   const float* __restrict__ vsum, const float* __restrict__ den,
                                                   bf16* __restrict__ nxt, float* __restrict__ accb) {
    __shared__ float qsl[8][HD];
    int node0 = blockIdx.x * 8;
    int b = node0 / NPG;
    int t = threadIdx.x;
    for (int i = t; i < 8 * HD; i += 512) {
        int r = i >> 9, f = i & 511;
        qsl[r][f] = b2f(qs[(size_t)(node0 + r) * HD + f]);
    }
    __syncthreads();
    int f = t, h = f >> 7;
    float acc[8] = {0.f,0.f,0.f,0.f,0.f,0.f,0.f,0.f};
    const float* Bb = kvT + b * (DIN * HD);
    #pragma unroll 4
    for (int d = 0; d < DIN; d += 4) {
        float b0 = Bb[(d + 0) * HD + f];
        float b1 = Bb[(d + 1) * HD + f];
        float b2 = Bb[(d + 2) * HD + f];
        float b3 = Bb[(d + 3) * HD + f];
        int base = h * DIN + d;
        #pragma unroll
        for (int r = 0; r < 8; r++) {
            float4 qv = *(const float4*)&qsl[r][base];
            acc[r] += qv.x * b0 + qv.y * b1 + qv.z * b2 + qv.w * b3;
        }
    }
    float vs = vsum[b * HD + f];
    #pragma unroll
    for (int r = 0; r < 8; r++) {
        int n = node0 + r;
        float attnv = (acc[r] + vs) / den[n * NH + h];
        float val = 0.5f * b2f(nxt[(size_t)n * HD + f]) + 0.5f * attnv;
        nxt[(size_t)n * HD + f] = __float2bfloat16(val);
        accb[(size_t)n * HD + f] += val;
    }
}

// ---------------------------------------------------------------- output projection (fp32 out)
__global__ __launch_bounds__(128) void out_kernel(const float* __restrict__ accb, const float* __restrict__ WoT,
                                                  const float* __restrict__ Wo_b, float* __restrict__ out) {
    __shared__ float xs[8][HD];
    int node0 = blockIdx.x * 8;
    int t = threadIdx.x;
    for (int i = t; i < 8 * HD; i += 128) {
        int r = i >> 9, k = i & 511;
        xs[r][k] = accb[(size_t)(node0 + r) * HD + k];
    }
    __syncthreads();
    float acc[8] = {0.f,0.f,0.f,0.f,0.f,0.f,0.f,0.f};
    #pragma unroll 4
    for (int k = 0; k < HD; k += 4) {
        float w0 = WoT[(k + 0) * DOUTF + t];
        float w1 = WoT[(k + 1) * DOUTF + t];
        float w2 = WoT[(k + 2) * DOUTF + t];
        float w3 = WoT[(k + 3) * DOUTF + t];
        #pragma unroll
        for (int r = 0; r < 8; r++) {
            float4 xv = *(const float4*)&xs[r][k];
            acc[r] += xv.x * w0 + xv.y * w1 + xv.z * w2 + xv.w * w3;
        }
    }
    float bias = Wo_b[t];
    #pragma unroll
    for (int r = 0; r < 8; r++)
        out[(size_t)(node0 + r) * DOUTF + t] = (acc[r] + bias) * 0.25f;
}

// ================================================================ launch
extern "C" void kernel_launch(void* const* d_in, const int* in_sizes, int n_in,
                              void* d_out, int out_size, void* d_ws, size_t ws_size,
                              hipStream_t stream) {
    const float* x     = (const float*)d_in[0];
    const float* Wq_w  = (const float*)d_in[1];
    const float* Wq_b  = (const float*)d_in[2];
    const float* Wk_w  = (const float*)d_in[3];
    const float* Wk_b  = (const float*)d_in[4];
    const float* Wo_w  = (const float*)d_in[5];
    const float* Wo_b  = (const float*)d_in[6];
    const int*   edge  = (const int*)d_in[7];
    const int*   n_nod = (const int*)d_in[8];
    float* out = (float*)d_out;
    const int* erow = edge;
    const int* ecol = edge + NEDGE;

    char* w = (char*)d_ws;
    auto alloc = [&](size_t bytes) -> char* {
        char* p = w;
        w += (bytes + 255) & ~(size_t)255;
        return p;
    };
    bf16*  qs      = (bf16*) alloc((size_t)NTOT * HD * 2);   // 33.5 MB
    bf16*  ks      = (bf16*) alloc((size_t)NTOT * HD * 2);   // 33.5 MB
    bf16*  cur     = (bf16*) alloc((size_t)NTOT * HD * 2);   // 33.5 MB
    bf16*  nxt     = (bf16*) alloc((size_t)NTOT * HD * 2);   // 33.5 MB
    float* accb    = (float*)alloc((size_t)NTOT * HD * 4);   // 67 MB
    float* WqT     = (float*)alloc(DIN * HD * 4);
    float* WkT     = (float*)alloc(DIN * HD * 4);
    float* WoT     = (float*)alloc(HD * DOUTF * 4);
    int*   degfill = (int*)  alloc(2 * NTOT * 4);
    float* dis     = (float*)alloc(NTOT * 4);
    int*   row_ptr = (int*)  alloc((NTOT + 1) * 4);
    int*   col_idx = (int*)  alloc(NEDGE * 4);
    float* wcol    = (float*)alloc(NEDGE * 4);
    float* ksum    = (float*)alloc(BATCH * HD * 4);
    float* den     = (float*)alloc((size_t)NTOT * NH * 4);
    float* kvT     = (float*)alloc((size_t)BATCH * DIN * HD * 4);  // 2 MB
    float* vsum    = (float*)alloc(BATCH * HD * 4);                // contiguous after kvT
    int* deg  = degfill;
    int* fill = degfill + NTOT;
    // total ~207 MiB

    zero_kernel<<<64, 256, 0, stream>>>((uint4*)degfill, 2 * NTOT / 4);
    zero_kernel<<<4, 256, 0, stream>>>((uint4*)ksum, BATCH * HD / 4);

    transpose_kernel<<<(HD * DIN + 255) / 256, 256, 0, stream>>>(Wq_w, WqT, HD, DIN);
    transpose_kernel<<<(HD * DIN + 255) / 256, 256, 0, stream>>>(Wk_w, WkT, HD, DIN);
    transpose_kernel<<<(DOUTF * HD + 255) / 256, 256, 0, stream>>>(Wo_w, WoT, DOUTF, HD);

    proj_norm_kernel<<<NTOT / 8, 512, 0, stream>>>(x, WqT, Wq_b, qs);
    proj_norm_kernel<<<NTOT / 8, 512, 0, stream>>>(x, WkT, Wk_b, ks);

    deg_kernel<<<NEDGE / 256, 256, 0, stream>>>(erow, deg);
    dis_kernel<<<NTOT / 256, 256, 0, stream>>>(deg, dis);
    scan_kernel<<<1, 1024, 0, stream>>>(deg, row_ptr);
    scatter_kernel<<<NEDGE / 256, 256, 0, stream>>>(erow, ecol, row_ptr, fill, dis, col_idx, wcol);

    ksum_kernel<<<BATCH * 32, 512, 0, stream>>>(ks, ksum);
    den_kernel<<<NTOT, 256, 0, stream>>>(qs, ksum, n_nod, den);

    init_kernel<<<NTOT * HD / 256, 256, 0, stream>>>(x, cur, accb);

    bf16* c = cur;
    bf16* nx = nxt;
    for (int it = 0; it < KORDER; it++) {
        zero_kernel<<<((BATCH * DIN * HD + BATCH * HD) / 4 + 255) / 256, 256, 0, stream>>>(
            (uint4*)kvT, (BATCH * DIN * HD + BATCH * HD) / 4);
        kv_kernel<<<BATCH * NH * KVCHUNKS, 256, 0, stream>>>(ks, c, kvT, vsum);
        gcn_kernel<<<NTOT, 128, 0, stream>>>(c, row_ptr, col_idx, wcol, dis, nx);
        attn_kernel<<<NTOT / 8, 512, 0, stream>>>(qs, kvT, vsum, den, nx, accb);
        bf16* tmp = c; c = nx; nx = tmp;
    }

    out_kernel<<<NTOT / 8, 128, 0, stream>>>(accb, WoT, Wo_b, out);

    (void)in_sizes; (void)n_in; (void)out_size; (void)ws_size;
}

// Round 5
// 1664.800 us; speedup vs baseline: 1.8235x; 1.8235x over previous
//
#include <hip/hip_runtime.h>
#include <hip/hip_bf16.h>
#include <stdint.h>

typedef __hip_bfloat16 bf16;

#define BATCH  8
#define NPG    4096
#define DIN    128
#define NH     4
#define NEDGE  262144
#define DOUTF  128
#define KORDER 4
#define NTOT   (BATCH*NPG)   // 32768
#define HD     (NH*DIN)      // 512

typedef __attribute__((ext_vector_type(8))) short short8;
typedef __attribute__((ext_vector_type(4))) float f32x4;

static __device__ __forceinline__ float b2f(bf16 v) { return __bfloat162float(v); }
static __device__ __forceinline__ float u2f(unsigned short u) {
    union { float f; unsigned int i; } c; c.i = ((unsigned int)u) << 16; return c.f;
}

// ---------------------------------------------------------------- zero
__global__ void zero_kernel(uint4* p, int n) {
    int i = blockIdx.x * 256 + threadIdx.x;
    if (i < n) p[i] = uint4{0u, 0u, 0u, 0u};
}

// ---------------------------------------------------------------- transpose (fp32)
__global__ void transpose_kernel(const float* in, float* out, int R, int C) {
    int i = blockIdx.x * 256 + threadIdx.x;
    if (i < R * C) {
        int r = i / C, c = i - r * C;
        out[c * R + r] = in[i];
    }
}

// ---------------------------------------------------------------- projection + per-head normalize
// writes node-major (outp) and/or dim-major transposed (outT), either may be null
__global__ __launch_bounds__(512) void proj_norm_kernel(const float* __restrict__ x,
                                                        const float* __restrict__ WT,
                                                        const float* __restrict__ bias,
                                                        bf16* __restrict__ outp,
                                                        bf16* __restrict__ outT) {
    __shared__ float xs[8][DIN];
    __shared__ float tile[8][HD];
    __shared__ float rs[8][NH];
    int node0 = blockIdx.x * 8;
    int t = threadIdx.x;
    for (int i = t; i < 8 * DIN; i += 512) {
        int r = i >> 7, c = i & 127;
        xs[r][c] = x[(node0 + r) * DIN + c];
    }
    __syncthreads();
    float acc[8] = {0.f,0.f,0.f,0.f,0.f,0.f,0.f,0.f};
    #pragma unroll 4
    for (int k = 0; k < DIN; k += 4) {
        float w0 = WT[(k + 0) * HD + t];
        float w1 = WT[(k + 1) * HD + t];
        float w2 = WT[(k + 2) * HD + t];
        float w3 = WT[(k + 3) * HD + t];
        #pragma unroll
        for (int r = 0; r < 8; r++) {
            float4 xv = *(const float4*)&xs[r][k];
            acc[r] += xv.x * w0 + xv.y * w1 + xv.z * w2 + xv.w * w3;
        }
    }
    float bv = bias[t];
    #pragma unroll
    for (int r = 0; r < 8; r++) tile[r][t] = acc[r] + bv;
    __syncthreads();
    if (t < 32) {
        int r = t >> 2, h = t & 3;
        float s = 0.f;
        for (int dd = 0; dd < DIN; dd++) {
            int d = (dd + t) & 127;
            float v = tile[r][h * DIN + d];
            s += v * v;
        }
        rs[r][h] = rsqrtf(s);
    }
    __syncthreads();
    int h = t >> 7;
    unsigned short arr[8];
    #pragma unroll
    for (int r = 0; r < 8; r++) {
        bf16 hb = __float2bfloat16(tile[r][t] * rs[r][h]);
        arr[r] = *(unsigned short*)&hb;
        if (outp) outp[(size_t)(node0 + r) * HD + t] = hb;
    }
    if (outT) {
        int b = node0 >> 12, nl = node0 & 4095;
        *(uint4*)(outT + ((size_t)b * HD + t) * NPG + nl) = *(uint4*)arr;
    }
}

// ---------------------------------------------------------------- degree
__global__ void deg_kernel(const int* __restrict__ row, int* __restrict__ deg) {
    int e = blockIdx.x * 256 + threadIdx.x;
    if (e < NEDGE) atomicAdd(&deg[row[e]], 1);
}

__global__ void dis_kernel(const int* __restrict__ deg, float* __restrict__ dis) {
    int i = blockIdx.x * 256 + threadIdx.x;
    if (i < NTOT) {
        int d = deg[i];
        dis[i] = d > 0 ? rsqrtf((float)d) : 0.f;
    }
}

// ---------------------------------------------------------------- multi-block exclusive scan
__global__ __launch_bounds__(1024) void scan1_kernel(const int* __restrict__ deg,
                                                     int* __restrict__ row_ptr, int* __restrict__ bsum) {
    __shared__ int buf[1024];
    int g = blockIdx.x, t = threadIdx.x;
    int v = deg[g * 1024 + t];
    buf[t] = v;
    __syncthreads();
    for (int off = 1; off < 1024; off <<= 1) {
        int add = (t >= off) ? buf[t - off] : 0;
        __syncthreads();
        buf[t] += add;
        __syncthreads();
    }
    row_ptr[g * 1024 + t] = buf[t] - v;
    if (t == 1023) bsum[g] = buf[1023];
}

__global__ void scan2_kernel(const int* __restrict__ bsum, int* __restrict__ boff, int* __restrict__ row_ptr) {
    int run = 0;
    for (int g = 0; g < 32; g++) { boff[g] = run; run += bsum[g]; }
    row_ptr[NTOT] = run;
}

__global__ __launch_bounds__(1024) void scan3_kernel(int* __restrict__ row_ptr, const int* __restrict__ boff) {
    row_ptr[blockIdx.x * 1024 + threadIdx.x] += boff[blockIdx.x];
}

// ---------------------------------------------------------------- CSR scatter
__global__ void scatter_kernel(const int* __restrict__ row, const int* __restrict__ col,
                               const int* __restrict__ row_ptr, int* __restrict__ fill,
                               const float* __restrict__ dis,
                               int* __restrict__ col_idx, float* __restrict__ wcol) {
    int e = blockIdx.x * 256 + threadIdx.x;
    if (e < NEDGE) {
        int r = row[e], c = col[e];
        int pos = row_ptr[r] + atomicAdd(&fill[r], 1);
        col_idx[pos] = c;
        wcol[pos] = dis[c];
    }
}

// ---------------------------------------------------------------- row sums over transposed layout
// out[row] = sum_n T[row][n], rows = BATCH*HD, row length NPG
__global__ __launch_bounds__(256) void rowsum_kernel(const bf16* __restrict__ T, float* __restrict__ out) {
    int row = blockIdx.x * 4 + (threadIdx.x >> 6);
    int lane = threadIdx.x & 63;
    const ushort4* p = (const ushort4*)(T + (size_t)row * NPG);
    float s = 0.f;
    #pragma unroll
    for (int wv = 0; wv < 16; wv++) {
        ushort4 u = p[lane + wv * 64];
        s += u2f(u.x) + u2f(u.y) + u2f(u.z) + u2f(u.w);
    }
    for (int off = 32; off > 0; off >>= 1) s += __shfl_down(s, off);
    if (lane == 0) out[row] = s;
}

// ---------------------------------------------------------------- den = qs . ksum + n (loop-invariant)
__global__ __launch_bounds__(256) void den_kernel(const bf16* __restrict__ qs, const float* __restrict__ ksum,
                                                  const int* __restrict__ n_nodes, float* __restrict__ den) {
    int n = blockIdx.x;
    int b = n >> 12;
    int w = threadIdx.x >> 6, lane = threadIdx.x & 63;
    int base = w * DIN;
    float p = b2f(qs[(size_t)n * HD + base + lane])      * ksum[b * HD + base + lane]
            + b2f(qs[(size_t)n * HD + base + 64 + lane]) * ksum[b * HD + base + 64 + lane];
    for (int off = 32; off > 0; off >>= 1) p += __shfl_down(p, off);
    if (lane == 0) den[n * NH + w] = p + (float)n_nodes[b];
}

// ---------------------------------------------------------------- init: cur(bf16 node-major) + curT(bf16 dim-major) + acc(f32)
__global__ __launch_bounds__(512) void init_kernel(const float* __restrict__ x, bf16* __restrict__ cur,
                                                   bf16* __restrict__ curT, float* __restrict__ acc) {
    int node0 = blockIdx.x * 8;
    int t = threadIdx.x;
    int d = t & 127;
    int b = node0 >> 12, nl = node0 & 4095;
    unsigned short arr[8];
    #pragma unroll
    for (int r = 0; r < 8; r++) {
        float v = x[(size_t)(node0 + r) * DIN + d];
        bf16 hb = __float2bfloat16(v);
        cur[(size_t)(node0 + r) * HD + t] = hb;
        acc[(size_t)(node0 + r) * HD + t] = v;
        arr[r] = *(unsigned short*)&hb;
    }
    *(uint4*)(curT + ((size_t)b * HD + t) * NPG + nl) = *(uint4*)arr;
}

// ---------------------------------------------------------------- kv via MFMA: partial[blk][128][128] = ks^T * cur over node slice
// grid: (b*NH+h)*8 + s ; block 512 threads = 8 waves
#define KVSPLIT 8
__global__ __launch_bounds__(512, 1) void kv_mfma_kernel(const bf16* __restrict__ ksT,
                                                         const bf16* __restrict__ curT,
                                                         float* __restrict__ partial) {
    __shared__ __align__(16) short kshT[128][72];   // pad 64->72: 2-way (free) banking
    __shared__ __align__(16) short vshT[128][72];
    int blk = blockIdx.x;
    int s = blk & (KVSPLIT - 1);
    int bh = blk >> 3;                 // b*4 + h
    int tid = threadIdx.x;
    int lane = tid & 63;
    int w = tid >> 6;
    int wr = w >> 1, wc = w & 1;       // 4x2 wave grid
    int d0w = wr * 32, e0w = wc * 64;
    int l15 = lane & 15, quad = lane >> 4;

    f32x4 acc[2][4];
    #pragma unroll
    for (int i = 0; i < 2; i++)
        #pragma unroll
        for (int j = 0; j < 4; j++) acc[i][j] = f32x4{0.f, 0.f, 0.f, 0.f};

    const uint4* kg = (const uint4*)(ksT + ((size_t)bh * 128) * NPG);
    const uint4* vg = (const uint4*)(curT + ((size_t)bh * 128) * NPG);
    int n0 = s * (NPG / KVSPLIT);      // 512-node slice

    for (int c = 0; c < 8; c++) {
        int nb = n0 + c * 64;
        #pragma unroll
        for (int u = 0; u < 2; u++) {
            int unit = u * 512 + tid;       // 0..1023 : 128 rows x 8 parts
            int row = unit >> 3;
            int part = unit & 7;
            int gidx = row * (NPG / 8) + (nb >> 3) + part;
            uint4 kd = kg[gidx];
            uint4 vd = vg[gidx];
            *(uint4*)&kshT[row][part * 8] = kd;
            *(uint4*)&vshT[row][part * 8] = vd;
        }
        __syncthreads();
        #pragma unroll
        for (int kkstep = 0; kkstep < 2; kkstep++) {
            int kk = kkstep * 32 + quad * 8;
            short8 af[2], bfr[4];
            #pragma unroll
            for (int ti = 0; ti < 2; ti++)
                af[ti] = *(const short8*)&kshT[d0w + ti * 16 + l15][kk];
            #pragma unroll
            for (int tj = 0; tj < 4; tj++)
                bfr[tj] = *(const short8*)&vshT[e0w + tj * 16 + l15][kk];
            #pragma unroll
            for (int ti = 0; ti < 2; ti++)
                #pragma unroll
                for (int tj = 0; tj < 4; tj++)
                    acc[ti][tj] = __builtin_amdgcn_mfma_f32_16x16x32_bf16(af[ti], bfr[tj], acc[ti][tj], 0, 0, 0);
        }
        __syncthreads();
    }
    float* p = partial + (size_t)blk * (128 * 128);
    #pragma unroll
    for (int ti = 0; ti < 2; ti++)
        #pragma unroll
        for (int tj = 0; tj < 4; tj++)
            #pragma unroll
            for (int r = 0; r < 4; r++) {
                int row = d0w + ti * 16 + quad * 4 + r;
                int col = e0w + tj * 16 + l15;
                p[row * 128 + col] = acc[ti][tj][r];
            }
}

// ---------------------------------------------------------------- reduce split-K partials into kvT[b][d][h*128+e]
__global__ __launch_bounds__(256) void kvred_kernel(const float* __restrict__ partial, float* __restrict__ kvT) {
    int id = blockIdx.x * 256 + threadIdx.x;   // 524288
    int e = id & 127;
    int d = (id >> 7) & 127;
    int bh = id >> 14;
    const float* p = partial + (size_t)bh * KVSPLIT * 16384 + d * 128 + e;
    float sum = 0.f;
    #pragma unroll
    for (int s = 0; s < KVSPLIT; s++) sum += p[s * 16384];
    int b = bh >> 2, h = bh & 3;
    kvT[(size_t)b * 65536 + d * 512 + h * 128 + e] = sum;
}

// ---------------------------------------------------------------- GCN gather (bf16 in, bf16 out)
__global__ __launch_bounds__(128) void gcn_kernel(const bf16* __restrict__ cur, const int* __restrict__ row_ptr,
                                                  const int* __restrict__ col_idx, const float* __restrict__ wcol,
                                                  const float* __restrict__ dis, bf16* __restrict__ nxt) {
    int n = blockIdx.x;
    int t = threadIdx.x;
    int start = row_ptr[n], end = row_ptr[n + 1];
    float sx = 0.f, sy = 0.f, sz = 0.f, sw = 0.f;
    for (int j = start; j < end; j++) {
        int c = col_idx[j];
        float w = wcol[j];
        ushort4 v = *(const ushort4*)(cur + (size_t)c * HD + t * 4);
        sx += w * u2f(v.x); sy += w * u2f(v.y); sz += w * u2f(v.z); sw += w * u2f(v.w);
    }
    float dn = dis[n];
    bf16* o = nxt + (size_t)n * HD + t * 4;
    o[0] = __float2bfloat16(sx * dn);
    o[1] = __float2bfloat16(sy * dn);
    o[2] = __float2bfloat16(sz * dn);
    o[3] = __float2bfloat16(sw * dn);
}

// ---------------------------------------------------------------- attn numerator + combine + acc update (+ write curT)
__global__ __launch_bounds__(512) void attn_kernel(const bf16* __restrict__ qs, const float* __restrict__ kvT,
                                                   const float* __restrict__ vsum, const float* __restrict__ den,
                                                   bf16* __restrict__ nxt, bf16* __restrict__ curT,
                                                   float* __restrict__ accb) {
    __shared__ float qsl[8][HD];
    int node0 = blockIdx.x * 8;
    int b = node0 >> 12;
    int t = threadIdx.x;
    for (int i = t; i < 8 * HD; i += 512) {
        int r = i >> 9, f = i & 511;
        qsl[r][f] = b2f(qs[(size_t)(node0 + r) * HD + f]);
    }
    __syncthreads();
    int f = t, h = f >> 7;
    float acc[8] = {0.f,0.f,0.f,0.f,0.f,0.f,0.f,0.f};
    const float* Bb = kvT + (size_t)b * (DIN * HD);
    #pragma unroll 4
    for (int d = 0; d < DIN; d += 4) {
        float b0 = Bb[(d + 0) * HD + f];
        float b1 = Bb[(d + 1) * HD + f];
        float b2 = Bb[(d + 2) * HD + f];
        float b3 = Bb[(d + 3) * HD + f];
        int base = h * DIN + d;
        #pragma unroll
        for (int r = 0; r < 8; r++) {
            float4 qv = *(const float4*)&qsl[r][base];
            acc[r] += qv.x * b0 + qv.y * b1 + qv.z * b2 + qv.w * b3;
        }
    }
    float vs = vsum[b * HD + f];
    unsigned short arr[8];
    #pragma unroll
    for (int r = 0; r < 8; r++) {
        int n = node0 + r;
        float attnv = (acc[r] + vs) / den[n * NH + h];
        float val = 0.5f * b2f(nxt[(size_t)n * HD + f]) + 0.5f * attnv;
        bf16 hb = __float2bfloat16(val);
        nxt[(size_t)n * HD + f] = hb;
        arr[r] = *(unsigned short*)&hb;
        accb[(size_t)n * HD + f] += val;
    }
    int nl = node0 & 4095;
    *(uint4*)(curT + ((size_t)b * HD + f) * NPG + nl) = *(uint4*)arr;
}

// ---------------------------------------------------------------- output projection (fp32 out)
__global__ __launch_bounds__(128) void out_kernel(const float* __restrict__ accb, const float* __restrict__ WoT,
                                                  const float* __restrict__ Wo_b, float* __restrict__ out) {
    __shared__ float xs[8][HD];
    int node0 = blockIdx.x * 8;
    int t = threadIdx.x;
    for (int i = t; i < 8 * HD; i += 128) {
        int r = i >> 9, k = i & 511;
        xs[r][k] = accb[(size_t)(node0 + r) * HD + k];
    }
    __syncthreads();
    float acc[8] = {0.f,0.f,0.f,0.f,0.f,0.f,0.f,0.f};
    #pragma unroll 4
    for (int k = 0; k < HD; k += 4) {
        float w0 = WoT[(k + 0) * DOUTF + t];
        float w1 = WoT[(k + 1) * DOUTF + t];
        float w2 = WoT[(k + 2) * DOUTF + t];
        float w3 = WoT[(k + 3) * DOUTF + t];
        #pragma unroll
        for (int r = 0; r < 8; r++) {
            float4 xv = *(const float4*)&xs[r][k];
            acc[r] += xv.x * w0 + xv.y * w1 + xv.z * w2 + xv.w * w3;
        }
    }
    float bias = Wo_b[t];
    #pragma unroll
    for (int r = 0; r < 8; r++)
        out[(size_t)(node0 + r) * DOUTF + t] = (acc[r] + bias) * 0.25f;
}

// ================================================================ launch
extern "C" void kernel_launch(void* const* d_in, const int* in_sizes, int n_in,
                              void* d_out, int out_size, void* d_ws, size_t ws_size,
                              hipStream_t stream) {
    const float* x     = (const float*)d_in[0];
    const float* Wq_w  = (const float*)d_in[1];
    const float* Wq_b  = (const float*)d_in[2];
    const float* Wk_w  = (const float*)d_in[3];
    const float* Wk_b  = (const float*)d_in[4];
    const float* Wo_w  = (const float*)d_in[5];
    const float* Wo_b  = (const float*)d_in[6];
    const int*   edge  = (const int*)d_in[7];
    const int*   n_nod = (const int*)d_in[8];
    float* out = (float*)d_out;
    const int* erow = edge;
    const int* ecol = edge + NEDGE;

    char* w = (char*)d_ws;
    auto alloc = [&](size_t bytes) -> char* {
        char* p = w;
        w += (bytes + 255) & ~(size_t)255;
        return p;
    };
    bf16*  qs      = (bf16*) alloc((size_t)NTOT * HD * 2);            // 32 MiB (node-major)
    bf16*  ksT     = (bf16*) alloc((size_t)NTOT * HD * 2);            // 32 MiB (dim-major)
    bf16*  cur     = (bf16*) alloc((size_t)NTOT * HD * 2);            // 32 MiB
    bf16*  nxt     = (bf16*) alloc((size_t)NTOT * HD * 2);            // 32 MiB
    bf16*  curT    = (bf16*) alloc((size_t)NTOT * HD * 2);            // 32 MiB
    float* accb    = (float*)alloc((size_t)NTOT * HD * 4);            // 64 MiB
    float* partial = (float*)alloc((size_t)32 * KVSPLIT * 16384 * 4); // 16 MiB
    float* WqT     = (float*)alloc(DIN * HD * 4);
    float* WkT     = (float*)alloc(DIN * HD * 4);
    float* WoT     = (float*)alloc(HD * DOUTF * 4);
    int*   degfill = (int*)  alloc(2 * NTOT * 4);
    float* dis     = (float*)alloc(NTOT * 4);
    int*   row_ptr = (int*)  alloc((NTOT + 1) * 4);
    int*   col_idx = (int*)  alloc(NEDGE * 4);
    float* wcol    = (float*)alloc(NEDGE * 4);
    float* ksum    = (float*)alloc(BATCH * HD * 4);
    float* vsum    = (float*)alloc(BATCH * HD * 4);
    float* den     = (float*)alloc((size_t)NTOT * NH * 4);
    float* kvT     = (float*)alloc((size_t)BATCH * DIN * HD * 4);     // 2 MiB
    int*   bsum    = (int*)  alloc(32 * 4);
    int*   boff    = (int*)  alloc(32 * 4);
    int* deg  = degfill;
    int* fill = degfill + NTOT;
    // total ~246 MiB

    zero_kernel<<<64, 256, 0, stream>>>((uint4*)degfill, 2 * NTOT / 4);

    transpose_kernel<<<(HD * DIN + 255) / 256, 256, 0, stream>>>(Wq_w, WqT, HD, DIN);
    transpose_kernel<<<(HD * DIN + 255) / 256, 256, 0, stream>>>(Wk_w, WkT, HD, DIN);
    transpose_kernel<<<(DOUTF * HD + 255) / 256, 256, 0, stream>>>(Wo_w, WoT, DOUTF, HD);

    proj_norm_kernel<<<NTOT / 8, 512, 0, stream>>>(x, WqT, Wq_b, qs, (bf16*)nullptr);
    proj_norm_kernel<<<NTOT / 8, 512, 0, stream>>>(x, WkT, Wk_b, (bf16*)nullptr, ksT);

    deg_kernel<<<NEDGE / 256, 256, 0, stream>>>(erow, deg);
    dis_kernel<<<NTOT / 256, 256, 0, stream>>>(deg, dis);
    scan1_kernel<<<32, 1024, 0, stream>>>(deg, row_ptr, bsum);
    scan2_kernel<<<1, 1, 0, stream>>>(bsum, boff, row_ptr);
    scan3_kernel<<<32, 1024, 0, stream>>>(row_ptr, boff);
    scatter_kernel<<<NEDGE / 256, 256, 0, stream>>>(erow, ecol, row_ptr, fill, dis, col_idx, wcol);

    rowsum_kernel<<<BATCH * HD / 4, 256, 0, stream>>>(ksT, ksum);
    den_kernel<<<NTOT, 256, 0, stream>>>(qs, ksum, n_nod, den);

    init_kernel<<<NTOT / 8, 512, 0, stream>>>(x, cur, curT, accb);

    bf16* c = cur;
    bf16* nx = nxt;
    for (int it = 0; it < KORDER; it++) {
        kv_mfma_kernel<<<32 * KVSPLIT, 512, 0, stream>>>(ksT, curT, partial);
        kvred_kernel<<<32 * 16384 / 256, 256, 0, stream>>>(partial, kvT);
        rowsum_kernel<<<BATCH * HD / 4, 256, 0, stream>>>(curT, vsum);
        gcn_kernel<<<NTOT, 128, 0, stream>>>(c, row_ptr, col_idx, wcol, dis, nx);
        attn_kernel<<<NTOT / 8, 512, 0, stream>>>(qs, kvT, vsum, den, nx, curT, accb);
        bf16* tmp = c; c = nx; nx = tmp;
    }

    out_kernel<<<NTOT / 8, 128, 0, stream>>>(accb, WoT, Wo_b, out);

    (void)in_sizes; (void)n_in; (void)out_size; (void)ws_size;
}

// Round 6
// 1147.481 us; speedup vs baseline: 2.6456x; 1.4508x over previous
//
#include <hip/hip_runtime.h>
#include <hip/hip_bf16.h>
#include <stdint.h>

typedef __hip_bfloat16 bf16;

#define BATCH  8
#define NPG    4096
#define DIN    128
#define NH     4
#define NEDGE  262144
#define DOUTF  128
#define KORDER 4
#define NTOT   (BATCH*NPG)   // 32768
#define HD     (NH*DIN)      // 512

typedef __attribute__((ext_vector_type(8))) short short8;
typedef __attribute__((ext_vector_type(4))) float f32x4;

static __device__ __forceinline__ float b2f(bf16 v) { return __bfloat162float(v); }
static __device__ __forceinline__ float u2f(unsigned short u) {
    union { float f; unsigned int i; } c; c.i = ((unsigned int)u) << 16; return c.f;
}
static __device__ __forceinline__ unsigned short f2u(float f) {
    bf16 hb = __float2bfloat16(f);
    return *(unsigned short*)&hb;
}

// ---------------------------------------------------------------- zero
__global__ void zero_kernel(uint4* p, int n) {
    int i = blockIdx.x * 256 + threadIdx.x;
    if (i < n) p[i] = uint4{0u, 0u, 0u, 0u};
}

// ---------------------------------------------------------------- transpose (fp32)
__global__ void transpose_kernel(const float* in, float* out, int R, int C) {
    int i = blockIdx.x * 256 + threadIdx.x;
    if (i < R * C) {
        int r = i / C, c = i - r * C;
        out[c * R + r] = in[i];
    }
}

// ---------------------------------------------------------------- projection + per-head normalize
__global__ __launch_bounds__(512) void proj_norm_kernel(const float* __restrict__ x,
                                                        const float* __restrict__ WT,
                                                        const float* __restrict__ bias,
                                                        bf16* __restrict__ outp,
                                                        bf16* __restrict__ outT) {
    __shared__ float xs[8][DIN];
    __shared__ float tile[8][HD];
    __shared__ float rs[8][NH];
    int node0 = blockIdx.x * 8;
    int t = threadIdx.x;
    for (int i = t; i < 8 * DIN; i += 512) {
        int r = i >> 7, c = i & 127;
        xs[r][c] = x[(node0 + r) * DIN + c];
    }
    __syncthreads();
    float acc[8] = {0.f,0.f,0.f,0.f,0.f,0.f,0.f,0.f};
    #pragma unroll 4
    for (int k = 0; k < DIN; k += 4) {
        float w0 = WT[(k + 0) * HD + t];
        float w1 = WT[(k + 1) * HD + t];
        float w2 = WT[(k + 2) * HD + t];
        float w3 = WT[(k + 3) * HD + t];
        #pragma unroll
        for (int r = 0; r < 8; r++) {
            float4 xv = *(const float4*)&xs[r][k];
            acc[r] += xv.x * w0 + xv.y * w1 + xv.z * w2 + xv.w * w3;
        }
    }
    float bv = bias[t];
    #pragma unroll
    for (int r = 0; r < 8; r++) tile[r][t] = acc[r] + bv;
    __syncthreads();
    if (t < 32) {
        int r = t >> 2, h = t & 3;
        float s = 0.f;
        for (int dd = 0; dd < DIN; dd++) {
            int d = (dd + t) & 127;
            float v = tile[r][h * DIN + d];
            s += v * v;
        }
        rs[r][h] = rsqrtf(s);
    }
    __syncthreads();
    int h = t >> 7;
    unsigned short arr[8];
    #pragma unroll
    for (int r = 0; r < 8; r++) {
        bf16 hb = __float2bfloat16(tile[r][t] * rs[r][h]);
        arr[r] = *(unsigned short*)&hb;
        if (outp) outp[(size_t)(node0 + r) * HD + t] = hb;
    }
    if (outT) {
        int b = node0 >> 12, nl = node0 & 4095;
        *(uint4*)(outT + ((size_t)b * HD + t) * NPG + nl) = *(uint4*)arr;
    }
}

// ---------------------------------------------------------------- degree
__global__ void deg_kernel(const int* __restrict__ row, int* __restrict__ deg) {
    int e = blockIdx.x * 256 + threadIdx.x;
    if (e < NEDGE) atomicAdd(&deg[row[e]], 1);
}

__global__ void dis_kernel(const int* __restrict__ deg, float* __restrict__ dis) {
    int i = blockIdx.x * 256 + threadIdx.x;
    if (i < NTOT) {
        int d = deg[i];
        dis[i] = d > 0 ? rsqrtf((float)d) : 0.f;
    }
}

// ---------------------------------------------------------------- multi-block exclusive scan
__global__ __launch_bounds__(1024) void scan1_kernel(const int* __restrict__ deg,
                                                     int* __restrict__ row_ptr, int* __restrict__ bsum) {
    __shared__ int buf[1024];
    int g = blockIdx.x, t = threadIdx.x;
    int v = deg[g * 1024 + t];
    buf[t] = v;
    __syncthreads();
    for (int off = 1; off < 1024; off <<= 1) {
        int add = (t >= off) ? buf[t - off] : 0;
        __syncthreads();
        buf[t] += add;
        __syncthreads();
    }
    row_ptr[g * 1024 + t] = buf[t] - v;
    if (t == 1023) bsum[g] = buf[1023];
}

__global__ void scan2_kernel(const int* __restrict__ bsum, int* __restrict__ boff, int* __restrict__ row_ptr) {
    int run = 0;
    for (int g = 0; g < 32; g++) { boff[g] = run; run += bsum[g]; }
    row_ptr[NTOT] = run;
}

__global__ __launch_bounds__(1024) void scan3_kernel(int* __restrict__ row_ptr, const int* __restrict__ boff) {
    row_ptr[blockIdx.x * 1024 + threadIdx.x] += boff[blockIdx.x];
}

// ---------------------------------------------------------------- CSR scatter
__global__ void scatter_kernel(const int* __restrict__ row, const int* __restrict__ col,
                               const int* __restrict__ row_ptr, int* __restrict__ fill,
                               const float* __restrict__ dis,
                               int* __restrict__ col_idx, float* __restrict__ wcol) {
    int e = blockIdx.x * 256 + threadIdx.x;
    if (e < NEDGE) {
        int r = row[e], c = col[e];
        int pos = row_ptr[r] + atomicAdd(&fill[r], 1);
        col_idx[pos] = c;
        wcol[pos] = dis[c];
    }
}

// ---------------------------------------------------------------- row sums over transposed layout
__global__ __launch_bounds__(256) void rowsum_kernel(const bf16* __restrict__ T, float* __restrict__ out) {
    int row = blockIdx.x * 4 + (threadIdx.x >> 6);
    int lane = threadIdx.x & 63;
    const ushort4* p = (const ushort4*)(T + (size_t)row * NPG);
    float s = 0.f;
    #pragma unroll
    for (int wv = 0; wv < 16; wv++) {
        ushort4 u = p[lane + wv * 64];
        s += u2f(u.x) + u2f(u.y) + u2f(u.z) + u2f(u.w);
    }
    for (int off = 32; off > 0; off >>= 1) s += __shfl_down(s, off);
    if (lane == 0) out[row] = s;
}

// ---------------------------------------------------------------- rden = 1/(qs . ksum + n)  (loop-invariant)
__global__ __launch_bounds__(256) void den_kernel(const bf16* __restrict__ qs, const float* __restrict__ ksum,
                                                  const int* __restrict__ n_nodes, float* __restrict__ rden) {
    int n = blockIdx.x;
    int b = n >> 12;
    int w = threadIdx.x >> 6, lane = threadIdx.x & 63;
    int base = w * DIN;
    float p = b2f(qs[(size_t)n * HD + base + lane])      * ksum[b * HD + base + lane]
            + b2f(qs[(size_t)n * HD + base + 64 + lane]) * ksum[b * HD + base + 64 + lane];
    for (int off = 32; off > 0; off >>= 1) p += __shfl_down(p, off);
    if (lane == 0) rden[n * NH + w] = 1.0f / (p + (float)n_nodes[b]);
}

// ---------------------------------------------------------------- init
__global__ __launch_bounds__(512) void init_kernel(const float* __restrict__ x, bf16* __restrict__ cur,
                                                   bf16* __restrict__ curT, float* __restrict__ acc) {
    int node0 = blockIdx.x * 8;
    int t = threadIdx.x;
    int d = t & 127;
    int b = node0 >> 12, nl = node0 & 4095;
    unsigned short arr[8];
    #pragma unroll
    for (int r = 0; r < 8; r++) {
        float v = x[(size_t)(node0 + r) * DIN + d];
        bf16 hb = __float2bfloat16(v);
        cur[(size_t)(node0 + r) * HD + t] = hb;
        acc[(size_t)(node0 + r) * HD + t] = v;
        arr[r] = *(unsigned short*)&hb;
    }
    *(uint4*)(curT + ((size_t)b * HD + t) * NPG + nl) = *(uint4*)arr;
}

// ---------------------------------------------------------------- kv via MFMA: split-K partials
#define KVSPLIT 8
__global__ __launch_bounds__(512, 1) void kv_mfma_kernel(const bf16* __restrict__ ksT,
                                                         const bf16* __restrict__ curT,
                                                         float* __restrict__ partial) {
    __shared__ __align__(16) short kshT[128][72];
    __shared__ __align__(16) short vshT[128][72];
    int blk = blockIdx.x;
    int s = blk & (KVSPLIT - 1);
    int bh = blk >> 3;
    int tid = threadIdx.x;
    int lane = tid & 63;
    int w = tid >> 6;
    int wr = w >> 1, wc = w & 1;
    int d0w = wr * 32, e0w = wc * 64;
    int l15 = lane & 15, quad = lane >> 4;

    f32x4 acc[2][4];
    #pragma unroll
    for (int i = 0; i < 2; i++)
        #pragma unroll
        for (int j = 0; j < 4; j++) acc[i][j] = f32x4{0.f, 0.f, 0.f, 0.f};

    const uint4* kg = (const uint4*)(ksT + ((size_t)bh * 128) * NPG);
    const uint4* vg = (const uint4*)(curT + ((size_t)bh * 128) * NPG);
    int n0 = s * (NPG / KVSPLIT);

    for (int c = 0; c < 8; c++) {
        int nb = n0 + c * 64;
        #pragma unroll
        for (int u = 0; u < 2; u++) {
            int unit = u * 512 + tid;
            int row = unit >> 3;
            int part = unit & 7;
            int gidx = row * (NPG / 8) + (nb >> 3) + part;
            uint4 kd = kg[gidx];
            uint4 vd = vg[gidx];
            *(uint4*)&kshT[row][part * 8] = kd;
            *(uint4*)&vshT[row][part * 8] = vd;
        }
        __syncthreads();
        #pragma unroll
        for (int kkstep = 0; kkstep < 2; kkstep++) {
            int kk = kkstep * 32 + quad * 8;
            short8 af[2], bfr[4];
            #pragma unroll
            for (int ti = 0; ti < 2; ti++)
                af[ti] = *(const short8*)&kshT[d0w + ti * 16 + l15][kk];
            #pragma unroll
            for (int tj = 0; tj < 4; tj++)
                bfr[tj] = *(const short8*)&vshT[e0w + tj * 16 + l15][kk];
            #pragma unroll
            for (int ti = 0; ti < 2; ti++)
                #pragma unroll
                for (int tj = 0; tj < 4; tj++)
                    acc[ti][tj] = __builtin_amdgcn_mfma_f32_16x16x32_bf16(af[ti], bfr[tj], acc[ti][tj], 0, 0, 0);
        }
        __syncthreads();
    }
    float* p = partial + (size_t)blk * (128 * 128);
    #pragma unroll
    for (int ti = 0; ti < 2; ti++)
        #pragma unroll
        for (int tj = 0; tj < 4; tj++)
            #pragma unroll
            for (int r = 0; r < 4; r++) {
                int row = d0w + ti * 16 + quad * 4 + r;
                int col = e0w + tj * 16 + l15;
                p[row * 128 + col] = acc[ti][tj][r];
            }
}

// ---------------------------------------------------------------- reduce split-K partials -> kvB[bh][e][d] (bf16)
__global__ __launch_bounds__(512) void kvredB_kernel(const float* __restrict__ partial, bf16* __restrict__ kvB) {
    __shared__ short t[128][136];
    int bh = blockIdx.x;
    const float* p = partial + (size_t)bh * KVSPLIT * 16384;
    int tid = threadIdx.x;
    for (int c = 0; c < 32; c++) {
        int idx = c * 512 + tid;       // = d*128 + e, coalesced reads
        int e = idx & 127, d = idx >> 7;
        float s = 0.f;
        #pragma unroll
        for (int sl = 0; sl < KVSPLIT; sl++) s += p[sl * 16384 + idx];
        t[e][d] = (short)f2u(s);
    }
    __syncthreads();
    for (int c = 0; c < 4; c++) {
        int unit = c * 512 + tid;      // 2048 units: (e, 8d)
        int e = unit >> 4, dp = (unit & 15) * 8;
        *(uint4*)((unsigned short*)kvB + (size_t)bh * 16384 + e * 128 + dp) = *(uint4*)&t[e][dp];
    }
}

// ---------------------------------------------------------------- GCN gather (bf16 in, bf16 out)
__global__ __launch_bounds__(128) void gcn_kernel(const bf16* __restrict__ cur, const int* __restrict__ row_ptr,
                                                  const int* __restrict__ col_idx, const float* __restrict__ wcol,
                                                  const float* __restrict__ dis, bf16* __restrict__ nxt) {
    int n = blockIdx.x;
    int t = threadIdx.x;
    int start = row_ptr[n], end = row_ptr[n + 1];
    float sx = 0.f, sy = 0.f, sz = 0.f, sw = 0.f;
    for (int j = start; j < end; j++) {
        int c = col_idx[j];
        float w = wcol[j];
        ushort4 v = *(const ushort4*)(cur + (size_t)c * HD + t * 4);
        sx += w * u2f(v.x); sy += w * u2f(v.y); sz += w * u2f(v.z); sw += w * u2f(v.w);
    }
    float dn = dis[n];
    bf16* o = nxt + (size_t)n * HD + t * 4;
    o[0] = __float2bfloat16(sx * dn);
    o[1] = __float2bfloat16(sy * dn);
    o[2] = __float2bfloat16(sz * dn);
    o[3] = __float2bfloat16(sw * dn);
}

// ---------------------------------------------------------------- attn via MFMA + fused combine/acc epilogue
// grid: (b*NH+h)*32 + m ; 128 nodes x 128 e per block, 512 threads
__global__ __launch_bounds__(512, 2) void attn_mfma_kernel(const bf16* __restrict__ qs,
                                                           const bf16* __restrict__ kvB,
                                                           const float* __restrict__ vsum,
                                                           const float* __restrict__ rden,
                                                           bf16* __restrict__ nxt,
                                                           bf16* __restrict__ curT,
                                                           float* __restrict__ accb) {
    __shared__ __align__(16) short t1[128][136];   // [n_local][f_local]
    int blk = blockIdx.x;
    int m = blk & 31;
    int bh = blk >> 5;
    int h = bh & 3, b = bh >> 2;
    int n0 = b * NPG + m * 128;
    int tid = threadIdx.x;
    int lane = tid & 63, w = tid >> 6;
    int wr = w >> 1, wc = w & 1;
    int e0w = wc * 64;
    int l15 = lane & 15, quad = lane >> 4;

    // stage gcn result (nxt) into LDS, coalesced
    {
        const bf16* src = nxt + (size_t)n0 * HD + h * DIN;
        #pragma unroll
        for (int u = 0; u < 4; u++) {
            int unit = u * 512 + tid;          // (nl, fp): 128 x 16
            int nl = unit >> 4, fp = (unit & 15) * 8;
            uint4 v = *(const uint4*)(src + (size_t)nl * HD + fp);
            *(uint4*)&t1[nl][fp] = v;
        }
    }

    f32x4 acc[2][4];
    #pragma unroll
    for (int i = 0; i < 2; i++)
        #pragma unroll
        for (int j = 0; j < 4; j++) acc[i][j] = f32x4{0.f, 0.f, 0.f, 0.f};

    const bf16* Aq = qs + (size_t)n0 * HD + h * DIN;
    const unsigned short* Bk = (const unsigned short*)kvB + (size_t)bh * 16384;
    #pragma unroll
    for (int ks = 0; ks < 4; ks++) {
        int kk = ks * 32 + quad * 8;
        short8 af[2], bfr[4];
        #pragma unroll
        for (int ti = 0; ti < 2; ti++)
            af[ti] = *(const short8*)(Aq + (size_t)(wr * 32 + ti * 16 + l15) * HD + kk);
        #pragma unroll
        for (int tj = 0; tj < 4; tj++)
            bfr[tj] = *(const short8*)(Bk + (e0w + tj * 16 + l15) * 128 + kk);
        #pragma unroll
        for (int ti = 0; ti < 2; ti++)
            #pragma unroll
            for (int tj = 0; tj < 4; tj++)
                acc[ti][tj] = __builtin_amdgcn_mfma_f32_16x16x32_bf16(af[ti], bfr[tj], acc[ti][tj], 0, 0, 0);
    }
    __syncthreads();   // staging complete before epilogue reads t1

    // epilogue phase 1: combine, write val back into t1
    #pragma unroll
    for (int tj = 0; tj < 4; tj++) {
        int el = e0w + tj * 16 + l15;
        float vs = vsum[b * HD + h * DIN + el];
        #pragma unroll
        for (int ti = 0; ti < 2; ti++) {
            int nlb = wr * 32 + ti * 16 + quad * 4;
            #pragma unroll
            for (int r = 0; r < 4; r++) {
                int nl = nlb + r;
                float attnv = (acc[ti][tj][r] + vs) * rden[(size_t)(n0 + nl) * NH + h];
                float g = u2f((unsigned short)t1[nl][el]);
                float val = 0.5f * g + 0.5f * attnv;
                t1[nl][el] = (short)f2u(val);
            }
        }
    }
    __syncthreads();

    // phase 2a: nxt store + accb RMW (node-major, coalesced)
    {
        bf16* dstn = nxt + (size_t)n0 * HD + h * DIN;
        float* dsta = accb + (size_t)n0 * HD + h * DIN;
        #pragma unroll
        for (int u = 0; u < 4; u++) {
            int unit = u * 512 + tid;
            int nl = unit >> 4, fp = (unit & 15) * 8;
            uint4 v = *(uint4*)&t1[nl][fp];
            *(uint4*)(dstn + (size_t)nl * HD + fp) = v;
            unsigned short* sv = (unsigned short*)&v;
            float* ap = dsta + (size_t)nl * HD + fp;
            float4 a0 = *(float4*)ap;
            float4 a1 = *(float4*)(ap + 4);
            a0.x += u2f(sv[0]); a0.y += u2f(sv[1]); a0.z += u2f(sv[2]); a0.w += u2f(sv[3]);
            a1.x += u2f(sv[4]); a1.y += u2f(sv[5]); a1.z += u2f(sv[6]); a1.w += u2f(sv[7]);
            *(float4*)ap = a0;
            *(float4*)(ap + 4) = a1;
        }
    }
    // phase 2b: curT store (dim-major, coalesced 16B)
    {
        bf16* dstT = curT + ((size_t)b * HD + h * DIN) * NPG + m * 128;
        #pragma unroll
        for (int u = 0; u < 4; u++) {
            int unit = u * 512 + tid;
            int fl = unit >> 4, np = (unit & 15) * 8;
            unsigned short arr[8];
            #pragma unroll
            for (int j = 0; j < 8; j++) arr[j] = (unsigned short)t1[np + j][fl];
            *(uint4*)(dstT + (size_t)fl * NPG + np) = *(uint4*)arr;
        }
    }
}

// ---------------------------------------------------------------- output projection (fp32 out)
__global__ __launch_bounds__(128) void out_kernel(const float* __restrict__ accb, const float* __restrict__ WoT,
                                                  const float* __restrict__ Wo_b, float* __restrict__ out) {
    __shared__ float xs[8][HD];
    int node0 = blockIdx.x * 8;
    int t = threadIdx.x;
    for (int i = t; i < 8 * HD; i += 128) {
        int r = i >> 9, k = i & 511;
        xs[r][k] = accb[(size_t)(node0 + r) * HD + k];
    }
    __syncthreads();
    float acc[8] = {0.f,0.f,0.f,0.f,0.f,0.f,0.f,0.f};
    #pragma unroll 4
    for (int k = 0; k < HD; k += 4) {
        float w0 = WoT[(k + 0) * DOUTF + t];
        float w1 = WoT[(k + 1) * DOUTF + t];
        float w2 = WoT[(k + 2) * DOUTF + t];
        float w3 = WoT[(k + 3) * DOUTF + t];
        #pragma unroll
        for (int r = 0; r < 8; r++) {
            float4 xv = *(const float4*)&xs[r][k];
            acc[r] += xv.x * w0 + xv.y * w1 + xv.z * w2 + xv.w * w3;
        }
    }
    float bias = Wo_b[t];
    #pragma unroll
    for (int r = 0; r < 8; r++)
        out[(size_t)(node0 + r) * DOUTF + t] = (acc[r] + bias) * 0.25f;
}

// ================================================================ launch
extern "C" void kernel_launch(void* const* d_in, const int* in_sizes, int n_in,
                              void* d_out, int out_size, void* d_ws, size_t ws_size,
                              hipStream_t stream) {
    const float* x     = (const float*)d_in[0];
    const float* Wq_w  = (const float*)d_in[1];
    const float* Wq_b  = (const float*)d_in[2];
    const float* Wk_w  = (const float*)d_in[3];
    const float* Wk_b  = (const float*)d_in[4];
    const float* Wo_w  = (const float*)d_in[5];
    const float* Wo_b  = (const float*)d_in[6];
    const int*   edge  = (const int*)d_in[7];
    const int*   n_nod = (const int*)d_in[8];
    float* out = (float*)d_out;
    const int* erow = edge;
    const int* ecol = edge + NEDGE;

    char* w = (char*)d_ws;
    auto alloc = [&](size_t bytes) -> char* {
        char* p = w;
        w += (bytes + 255) & ~(size_t)255;
        return p;
    };
    bf16*  qs      = (bf16*) alloc((size_t)NTOT * HD * 2);            // 32 MiB
    bf16*  ksT     = (bf16*) alloc((size_t)NTOT * HD * 2);            // 32 MiB
    bf16*  cur     = (bf16*) alloc((size_t)NTOT * HD * 2);            // 32 MiB
    bf16*  nxt     = (bf16*) alloc((size_t)NTOT * HD * 2);            // 32 MiB
    bf16*  curT    = (bf16*) alloc((size_t)NTOT * HD * 2);            // 32 MiB
    float* accb    = (float*)alloc((size_t)NTOT * HD * 4);            // 64 MiB
    float* partial = (float*)alloc((size_t)32 * KVSPLIT * 16384 * 4); // 16 MiB
    bf16*  kvB     = (bf16*) alloc((size_t)32 * 16384 * 2);           // 1 MiB
    float* WqT     = (float*)alloc(DIN * HD * 4);
    float* WkT     = (float*)alloc(DIN * HD * 4);
    float* WoT     = (float*)alloc(HD * DOUTF * 4);
    int*   degfill = (int*)  alloc(2 * NTOT * 4);
    float* dis     = (float*)alloc(NTOT * 4);
    int*   row_ptr = (int*)  alloc((NTOT + 1) * 4);
    int*   col_idx = (int*)  alloc(NEDGE * 4);
    float* wcol    = (float*)alloc(NEDGE * 4);
    float* ksum    = (float*)alloc(BATCH * HD * 4);
    float* vsum    = (float*)alloc(BATCH * HD * 4);
    float* rden    = (float*)alloc((size_t)NTOT * NH * 4);
    int*   bsum    = (int*)  alloc(32 * 4);
    int*   boff    = (int*)  alloc(32 * 4);
    int* deg  = degfill;
    int* fill = degfill + NTOT;
    // total ~242 MiB

    zero_kernel<<<64, 256, 0, stream>>>((uint4*)degfill, 2 * NTOT / 4);

    transpose_kernel<<<(HD * DIN + 255) / 256, 256, 0, stream>>>(Wq_w, WqT, HD, DIN);
    transpose_kernel<<<(HD * DIN + 255) / 256, 256, 0, stream>>>(Wk_w, WkT, HD, DIN);
    transpose_kernel<<<(DOUTF * HD + 255) / 256, 256, 0, stream>>>(Wo_w, WoT, DOUTF, HD);

    proj_norm_kernel<<<NTOT / 8, 512, 0, stream>>>(x, WqT, Wq_b, qs, (bf16*)nullptr);
    proj_norm_kernel<<<NTOT / 8, 512, 0, stream>>>(x, WkT, Wk_b, (bf16*)nullptr, ksT);

    deg_kernel<<<NEDGE / 256, 256, 0, stream>>>(erow, deg);
    dis_kernel<<<NTOT / 256, 256, 0, stream>>>(deg, dis);
    scan1_kernel<<<32, 1024, 0, stream>>>(deg, row_ptr, bsum);
    scan2_kernel<<<1, 1, 0, stream>>>(bsum, boff, row_ptr);
    scan3_kernel<<<32, 1024, 0, stream>>>(row_ptr, boff);
    scatter_kernel<<<NEDGE / 256, 256, 0, stream>>>(erow, ecol, row_ptr, fill, dis, col_idx, wcol);

    rowsum_kernel<<<BATCH * HD / 4, 256, 0, stream>>>(ksT, ksum);
    den_kernel<<<NTOT, 256, 0, stream>>>(qs, ksum, n_nod, rden);

    init_kernel<<<NTOT / 8, 512, 0, stream>>>(x, cur, curT, accb);

    bf16* c = cur;
    bf16* nx = nxt;
    for (int it = 0; it < KORDER; it++) {
        kv_mfma_kernel<<<32 * KVSPLIT, 512, 0, stream>>>(ksT, curT, partial);
        kvredB_kernel<<<32, 512, 0, stream>>>(partial, kvB);
        rowsum_kernel<<<BATCH * HD / 4, 256, 0, stream>>>(curT, vsum);
        gcn_kernel<<<NTOT, 128, 0, stream>>>(c, row_ptr, col_idx, wcol, dis, nx);
        attn_mfma_kernel<<<32 * 32, 512, 0, stream>>>(qs, kvB, vsum, rden, nx, curT, accb);
        bf16* tmp = c; c = nx; nx = tmp;
    }

    out_kernel<<<NTOT / 8, 128, 0, stream>>>(accb, WoT, Wo_b, out);

    (void)in_sizes; (void)n_in; (void)out_size; (void)ws_size;
}

// Round 7
// 822.084 us; speedup vs baseline: 3.6927x; 1.3958x over previous
//
#include <hip/hip_runtime.h>
#include <hip/hip_bf16.h>
#include <stdint.h>

typedef __hip_bfloat16 bf16;

#define BATCH  8
#define NPG    4096
#define DIN    128
#define NH     4
#define NEDGE  262144
#define DOUTF  128
#define KORDER 4
#define NTOT   (BATCH*NPG)   // 32768
#define HD     (NH*DIN)      // 512

typedef __attribute__((ext_vector_type(8))) short short8;
typedef __attribute__((ext_vector_type(4))) float f32x4;

static __device__ __forceinline__ float b2f(bf16 v) { return __bfloat162float(v); }
static __device__ __forceinline__ float u2f(unsigned short u) {
    union { float f; unsigned int i; } c; c.i = ((unsigned int)u) << 16; return c.f;
}
static __device__ __forceinline__ unsigned short f2u(float f) {
    bf16 hb = __float2bfloat16(f);
    return *(unsigned short*)&hb;
}
static __device__ __forceinline__ short8 cvt8(const float* __restrict__ p) {
    float4 a = *(const float4*)p;
    float4 b = *(const float4*)(p + 4);
    unsigned short u[8] = { f2u(a.x), f2u(a.y), f2u(a.z), f2u(a.w),
                            f2u(b.x), f2u(b.y), f2u(b.z), f2u(b.w) };
    return *(short8*)u;
}

// ---------------------------------------------------------------- zero
__global__ void zero_kernel(uint4* p, int n) {
    int i = blockIdx.x * 256 + threadIdx.x;
    if (i < n) p[i] = uint4{0u, 0u, 0u, 0u};
}

// ---------------------------------------------------------------- projection + per-head normalize via MFMA
// block: 32 nodes x 512 features, 256 thr (4 waves, wave wc = head wc)
__global__ __launch_bounds__(256) void proj_mfma_kernel(const float* __restrict__ x,
                                                        const float* __restrict__ W,     // [512][128] row-major
                                                        const float* __restrict__ bias,  // [512]
                                                        bf16* __restrict__ outp,         // node-major or null
                                                        bf16* __restrict__ outT) {       // dim-major or null
    __shared__ __align__(16) short t1[32][520];
    int n0 = blockIdx.x * 32;
    int tid = threadIdx.x;
    int lane = tid & 63, wc = tid >> 6;        // wc = head
    int l15 = lane & 15, quad = lane >> 4;

    f32x4 acc[2][8];
    #pragma unroll
    for (int i = 0; i < 2; i++)
        #pragma unroll
        for (int j = 0; j < 8; j++) acc[i][j] = f32x4{0.f, 0.f, 0.f, 0.f};

    #pragma unroll
    for (int ks = 0; ks < 4; ks++) {
        int kk = ks * 32 + quad * 8;
        short8 af[2];
        #pragma unroll
        for (int ti = 0; ti < 2; ti++)
            af[ti] = cvt8(x + (size_t)(n0 + ti * 16 + l15) * DIN + kk);
        #pragma unroll
        for (int tj = 0; tj < 8; tj++) {
            short8 bfr = cvt8(W + (size_t)(wc * 128 + tj * 16 + l15) * DIN + kk);
            acc[0][tj] = __builtin_amdgcn_mfma_f32_16x16x32_bf16(af[0], bfr, acc[0][tj], 0, 0, 0);
            acc[1][tj] = __builtin_amdgcn_mfma_f32_16x16x32_bf16(af[1], bfr, acc[1][tj], 0, 0, 0);
        }
    }

    float bias_v[8];
    #pragma unroll
    for (int tj = 0; tj < 8; tj++) bias_v[tj] = bias[wc * 128 + tj * 16 + l15];

    #pragma unroll
    for (int ti = 0; ti < 2; ti++) {
        #pragma unroll
        for (int r = 0; r < 4; r++) {
            float s = 0.f;
            #pragma unroll
            for (int tj = 0; tj < 8; tj++) {
                float v = acc[ti][tj][r] + bias_v[tj];
                acc[ti][tj][r] = v;
                s += v * v;
            }
            s += __shfl_xor(s, 1); s += __shfl_xor(s, 2);
            s += __shfl_xor(s, 4); s += __shfl_xor(s, 8);
            float rs = rsqrtf(s);
            int node = ti * 16 + quad * 4 + r;
            #pragma unroll
            for (int tj = 0; tj < 8; tj++)
                t1[node][wc * 128 + tj * 16 + l15] = (short)f2u(acc[ti][tj][r] * rs);
        }
    }
    __syncthreads();

    if (outp) {
        #pragma unroll
        for (int u = 0; u < 8; u++) {
            int unit = u * 256 + tid;          // 2048 units: nl(32) x fp(64)
            int nl = unit >> 6, fp = (unit & 63) * 8;
            *(uint4*)(outp + (size_t)(n0 + nl) * HD + fp) = *(uint4*)&t1[nl][fp];
        }
    }
    if (outT) {
        int b = n0 >> 12, nl0 = n0 & 4095;
        #pragma unroll
        for (int u = 0; u < 8; u++) {
            int unit = u * 256 + tid;          // 2048 units: f(512) x np(4)
            int f = unit >> 2, np = (unit & 3) * 8;
            unsigned short arr[8];
            #pragma unroll
            for (int j = 0; j < 8; j++) arr[j] = (unsigned short)t1[np + j][f];
            *(uint4*)(outT + ((size_t)b * HD + f) * NPG + nl0 + np) = *(uint4*)arr;
        }
    }
}

// ---------------------------------------------------------------- degree
__global__ void deg_kernel(const int* __restrict__ row, int* __restrict__ deg) {
    int e = blockIdx.x * 256 + threadIdx.x;
    if (e < NEDGE) atomicAdd(&deg[row[e]], 1);
}

__global__ void dis_kernel(const int* __restrict__ deg, float* __restrict__ dis) {
    int i = blockIdx.x * 256 + threadIdx.x;
    if (i < NTOT) {
        int d = deg[i];
        dis[i] = d > 0 ? rsqrtf((float)d) : 0.f;
    }
}

// ---------------------------------------------------------------- multi-block exclusive scan
__global__ __launch_bounds__(1024) void scan1_kernel(const int* __restrict__ deg,
                                                     int* __restrict__ row_ptr, int* __restrict__ bsum) {
    __shared__ int buf[1024];
    int g = blockIdx.x, t = threadIdx.x;
    int v = deg[g * 1024 + t];
    buf[t] = v;
    __syncthreads();
    for (int off = 1; off < 1024; off <<= 1) {
        int add = (t >= off) ? buf[t - off] : 0;
        __syncthreads();
        buf[t] += add;
        __syncthreads();
    }
    row_ptr[g * 1024 + t] = buf[t] - v;
    if (t == 1023) bsum[g] = buf[1023];
}

__global__ void scan2_kernel(const int* __restrict__ bsum, int* __restrict__ boff, int* __restrict__ row_ptr) {
    int run = 0;
    for (int g = 0; g < 32; g++) { boff[g] = run; run += bsum[g]; }
    row_ptr[NTOT] = run;
}

__global__ __launch_bounds__(1024) void scan3_kernel(int* __restrict__ row_ptr, const int* __restrict__ boff) {
    row_ptr[blockIdx.x * 1024 + threadIdx.x] += boff[blockIdx.x];
}

// ---------------------------------------------------------------- CSR scatter
__global__ void scatter_kernel(const int* __restrict__ row, const int* __restrict__ col,
                               const int* __restrict__ row_ptr, int* __restrict__ fill,
                               const float* __restrict__ dis,
                               int* __restrict__ col_idx, float* __restrict__ wcol) {
    int e = blockIdx.x * 256 + threadIdx.x;
    if (e < NEDGE) {
        int r = row[e], c = col[e];
        int pos = row_ptr[r] + atomicAdd(&fill[r], 1);
        col_idx[pos] = c;
        wcol[pos] = dis[c];
    }
}

// ---------------------------------------------------------------- row sums over transposed layout
__global__ __launch_bounds__(256) void rowsum_kernel(const bf16* __restrict__ T, float* __restrict__ out) {
    int row = blockIdx.x * 4 + (threadIdx.x >> 6);
    int lane = threadIdx.x & 63;
    const ushort4* p = (const ushort4*)(T + (size_t)row * NPG);
    float s = 0.f;
    #pragma unroll
    for (int wv = 0; wv < 16; wv++) {
        ushort4 u = p[lane + wv * 64];
        s += u2f(u.x) + u2f(u.y) + u2f(u.z) + u2f(u.w);
    }
    for (int off = 32; off > 0; off >>= 1) s += __shfl_down(s, off);
    if (lane == 0) out[row] = s;
}

// ---------------------------------------------------------------- rden = 1/(qs . ksum + n)
__global__ __launch_bounds__(256) void den_kernel(const bf16* __restrict__ qs, const float* __restrict__ ksum,
                                                  const int* __restrict__ n_nodes, float* __restrict__ rden) {
    int n = blockIdx.x;
    int b = n >> 12;
    int w = threadIdx.x >> 6, lane = threadIdx.x & 63;
    int base = w * DIN;
    float p = b2f(qs[(size_t)n * HD + base + lane])      * ksum[b * HD + base + lane]
            + b2f(qs[(size_t)n * HD + base + 64 + lane]) * ksum[b * HD + base + 64 + lane];
    for (int off = 32; off > 0; off >>= 1) p += __shfl_down(p, off);
    if (lane == 0) rden[n * NH + w] = 1.0f / (p + (float)n_nodes[b]);
}

// ---------------------------------------------------------------- init
__global__ __launch_bounds__(512) void init_kernel(const float* __restrict__ x, bf16* __restrict__ cur,
                                                   bf16* __restrict__ curT, float* __restrict__ acc) {
    int node0 = blockIdx.x * 8;
    int t = threadIdx.x;
    int d = t & 127;
    int b = node0 >> 12, nl = node0 & 4095;
    unsigned short arr[8];
    #pragma unroll
    for (int r = 0; r < 8; r++) {
        float v = x[(size_t)(node0 + r) * DIN + d];
        bf16 hb = __float2bfloat16(v);
        cur[(size_t)(node0 + r) * HD + t] = hb;
        acc[(size_t)(node0 + r) * HD + t] = v;
        arr[r] = *(unsigned short*)&hb;
    }
    *(uint4*)(curT + ((size_t)b * HD + t) * NPG + nl) = *(uint4*)arr;
}

// ---------------------------------------------------------------- kv via MFMA: split-K partials
#define KVSPLIT 8
__global__ __launch_bounds__(512, 1) void kv_mfma_kernel(const bf16* __restrict__ ksT,
                                                         const bf16* __restrict__ curT,
                                                         float* __restrict__ partial) {
    __shared__ __align__(16) short kshT[128][72];
    __shared__ __align__(16) short vshT[128][72];
    int blk = blockIdx.x;
    int s = blk & (KVSPLIT - 1);
    int bh = blk >> 3;
    int tid = threadIdx.x;
    int lane = tid & 63;
    int w = tid >> 6;
    int wr = w >> 1, wc = w & 1;
    int d0w = wr * 32, e0w = wc * 64;
    int l15 = lane & 15, quad = lane >> 4;

    f32x4 acc[2][4];
    #pragma unroll
    for (int i = 0; i < 2; i++)
        #pragma unroll
        for (int j = 0; j < 4; j++) acc[i][j] = f32x4{0.f, 0.f, 0.f, 0.f};

    const uint4* kg = (const uint4*)(ksT + ((size_t)bh * 128) * NPG);
    const uint4* vg = (const uint4*)(curT + ((size_t)bh * 128) * NPG);
    int n0 = s * (NPG / KVSPLIT);

    for (int c = 0; c < 8; c++) {
        int nb = n0 + c * 64;
        #pragma unroll
        for (int u = 0; u < 2; u++) {
            int unit = u * 512 + tid;
            int row = unit >> 3;
            int part = unit & 7;
            int gidx = row * (NPG / 8) + (nb >> 3) + part;
            uint4 kd = kg[gidx];
            uint4 vd = vg[gidx];
            *(uint4*)&kshT[row][part * 8] = kd;
            *(uint4*)&vshT[row][part * 8] = vd;
        }
        __syncthreads();
        #pragma unroll
        for (int kkstep = 0; kkstep < 2; kkstep++) {
            int kk = kkstep * 32 + quad * 8;
            short8 af[2], bfr[4];
            #pragma unroll
            for (int ti = 0; ti < 2; ti++)
                af[ti] = *(const short8*)&kshT[d0w + ti * 16 + l15][kk];
            #pragma unroll
            for (int tj = 0; tj < 4; tj++)
                bfr[tj] = *(const short8*)&vshT[e0w + tj * 16 + l15][kk];
            #pragma unroll
            for (int ti = 0; ti < 2; ti++)
                #pragma unroll
                for (int tj = 0; tj < 4; tj++)
                    acc[ti][tj] = __builtin_amdgcn_mfma_f32_16x16x32_bf16(af[ti], bfr[tj], acc[ti][tj], 0, 0, 0);
        }
        __syncthreads();
    }
    float* p = partial + (size_t)blk * (128 * 128);
    #pragma unroll
    for (int ti = 0; ti < 2; ti++)
        #pragma unroll
        for (int tj = 0; tj < 4; tj++)
            #pragma unroll
            for (int r = 0; r < 4; r++) {
                int row = d0w + ti * 16 + quad * 4 + r;
                int col = e0w + tj * 16 + l15;
                p[row * 128 + col] = acc[ti][tj][r];
            }
}

// ---------------------------------------------------------------- reduce split-K partials -> kvB[bh][e][d] (bf16)
__global__ __launch_bounds__(512) void kvredB_kernel(const float* __restrict__ partial, bf16* __restrict__ kvB) {
    __shared__ short t[128][136];
    int bh = blockIdx.x;
    const float* p = partial + (size_t)bh * KVSPLIT * 16384;
    int tid = threadIdx.x;
    for (int c = 0; c < 32; c++) {
        int idx = c * 512 + tid;       // = d*128 + e, coalesced reads
        int e = idx & 127, d = idx >> 7;
        float s = 0.f;
        #pragma unroll
        for (int sl = 0; sl < KVSPLIT; sl++) s += p[sl * 16384 + idx];
        t[e][d] = (short)f2u(s);
    }
    __syncthreads();
    for (int c = 0; c < 4; c++) {
        int unit = c * 512 + tid;      // 2048 units: (e, 8d)
        int e = unit >> 4, dp = (unit & 15) * 8;
        *(uint4*)((unsigned short*)kvB + (size_t)bh * 16384 + e * 128 + dp) = *(uint4*)&t[e][dp];
    }
}

// ---------------------------------------------------------------- GCN gather (bf16 in, bf16 out)
__global__ __launch_bounds__(128) void gcn_kernel(const bf16* __restrict__ cur, const int* __restrict__ row_ptr,
                                                  const int* __restrict__ col_idx, const float* __restrict__ wcol,
                                                  const float* __restrict__ dis, bf16* __restrict__ nxt) {
    int n = blockIdx.x;
    int t = threadIdx.x;
    int start = row_ptr[n], end = row_ptr[n + 1];
    float sx = 0.f, sy = 0.f, sz = 0.f, sw = 0.f;
    for (int j = start; j < end; j++) {
        int c = col_idx[j];
        float w = wcol[j];
        ushort4 v = *(const ushort4*)(cur + (size_t)c * HD + t * 4);
        sx += w * u2f(v.x); sy += w * u2f(v.y); sz += w * u2f(v.z); sw += w * u2f(v.w);
    }
    float dn = dis[n];
    bf16* o = nxt + (size_t)n * HD + t * 4;
    o[0] = __float2bfloat16(sx * dn);
    o[1] = __float2bfloat16(sy * dn);
    o[2] = __float2bfloat16(sz * dn);
    o[3] = __float2bfloat16(sw * dn);
}

// ---------------------------------------------------------------- attn via MFMA + fused combine/acc epilogue
__global__ __launch_bounds__(512, 2) void attn_mfma_kernel(const bf16* __restrict__ qs,
                                                           const bf16* __restrict__ kvB,
                                                           const float* __restrict__ vsum,
                                                           const float* __restrict__ rden,
                                                           bf16* __restrict__ nxt,
                                                           bf16* __restrict__ curT,
                                                           float* __restrict__ accb) {
    __shared__ __align__(16) short t1[128][136];
    int blk = blockIdx.x;
    int m = blk & 31;
    int bh = blk >> 5;
    int h = bh & 3, b = bh >> 2;
    int n0 = b * NPG + m * 128;
    int tid = threadIdx.x;
    int lane = tid & 63, w = tid >> 6;
    int wr = w >> 1, wc = w & 1;
    int e0w = wc * 64;
    int l15 = lane & 15, quad = lane >> 4;

    {
        const bf16* src = nxt + (size_t)n0 * HD + h * DIN;
        #pragma unroll
        for (int u = 0; u < 4; u++) {
            int unit = u * 512 + tid;
            int nl = unit >> 4, fp = (unit & 15) * 8;
            uint4 v = *(const uint4*)(src + (size_t)nl * HD + fp);
            *(uint4*)&t1[nl][fp] = v;
        }
    }

    f32x4 acc[2][4];
    #pragma unroll
    for (int i = 0; i < 2; i++)
        #pragma unroll
        for (int j = 0; j < 4; j++) acc[i][j] = f32x4{0.f, 0.f, 0.f, 0.f};

    const bf16* Aq = qs + (size_t)n0 * HD + h * DIN;
    const unsigned short* Bk = (const unsigned short*)kvB + (size_t)bh * 16384;
    #pragma unroll
    for (int ks = 0; ks < 4; ks++) {
        int kk = ks * 32 + quad * 8;
        short8 af[2], bfr[4];
        #pragma unroll
        for (int ti = 0; ti < 2; ti++)
            af[ti] = *(const short8*)(Aq + (size_t)(wr * 32 + ti * 16 + l15) * HD + kk);
        #pragma unroll
        for (int tj = 0; tj < 4; tj++)
            bfr[tj] = *(const short8*)(Bk + (e0w + tj * 16 + l15) * 128 + kk);
        #pragma unroll
        for (int ti = 0; ti < 2; ti++)
            #pragma unroll
            for (int tj = 0; tj < 4; tj++)
                acc[ti][tj] = __builtin_amdgcn_mfma_f32_16x16x32_bf16(af[ti], bfr[tj], acc[ti][tj], 0, 0, 0);
    }
    __syncthreads();

    #pragma unroll
    for (int tj = 0; tj < 4; tj++) {
        int el = e0w + tj * 16 + l15;
        float vs = vsum[b * HD + h * DIN + el];
        #pragma unroll
        for (int ti = 0; ti < 2; ti++) {
            int nlb = wr * 32 + ti * 16 + quad * 4;
            #pragma unroll
            for (int r = 0; r < 4; r++) {
                int nl = nlb + r;
                float attnv = (acc[ti][tj][r] + vs) * rden[(size_t)(n0 + nl) * NH + h];
                float g = u2f((unsigned short)t1[nl][el]);
                float val = 0.5f * g + 0.5f * attnv;
                t1[nl][el] = (short)f2u(val);
            }
        }
    }
    __syncthreads();

    {
        bf16* dstn = nxt + (size_t)n0 * HD + h * DIN;
        float* dsta = accb + (size_t)n0 * HD + h * DIN;
        #pragma unroll
        for (int u = 0; u < 4; u++) {
            int unit = u * 512 + tid;
            int nl = unit >> 4, fp = (unit & 15) * 8;
            uint4 v = *(uint4*)&t1[nl][fp];
            *(uint4*)(dstn + (size_t)nl * HD + fp) = v;
            unsigned short* sv = (unsigned short*)&v;
            float* ap = dsta + (size_t)nl * HD + fp;
            float4 a0 = *(float4*)ap;
            float4 a1 = *(float4*)(ap + 4);
            a0.x += u2f(sv[0]); a0.y += u2f(sv[1]); a0.z += u2f(sv[2]); a0.w += u2f(sv[3]);
            a1.x += u2f(sv[4]); a1.y += u2f(sv[5]); a1.z += u2f(sv[6]); a1.w += u2f(sv[7]);
            *(float4*)ap = a0;
            *(float4*)(ap + 4) = a1;
        }
    }
    {
        bf16* dstT = curT + ((size_t)b * HD + h * DIN) * NPG + m * 128;
        #pragma unroll
        for (int u = 0; u < 4; u++) {
            int unit = u * 512 + tid;
            int fl = unit >> 4, np = (unit & 15) * 8;
            unsigned short arr[8];
            #pragma unroll
            for (int j = 0; j < 8; j++) arr[j] = (unsigned short)t1[np + j][fl];
            *(uint4*)(dstT + (size_t)fl * NPG + np) = *(uint4*)arr;
        }
    }
}

// ---------------------------------------------------------------- output projection via MFMA
// block: 128 nodes x 128 outs, 512 thr (8 waves 4x2), K=512, A cvt from fp32 accb
__global__ __launch_bounds__(512) void out_mfma_kernel(const float* __restrict__ accb,
                                                       const float* __restrict__ Wo,    // [128][512] row-major
                                                       const float* __restrict__ Wo_b,
                                                       float* __restrict__ out) {
    int n0 = blockIdx.x * 128;
    int tid = threadIdx.x;
    int lane = tid & 63, w = tid >> 6;
    int wr = w >> 1, wc = w & 1;
    int l15 = lane & 15, quad = lane >> 4;

    f32x4 acc[2][4];
    #pragma unroll
    for (int i = 0; i < 2; i++)
        #pragma unroll
        for (int j = 0; j < 4; j++) acc[i][j] = f32x4{0.f, 0.f, 0.f, 0.f};

    for (int ks = 0; ks < 16; ks++) {
        int kk = ks * 32 + quad * 8;
        short8 af[2], bfr[4];
        #pragma unroll
        for (int ti = 0; ti < 2; ti++)
            af[ti] = cvt8(accb + (size_t)(n0 + wr * 32 + ti * 16 + l15) * HD + kk);
        #pragma unroll
        for (int tj = 0; tj < 4; tj++)
            bfr[tj] = cvt8(Wo + (size_t)(wc * 64 + tj * 16 + l15) * HD + kk);
        #pragma unroll
        for (int ti = 0; ti < 2; ti++)
            #pragma unroll
            for (int tj = 0; tj < 4; tj++)
                acc[ti][tj] = __builtin_amdgcn_mfma_f32_16x16x32_bf16(af[ti], bfr[tj], acc[ti][tj], 0, 0, 0);
    }

    #pragma unroll
    for (int tj = 0; tj < 4; tj++) {
        int col = wc * 64 + tj * 16 + l15;
        float bv = Wo_b[col];
        #pragma unroll
        for (int ti = 0; ti < 2; ti++) {
            int rowb = wr * 32 + ti * 16 + quad * 4;
            #pragma unroll
            for (int r = 0; r < 4; r++)
                out[(size_t)(n0 + rowb + r) * DOUTF + col] = (acc[ti][tj][r] + bv) * 0.25f;
        }
    }
}

// ================================================================ launch
extern "C" void kernel_launch(void* const* d_in, const int* in_sizes, int n_in,
                              void* d_out, int out_size, void* d_ws, size_t ws_size,
                              hipStream_t stream) {
    const float* x     = (const float*)d_in[0];
    const float* Wq_w  = (const float*)d_in[1];
    const float* Wq_b  = (const float*)d_in[2];
    const float* Wk_w  = (const float*)d_in[3];
    const float* Wk_b  = (const float*)d_in[4];
    const float* Wo_w  = (const float*)d_in[5];
    const float* Wo_b  = (const float*)d_in[6];
    const int*   edge  = (const int*)d_in[7];
    const int*   n_nod = (const int*)d_in[8];
    float* out = (float*)d_out;
    const int* erow = edge;
    const int* ecol = edge + NEDGE;

    char* w = (char*)d_ws;
    auto alloc = [&](size_t bytes) -> char* {
        char* p = w;
        w += (bytes + 255) & ~(size_t)255;
        return p;
    };
    bf16*  qs      = (bf16*) alloc((size_t)NTOT * HD * 2);            // 32 MiB
    bf16*  ksT     = (bf16*) alloc((size_t)NTOT * HD * 2);            // 32 MiB
    bf16*  cur     = (bf16*) alloc((size_t)NTOT * HD * 2);            // 32 MiB
    bf16*  nxt     = (bf16*) alloc((size_t)NTOT * HD * 2);            // 32 MiB
    bf16*  curT    = (bf16*) alloc((size_t)NTOT * HD * 2);            // 32 MiB
    float* accb    = (float*)alloc((size_t)NTOT * HD * 4);            // 64 MiB
    float* partial = (float*)alloc((size_t)32 * KVSPLIT * 16384 * 4); // 16 MiB
    bf16*  kvB     = (bf16*) alloc((size_t)32 * 16384 * 2);           // 1 MiB
    int*   degfill = (int*)  alloc(2 * NTOT * 4);
    float* dis     = (float*)alloc(NTOT * 4);
    int*   row_ptr = (int*)  alloc((NTOT + 1) * 4);
    int*   col_idx = (int*)  alloc(NEDGE * 4);
    float* wcol    = (float*)alloc(NEDGE * 4);
    float* ksum    = (float*)alloc(BATCH * HD * 4);
    float* vsum    = (float*)alloc(BATCH * HD * 4);
    float* rden    = (float*)alloc((size_t)NTOT * NH * 4);
    int*   bsum    = (int*)  alloc(32 * 4);
    int*   boff    = (int*)  alloc(32 * 4);
    int* deg  = degfill;
    int* fill = degfill + NTOT;
    // total ~243 MiB

    zero_kernel<<<64, 256, 0, stream>>>((uint4*)degfill, 2 * NTOT / 4);

    proj_mfma_kernel<<<NTOT / 32, 256, 0, stream>>>(x, Wq_w, Wq_b, qs, (bf16*)nullptr);
    proj_mfma_kernel<<<NTOT / 32, 256, 0, stream>>>(x, Wk_w, Wk_b, (bf16*)nullptr, ksT);

    deg_kernel<<<NEDGE / 256, 256, 0, stream>>>(erow, deg);
    dis_kernel<<<NTOT / 256, 256, 0, stream>>>(deg, dis);
    scan1_kernel<<<32, 1024, 0, stream>>>(deg, row_ptr, bsum);
    scan2_kernel<<<1, 1, 0, stream>>>(bsum, boff, row_ptr);
    scan3_kernel<<<32, 1024, 0, stream>>>(row_ptr, boff);
    scatter_kernel<<<NEDGE / 256, 256, 0, stream>>>(erow, ecol, row_ptr, fill, dis, col_idx, wcol);

    rowsum_kernel<<<BATCH * HD / 4, 256, 0, stream>>>(ksT, ksum);
    den_kernel<<<NTOT, 256, 0, stream>>>(qs, ksum, n_nod, rden);

    init_kernel<<<NTOT / 8, 512, 0, stream>>>(x, cur, curT, accb);

    bf16* c = cur;
    bf16* nx = nxt;
    for (int it = 0; it < KORDER; it++) {
        kv_mfma_kernel<<<32 * KVSPLIT, 512, 0, stream>>>(ksT, curT, partial);
        kvredB_kernel<<<32, 512, 0, stream>>>(partial, kvB);
        rowsum_kernel<<<BATCH * HD / 4, 256, 0, stream>>>(curT, vsum);
        gcn_kernel<<<NTOT, 128, 0, stream>>>(c, row_ptr, col_idx, wcol, dis, nx);
        attn_mfma_kernel<<<32 * 32, 512, 0, stream>>>(qs, kvB, vsum, rden, nx, curT, accb);
        bf16* tmp = c; c = nx; nx = tmp;
    }

    out_mfma_kernel<<<NTOT / 128, 512, 0, stream>>>(accb, Wo_w, Wo_b, out);

    (void)in_sizes; (void)n_in; (void)out_size; (void)ws_size;
}

// Round 8
// 727.029 us; speedup vs baseline: 4.1755x; 1.1307x over previous
//
#include <hip/hip_runtime.h>
#include <hip/hip_bf16.h>
#include <stdint.h>

typedef __hip_bfloat16 bf16;

#define BATCH  8
#define NPG    4096
#define DIN    128
#define NH     4
#define NEDGE  262144
#define DOUTF  128
#define KORDER 4
#define NTOT   (BATCH*NPG)   // 32768
#define HD     (NH*DIN)      // 512

typedef __attribute__((ext_vector_type(8))) short short8;
typedef __attribute__((ext_vector_type(4))) float f32x4;

static __device__ __forceinline__ float b2f(bf16 v) { return __bfloat162float(v); }
static __device__ __forceinline__ float u2f(unsigned short u) {
    union { float f; unsigned int i; } c; c.i = ((unsigned int)u) << 16; return c.f;
}
static __device__ __forceinline__ unsigned short f2u(float f) {
    bf16 hb = __float2bfloat16(f);
    return *(unsigned short*)&hb;
}
static __device__ __forceinline__ short8 cvt8(const float* __restrict__ p) {
    float4 a = *(const float4*)p;
    float4 b = *(const float4*)(p + 4);
    unsigned short u[8] = { f2u(a.x), f2u(a.y), f2u(a.z), f2u(a.w),
                            f2u(b.x), f2u(b.y), f2u(b.z), f2u(b.w) };
    return *(short8*)u;
}

// ---------------------------------------------------------------- zero
__global__ void zero_kernel(uint4* p, int n) {
    int i = blockIdx.x * 256 + threadIdx.x;
    if (i < n) p[i] = uint4{0u, 0u, 0u, 0u};
}

// ---------------------------------------------------------------- projection + per-head normalize via MFMA
__global__ __launch_bounds__(256) void proj_mfma_kernel(const float* __restrict__ x,
                                                        const float* __restrict__ W,     // [512][128] row-major
                                                        const float* __restrict__ bias,  // [512]
                                                        bf16* __restrict__ outp,         // node-major or null
                                                        bf16* __restrict__ outT) {       // dim-major or null
    __shared__ __align__(16) short t1[32][520];
    int n0 = blockIdx.x * 32;
    int tid = threadIdx.x;
    int lane = tid & 63, wc = tid >> 6;        // wc = head
    int l15 = lane & 15, quad = lane >> 4;

    f32x4 acc[2][8];
    #pragma unroll
    for (int i = 0; i < 2; i++)
        #pragma unroll
        for (int j = 0; j < 8; j++) acc[i][j] = f32x4{0.f, 0.f, 0.f, 0.f};

    #pragma unroll
    for (int ks = 0; ks < 4; ks++) {
        int kk = ks * 32 + quad * 8;
        short8 af[2];
        #pragma unroll
        for (int ti = 0; ti < 2; ti++)
            af[ti] = cvt8(x + (size_t)(n0 + ti * 16 + l15) * DIN + kk);
        #pragma unroll
        for (int tj = 0; tj < 8; tj++) {
            short8 bfr = cvt8(W + (size_t)(wc * 128 + tj * 16 + l15) * DIN + kk);
            acc[0][tj] = __builtin_amdgcn_mfma_f32_16x16x32_bf16(af[0], bfr, acc[0][tj], 0, 0, 0);
            acc[1][tj] = __builtin_amdgcn_mfma_f32_16x16x32_bf16(af[1], bfr, acc[1][tj], 0, 0, 0);
        }
    }

    float bias_v[8];
    #pragma unroll
    for (int tj = 0; tj < 8; tj++) bias_v[tj] = bias[wc * 128 + tj * 16 + l15];

    #pragma unroll
    for (int ti = 0; ti < 2; ti++) {
        #pragma unroll
        for (int r = 0; r < 4; r++) {
            float s = 0.f;
            #pragma unroll
            for (int tj = 0; tj < 8; tj++) {
                float v = acc[ti][tj][r] + bias_v[tj];
                acc[ti][tj][r] = v;
                s += v * v;
            }
            s += __shfl_xor(s, 1); s += __shfl_xor(s, 2);
            s += __shfl_xor(s, 4); s += __shfl_xor(s, 8);
            float rs = rsqrtf(s);
            int node = ti * 16 + quad * 4 + r;
            #pragma unroll
            for (int tj = 0; tj < 8; tj++)
                t1[node][wc * 128 + tj * 16 + l15] = (short)f2u(acc[ti][tj][r] * rs);
        }
    }
    __syncthreads();

    if (outp) {
        #pragma unroll
        for (int u = 0; u < 8; u++) {
            int unit = u * 256 + tid;
            int nl = unit >> 6, fp = (unit & 63) * 8;
            *(uint4*)(outp + (size_t)(n0 + nl) * HD + fp) = *(uint4*)&t1[nl][fp];
        }
    }
    if (outT) {
        int b = n0 >> 12, nl0 = n0 & 4095;
        #pragma unroll
        for (int u = 0; u < 8; u++) {
            int unit = u * 256 + tid;
            int f = unit >> 2, np = (unit & 3) * 8;
            unsigned short arr[8];
            #pragma unroll
            for (int j = 0; j < 8; j++) arr[j] = (unsigned short)t1[np + j][f];
            *(uint4*)(outT + ((size_t)b * HD + f) * NPG + nl0 + np) = *(uint4*)arr;
        }
    }
}

// ---------------------------------------------------------------- degree
__global__ void deg_kernel(const int* __restrict__ row, int* __restrict__ deg) {
    int e = blockIdx.x * 256 + threadIdx.x;
    if (e < NEDGE) atomicAdd(&deg[row[e]], 1);
}

__global__ void dis_kernel(const int* __restrict__ deg, float* __restrict__ dis) {
    int i = blockIdx.x * 256 + threadIdx.x;
    if (i < NTOT) {
        int d = deg[i];
        dis[i] = d > 0 ? rsqrtf((float)d) : 0.f;
    }
}

// ---------------------------------------------------------------- multi-block exclusive scan
__global__ __launch_bounds__(1024) void scan1_kernel(const int* __restrict__ deg,
                                                     int* __restrict__ row_ptr, int* __restrict__ bsum) {
    __shared__ int buf[1024];
    int g = blockIdx.x, t = threadIdx.x;
    int v = deg[g * 1024 + t];
    buf[t] = v;
    __syncthreads();
    for (int off = 1; off < 1024; off <<= 1) {
        int add = (t >= off) ? buf[t - off] : 0;
        __syncthreads();
        buf[t] += add;
        __syncthreads();
    }
    row_ptr[g * 1024 + t] = buf[t] - v;
    if (t == 1023) bsum[g] = buf[1023];
}

__global__ void scan2_kernel(const int* __restrict__ bsum, int* __restrict__ boff, int* __restrict__ row_ptr) {
    int run = 0;
    for (int g = 0; g < 32; g++) { boff[g] = run; run += bsum[g]; }
    row_ptr[NTOT] = run;
}

__global__ __launch_bounds__(1024) void scan3_kernel(int* __restrict__ row_ptr, const int* __restrict__ boff) {
    row_ptr[blockIdx.x * 1024 + threadIdx.x] += boff[blockIdx.x];
}

// ---------------------------------------------------------------- CSR scatter
__global__ void scatter_kernel(const int* __restrict__ row, const int* __restrict__ col,
                               const int* __restrict__ row_ptr, int* __restrict__ fill,
                               const float* __restrict__ dis,
                               int* __restrict__ col_idx, float* __restrict__ wcol) {
    int e = blockIdx.x * 256 + threadIdx.x;
    if (e < NEDGE) {
        int r = row[e], c = col[e];
        int pos = row_ptr[r] + atomicAdd(&fill[r], 1);
        col_idx[pos] = c;
        wcol[pos] = dis[c];
    }
}

// ---------------------------------------------------------------- row sums over transposed layout
__global__ __launch_bounds__(256) void rowsum_kernel(const bf16* __restrict__ T, float* __restrict__ out) {
    int row = blockIdx.x * 4 + (threadIdx.x >> 6);
    int lane = threadIdx.x & 63;
    const ushort4* p = (const ushort4*)(T + (size_t)row * NPG);
    float s = 0.f;
    #pragma unroll
    for (int wv = 0; wv < 16; wv++) {
        ushort4 u = p[lane + wv * 64];
        s += u2f(u.x) + u2f(u.y) + u2f(u.z) + u2f(u.w);
    }
    for (int off = 32; off > 0; off >>= 1) s += __shfl_down(s, off);
    if (lane == 0) out[row] = s;
}

// ---------------------------------------------------------------- rden = 1/(qs . ksum + n)
__global__ __launch_bounds__(256) void den_kernel(const bf16* __restrict__ qs, const float* __restrict__ ksum,
                                                  const int* __restrict__ n_nodes, float* __restrict__ rden) {
    int n = blockIdx.x;
    int b = n >> 12;
    int w = threadIdx.x >> 6, lane = threadIdx.x & 63;
    int base = w * DIN;
    float p = b2f(qs[(size_t)n * HD + base + lane])      * ksum[b * HD + base + lane]
            + b2f(qs[(size_t)n * HD + base + 64 + lane]) * ksum[b * HD + base + 64 + lane];
    for (int off = 32; off > 0; off >>= 1) p += __shfl_down(p, off);
    if (lane == 0) rden[n * NH + w] = 1.0f / (p + (float)n_nodes[b]);
}

// ---------------------------------------------------------------- init: cur(bf16) + curT(bf16) + acc(bf16)
__global__ __launch_bounds__(512) void init_kernel(const float* __restrict__ x, bf16* __restrict__ cur,
                                                   bf16* __restrict__ curT, bf16* __restrict__ acc) {
    int node0 = blockIdx.x * 8;
    int t = threadIdx.x;
    int d = t & 127;
    int b = node0 >> 12, nl = node0 & 4095;
    unsigned short arr[8];
    #pragma unroll
    for (int r = 0; r < 8; r++) {
        float v = x[(size_t)(node0 + r) * DIN + d];
        bf16 hb = __float2bfloat16(v);
        cur[(size_t)(node0 + r) * HD + t] = hb;
        acc[(size_t)(node0 + r) * HD + t] = hb;
        arr[r] = *(unsigned short*)&hb;
    }
    *(uint4*)(curT + ((size_t)b * HD + t) * NPG + nl) = *(uint4*)arr;
}

// ---------------------------------------------------------------- kv via MFMA: split-K partials (XCD-swizzled)
#define KVSPLIT 8
__global__ __launch_bounds__(512, 1) void kv_mfma_kernel(const bf16* __restrict__ ksT,
                                                         const bf16* __restrict__ curT,
                                                         float* __restrict__ partial) {
    __shared__ __align__(16) short kshT[128][72];
    __shared__ __align__(16) short vshT[128][72];
    int id = blockIdx.x;
    int b = id & 7;                 // XCD-local graph
    int u = id >> 3;                // 0..31
    int h = u >> 3;
    int s = u & 7;
    int bh = b * 4 + h;
    int blk = bh * KVSPLIT + s;     // partial slot
    int tid = threadIdx.x;
    int lane = tid & 63;
    int w = tid >> 6;
    int wr = w >> 1, wc = w & 1;
    int d0w = wr * 32, e0w = wc * 64;
    int l15 = lane & 15, quad = lane >> 4;

    f32x4 acc[2][4];
    #pragma unroll
    for (int i = 0; i < 2; i++)
        #pragma unroll
        for (int j = 0; j < 4; j++) acc[i][j] = f32x4{0.f, 0.f, 0.f, 0.f};

    const uint4* kg = (const uint4*)(ksT + ((size_t)bh * 128) * NPG);
    const uint4* vg = (const uint4*)(curT + ((size_t)bh * 128) * NPG);
    int n0 = s * (NPG / KVSPLIT);

    for (int c = 0; c < 8; c++) {
        int nb = n0 + c * 64;
        #pragma unroll
        for (int uu = 0; uu < 2; uu++) {
            int unit = uu * 512 + tid;
            int row = unit >> 3;
            int part = unit & 7;
            int gidx = row * (NPG / 8) + (nb >> 3) + part;
            uint4 kd = kg[gidx];
            uint4 vd = vg[gidx];
            *(uint4*)&kshT[row][part * 8] = kd;
            *(uint4*)&vshT[row][part * 8] = vd;
        }
        __syncthreads();
        #pragma unroll
        for (int kkstep = 0; kkstep < 2; kkstep++) {
            int kk = kkstep * 32 + quad * 8;
            short8 af[2], bfr[4];
            #pragma unroll
            for (int ti = 0; ti < 2; ti++)
                af[ti] = *(const short8*)&kshT[d0w + ti * 16 + l15][kk];
            #pragma unroll
            for (int tj = 0; tj < 4; tj++)
                bfr[tj] = *(const short8*)&vshT[e0w + tj * 16 + l15][kk];
            #pragma unroll
            for (int ti = 0; ti < 2; ti++)
                #pragma unroll
                for (int tj = 0; tj < 4; tj++)
                    acc[ti][tj] = __builtin_amdgcn_mfma_f32_16x16x32_bf16(af[ti], bfr[tj], acc[ti][tj], 0, 0, 0);
        }
        __syncthreads();
    }
    float* p = partial + (size_t)blk * (128 * 128);
    #pragma unroll
    for (int ti = 0; ti < 2; ti++)
        #pragma unroll
        for (int tj = 0; tj < 4; tj++)
            #pragma unroll
            for (int r = 0; r < 4; r++) {
                int row = d0w + ti * 16 + quad * 4 + r;
                int col = e0w + tj * 16 + l15;
                p[row * 128 + col] = acc[ti][tj][r];
            }
}

// ---------------------------------------------------------------- reduce split-K partials -> kvB[bh][e][d] (bf16)
// grid: 256 blocks = bh(32) x e-sixteenth(8), 256 threads
__global__ __launch_bounds__(256) void kvredB_kernel(const float* __restrict__ partial, bf16* __restrict__ kvB) {
    __shared__ __align__(16) short t[16][136];
    int blk = blockIdx.x;
    int bh = blk >> 3;
    int e0 = (blk & 7) * 16;
    int tid = threadIdx.x;
    int el = tid & 15;
    int dc = tid >> 4;          // 0..15
    const float* p = partial + (size_t)bh * (KVSPLIT * 16384);
    #pragma unroll
    for (int j = 0; j < 8; j++) {
        int d = dc * 8 + j;
        int idx = d * 128 + e0 + el;
        float s = 0.f;
        #pragma unroll
        for (int sl = 0; sl < KVSPLIT; sl++) s += p[sl * 16384 + idx];
        t[el][d] = (short)f2u(s);
    }
    __syncthreads();
    int e = tid >> 4, dp = (tid & 15) * 8;
    *(uint4*)((unsigned short*)kvB + (size_t)bh * 16384 + (e0 + e) * 128 + dp) = *(uint4*)&t[e][dp];
}

// ---------------------------------------------------------------- GCN gather (XCD-swizzled: id%8 = graph)
__global__ __launch_bounds__(128) void gcn_kernel(const bf16* __restrict__ cur, const int* __restrict__ row_ptr,
                                                  const int* __restrict__ col_idx, const float* __restrict__ wcol,
                                                  const float* __restrict__ dis, bf16* __restrict__ nxt) {
    int id = blockIdx.x;
    int n = ((id & 7) << 12) | (id >> 3);
    int t = threadIdx.x;
    int start = row_ptr[n], end = row_ptr[n + 1];
    float sx = 0.f, sy = 0.f, sz = 0.f, sw = 0.f;
    for (int j = start; j < end; j++) {
        int c = col_idx[j];
        float w = wcol[j];
        ushort4 v = *(const ushort4*)(cur + (size_t)c * HD + t * 4);
        sx += w * u2f(v.x); sy += w * u2f(v.y); sz += w * u2f(v.z); sw += w * u2f(v.w);
    }
    float dn = dis[n];
    bf16* o = nxt + (size_t)n * HD + t * 4;
    o[0] = __float2bfloat16(sx * dn);
    o[1] = __float2bfloat16(sy * dn);
    o[2] = __float2bfloat16(sz * dn);
    o[3] = __float2bfloat16(sw * dn);
}

// ---------------------------------------------------------------- attn via MFMA + fused epilogue
// XCD-swizzled; XOR-swizzled LDS columns (s = (nl>>3)&7 at uint4 granularity)
__global__ __launch_bounds__(512, 2) void attn_mfma_kernel(const bf16* __restrict__ qs,
                                                           const bf16* __restrict__ kvB,
                                                           const float* __restrict__ vsum,
                                                           const float* __restrict__ rden,
                                                           bf16* __restrict__ nxt,
                                                           bf16* __restrict__ curT,
                                                           bf16* __restrict__ accb) {
    __shared__ __align__(16) short t1[128][136];
    int id = blockIdx.x;
    int b = id & 7;                 // XCD-local graph
    int u = id >> 3;                // 0..127
    int h = u >> 5;
    int m = u & 31;
    int bh = b * 4 + h;
    int n0 = b * NPG + m * 128;
    int tid = threadIdx.x;
    int lane = tid & 63, w = tid >> 6;
    int wr = w >> 1, wc = w & 1;
    int e0w = wc * 64;
    int l15 = lane & 15, quad = lane >> 4;

    // phase 0: stage gcn result (nxt) into swizzled LDS
    {
        const bf16* src = nxt + (size_t)n0 * HD + h * DIN;
        #pragma unroll
        for (int uu = 0; uu < 4; uu++) {
            int unit = uu * 512 + tid;
            int nl = unit >> 4, fb = unit & 15;
            int sw = (nl >> 3) & 7;
            uint4 v = *(const uint4*)(src + (size_t)nl * HD + fb * 8);
            *(uint4*)&t1[nl][(fb ^ sw) * 8] = v;
        }
    }

    f32x4 acc[2][4];
    #pragma unroll
    for (int i = 0; i < 2; i++)
        #pragma unroll
        for (int j = 0; j < 4; j++) acc[i][j] = f32x4{0.f, 0.f, 0.f, 0.f};

    const bf16* Aq = qs + (size_t)n0 * HD + h * DIN;
    const unsigned short* Bk = (const unsigned short*)kvB + (size_t)bh * 16384;
    #pragma unroll
    for (int ks = 0; ks < 4; ks++) {
        int kk = ks * 32 + quad * 8;
        short8 af[2], bfr[4];
        #pragma unroll
        for (int ti = 0; ti < 2; ti++)
            af[ti] = *(const short8*)(Aq + (size_t)(wr * 32 + ti * 16 + l15) * HD + kk);
        #pragma unroll
        for (int tj = 0; tj < 4; tj++)
            bfr[tj] = *(const short8*)(Bk + (e0w + tj * 16 + l15) * 128 + kk);
        #pragma unroll
        for (int ti = 0; ti < 2; ti++)
            #pragma unroll
            for (int tj = 0; tj < 4; tj++)
                acc[ti][tj] = __builtin_amdgcn_mfma_f32_16x16x32_bf16(af[ti], bfr[tj], acc[ti][tj], 0, 0, 0);
    }
    __syncthreads();

    // phase 1: combine (swizzled scalar access)
    #pragma unroll
    for (int tj = 0; tj < 4; tj++) {
        int el = e0w + tj * 16 + l15;
        float vs = vsum[b * HD + h * DIN + el];
        #pragma unroll
        for (int ti = 0; ti < 2; ti++) {
            int nlb = wr * 32 + ti * 16 + quad * 4;
            #pragma unroll
            for (int r = 0; r < 4; r++) {
                int nl = nlb + r;
                int sw = (nl >> 3) & 7;
                int pc = (((el >> 3) ^ sw) * 8) | (el & 7);
                float attnv = (acc[ti][tj][r] + vs) * rden[(size_t)(n0 + nl) * NH + h];
                float g = u2f((unsigned short)t1[nl][pc]);
                float val = 0.5f * g + 0.5f * attnv;
                t1[nl][pc] = (short)f2u(val);
            }
        }
    }
    __syncthreads();

    // phase 2a: nxt store + accb bf16 RMW (node-major, coalesced)
    {
        bf16* dstn = nxt + (size_t)n0 * HD + h * DIN;
        bf16* dsta = accb + (size_t)n0 * HD + h * DIN;
        #pragma unroll
        for (int uu = 0; uu < 4; uu++) {
            int unit = uu * 512 + tid;
            int nl = unit >> 4, fb = unit & 15;
            int sw = (nl >> 3) & 7;
            uint4 v = *(uint4*)&t1[nl][(fb ^ sw) * 8];
            *(uint4*)(dstn + (size_t)nl * HD + fb * 8) = v;
            unsigned short* sv = (unsigned short*)&v;
            unsigned short* ap = (unsigned short*)(dsta + (size_t)nl * HD + fb * 8);
            uint4 a = *(uint4*)ap;
            unsigned short* av = (unsigned short*)&a;
            unsigned short res[8];
            #pragma unroll
            for (int j = 0; j < 8; j++) res[j] = f2u(u2f(av[j]) + u2f(sv[j]));
            *(uint4*)ap = *(uint4*)res;
        }
    }
    // phase 2b: curT store (transpose via swizzled LDS — conflict-light)
    {
        bf16* dstT = curT + ((size_t)b * HD + h * DIN) * NPG + m * 128;
        #pragma unroll
        for (int uu = 0; uu < 4; uu++) {
            int unit = uu * 512 + tid;
            int fl = unit >> 4, np = (unit & 15) * 8;
            unsigned short arr[8];
            #pragma unroll
            for (int j = 0; j < 8; j++) {
                int row = np + j;
                int sw = (row >> 3) & 7;
                int pc = (((fl >> 3) ^ sw) * 8) | (fl & 7);
                arr[j] = (unsigned short)t1[row][pc];
            }
            *(uint4*)(dstT + (size_t)fl * NPG + np) = *(uint4*)arr;
        }
    }
}

// ---------------------------------------------------------------- output projection via MFMA (accb bf16)
__global__ __launch_bounds__(512) void out_mfma_kernel(const bf16* __restrict__ accb,
                                                       const float* __restrict__ Wo,    // [128][512] row-major
                                                       const float* __restrict__ Wo_b,
                                                       float* __restrict__ out) {
    int n0 = blockIdx.x * 128;
    int tid = threadIdx.x;
    int lane = tid & 63, w = tid >> 6;
    int wr = w >> 1, wc = w & 1;
    int l15 = lane & 15, quad = lane >> 4;

    f32x4 acc[2][4];
    #pragma unroll
    for (int i = 0; i < 2; i++)
        #pragma unroll
        for (int j = 0; j < 4; j++) acc[i][j] = f32x4{0.f, 0.f, 0.f, 0.f};

    for (int ks = 0; ks < 16; ks++) {
        int kk = ks * 32 + quad * 8;
        short8 af[2], bfr[4];
        #pragma unroll
        for (int ti = 0; ti < 2; ti++)
            af[ti] = *(const short8*)(accb + (size_t)(n0 + wr * 32 + ti * 16 + l15) * HD + kk);
        #pragma unroll
        for (int tj = 0; tj < 4; tj++)
            bfr[tj] = cvt8(Wo + (size_t)(wc * 64 + tj * 16 + l15) * HD + kk);
        #pragma unroll
        for (int ti = 0; ti < 2; ti++)
            #pragma unroll
            for (int tj = 0; tj < 4; tj++)
                acc[ti][tj] = __builtin_amdgcn_mfma_f32_16x16x32_bf16(af[ti], bfr[tj], acc[ti][tj], 0, 0, 0);
    }

    #pragma unroll
    for (int tj = 0; tj < 4; tj++) {
        int col = wc * 64 + tj * 16 + l15;
        float bv = Wo_b[col];
        #pragma unroll
        for (int ti = 0; ti < 2; ti++) {
            int rowb = wr * 32 + ti * 16 + quad * 4;
            #pragma unroll
            for (int r = 0; r < 4; r++)
                out[(size_t)(n0 + rowb + r) * DOUTF + col] = (acc[ti][tj][r] + bv) * 0.25f;
        }
    }
}

// ================================================================ launch
extern "C" void kernel_launch(void* const* d_in, const int* in_sizes, int n_in,
                              void* d_out, int out_size, void* d_ws, size_t ws_size,
                              hipStream_t stream) {
    const float* x     = (const float*)d_in[0];
    const float* Wq_w  = (const float*)d_in[1];
    const float* Wq_b  = (const float*)d_in[2];
    const float* Wk_w  = (const float*)d_in[3];
    const float* Wk_b  = (const float*)d_in[4];
    const float* Wo_w  = (const float*)d_in[5];
    const float* Wo_b  = (const float*)d_in[6];
    const int*   edge  = (const int*)d_in[7];
    const int*   n_nod = (const int*)d_in[8];
    float* out = (float*)d_out;
    const int* erow = edge;
    const int* ecol = edge + NEDGE;

    char* w = (char*)d_ws;
    auto alloc = [&](size_t bytes) -> char* {
        char* p = w;
        w += (bytes + 255) & ~(size_t)255;
        return p;
    };
    bf16*  qs      = (bf16*) alloc((size_t)NTOT * HD * 2);            // 32 MiB
    bf16*  ksT     = (bf16*) alloc((size_t)NTOT * HD * 2);            // 32 MiB
    bf16*  cur     = (bf16*) alloc((size_t)NTOT * HD * 2);            // 32 MiB
    bf16*  nxt     = (bf16*) alloc((size_t)NTOT * HD * 2);            // 32 MiB
    bf16*  curT    = (bf16*) alloc((size_t)NTOT * HD * 2);            // 32 MiB
    bf16*  accb    = (bf16*) alloc((size_t)NTOT * HD * 2);            // 32 MiB (bf16 now)
    float* partial = (float*)alloc((size_t)32 * KVSPLIT * 16384 * 4); // 16 MiB
    bf16*  kvB     = (bf16*) alloc((size_t)32 * 16384 * 2);           // 1 MiB
    int*   degfill = (int*)  alloc(2 * NTOT * 4);
    float* dis     = (float*)alloc(NTOT * 4);
    int*   row_ptr = (int*)  alloc((NTOT + 1) * 4);
    int*   col_idx = (int*)  alloc(NEDGE * 4);
    float* wcol    = (float*)alloc(NEDGE * 4);
    float* ksum    = (float*)alloc(BATCH * HD * 4);
    float* vsum    = (float*)alloc(BATCH * HD * 4);
    float* rden    = (float*)alloc((size_t)NTOT * NH * 4);
    int*   bsum    = (int*)  alloc(32 * 4);
    int*   boff    = (int*)  alloc(32 * 4);
    int* deg  = degfill;
    int* fill = degfill + NTOT;
    // total ~212 MiB

    zero_kernel<<<64, 256, 0, stream>>>((uint4*)degfill, 2 * NTOT / 4);

    proj_mfma_kernel<<<NTOT / 32, 256, 0, stream>>>(x, Wq_w, Wq_b, qs, (bf16*)nullptr);
    proj_mfma_kernel<<<NTOT / 32, 256, 0, stream>>>(x, Wk_w, Wk_b, (bf16*)nullptr, ksT);

    deg_kernel<<<NEDGE / 256, 256, 0, stream>>>(erow, deg);
    dis_kernel<<<NTOT / 256, 256, 0, stream>>>(deg, dis);
    scan1_kernel<<<32, 1024, 0, stream>>>(deg, row_ptr, bsum);
    scan2_kernel<<<1, 1, 0, stream>>>(bsum, boff, row_ptr);
    scan3_kernel<<<32, 1024, 0, stream>>>(row_ptr, boff);
    scatter_kernel<<<NEDGE / 256, 256, 0, stream>>>(erow, ecol, row_ptr, fill, dis, col_idx, wcol);

    rowsum_kernel<<<BATCH * HD / 4, 256, 0, stream>>>(ksT, ksum);
    den_kernel<<<NTOT, 256, 0, stream>>>(qs, ksum, n_nod, rden);

    init_kernel<<<NTOT / 8, 512, 0, stream>>>(x, cur, curT, accb);

    bf16* c = cur;
    bf16* nx = nxt;
    for (int it = 0; it < KORDER; it++) {
        kv_mfma_kernel<<<32 * KVSPLIT, 512, 0, stream>>>(ksT, curT, partial);
        kvredB_kernel<<<256, 256, 0, stream>>>(partial, kvB);
        rowsum_kernel<<<BATCH * HD / 4, 256, 0, stream>>>(curT, vsum);
        gcn_kernel<<<NTOT, 128, 0, stream>>>(c, row_ptr, col_idx, wcol, dis, nx);
        attn_mfma_kernel<<<32 * 32, 512, 0, stream>>>(qs, kvB, vsum, rden, nx, curT, accb);
        bf16* tmp = c; c = nx; nx = tmp;
    }

    out_mfma_kernel<<<NTOT / 128, 512, 0, stream>>>(accb, Wo_w, Wo_b, out);

    (void)in_sizes; (void)n_in; (void)out_size; (void)ws_size;
}

// Round 9
// 642.555 us; speedup vs baseline: 4.7245x; 1.1315x over previous
//
#include <hip/hip_runtime.h>
#include <hip/hip_bf16.h>
#include <stdint.h>

typedef __hip_bfloat16 bf16;

#define BATCH  8
#define NPG    4096
#define DIN    128
#define NH     4
#define NEDGE  262144
#define DOUTF  128
#define KORDER 4
#define NTOT   (BATCH*NPG)   // 32768
#define HD     (NH*DIN)      // 512

typedef __attribute__((ext_vector_type(8))) short short8;
typedef __attribute__((ext_vector_type(4))) float f32x4;

static __device__ __forceinline__ float b2f(bf16 v) { return __bfloat162float(v); }
static __device__ __forceinline__ float u2f(unsigned short u) {
    union { float f; unsigned int i; } c; c.i = ((unsigned int)u) << 16; return c.f;
}
static __device__ __forceinline__ unsigned short f2u(float f) {
    bf16 hb = __float2bfloat16(f);
    return *(unsigned short*)&hb;
}

// ---------------------------------------------------------------- zero
__global__ void zero_kernel(uint4* p, int n) {
    int i = blockIdx.x * 256 + threadIdx.x;
    if (i < n) p[i] = uint4{0u, 0u, 0u, 0u};
}

// ---------------------------------------------------------------- fp32 -> bf16 bulk convert (n multiple of 8)
__global__ void cvtbf_kernel(const float* __restrict__ in, bf16* __restrict__ out, int n) {
    int i = (blockIdx.x * 256 + threadIdx.x) * 8;
    if (i < n) {
        float4 a = *(const float4*)(in + i);
        float4 b = *(const float4*)(in + i + 4);
        unsigned short u[8] = { f2u(a.x), f2u(a.y), f2u(a.z), f2u(a.w),
                                f2u(b.x), f2u(b.y), f2u(b.z), f2u(b.w) };
        *(uint4*)(out + i) = *(uint4*)u;
    }
}

// ---------------------------------------------------------------- projection + per-head normalize via MFMA (bf16 inputs)
__global__ __launch_bounds__(256) void proj_mfma_kernel(const bf16* __restrict__ xbf,
                                                        const bf16* __restrict__ Wbf,    // [512][128] row-major
                                                        const float* __restrict__ bias,  // [512]
                                                        bf16* __restrict__ outp,         // node-major or null
                                                        bf16* __restrict__ outT) {       // dim-major or null
    __shared__ __align__(16) short t1[32][520];
    int n0 = blockIdx.x * 32;
    int tid = threadIdx.x;
    int lane = tid & 63, wc = tid >> 6;        // wc = head
    int l15 = lane & 15, quad = lane >> 4;

    f32x4 acc[2][8];
    #pragma unroll
    for (int i = 0; i < 2; i++)
        #pragma unroll
        for (int j = 0; j < 8; j++) acc[i][j] = f32x4{0.f, 0.f, 0.f, 0.f};

    #pragma unroll
    for (int ks = 0; ks < 4; ks++) {
        int kk = ks * 32 + quad * 8;
        short8 af[2];
        #pragma unroll
        for (int ti = 0; ti < 2; ti++)
            af[ti] = *(const short8*)(xbf + (size_t)(n0 + ti * 16 + l15) * DIN + kk);
        #pragma unroll
        for (int tj = 0; tj < 8; tj++) {
            short8 bfr = *(const short8*)(Wbf + (size_t)(wc * 128 + tj * 16 + l15) * DIN + kk);
            acc[0][tj] = __builtin_amdgcn_mfma_f32_16x16x32_bf16(af[0], bfr, acc[0][tj], 0, 0, 0);
            acc[1][tj] = __builtin_amdgcn_mfma_f32_16x16x32_bf16(af[1], bfr, acc[1][tj], 0, 0, 0);
        }
    }

    float bias_v[8];
    #pragma unroll
    for (int tj = 0; tj < 8; tj++) bias_v[tj] = bias[wc * 128 + tj * 16 + l15];

    #pragma unroll
    for (int ti = 0; ti < 2; ti++) {
        #pragma unroll
        for (int r = 0; r < 4; r++) {
            float s = 0.f;
            #pragma unroll
            for (int tj = 0; tj < 8; tj++) {
                float v = acc[ti][tj][r] + bias_v[tj];
                acc[ti][tj][r] = v;
                s += v * v;
            }
            s += __shfl_xor(s, 1); s += __shfl_xor(s, 2);
            s += __shfl_xor(s, 4); s += __shfl_xor(s, 8);
            float rs = rsqrtf(s);
            int node = ti * 16 + quad * 4 + r;
            #pragma unroll
            for (int tj = 0; tj < 8; tj++)
                t1[node][wc * 128 + tj * 16 + l15] = (short)f2u(acc[ti][tj][r] * rs);
        }
    }
    __syncthreads();

    if (outp) {
        #pragma unroll
        for (int u = 0; u < 8; u++) {
            int unit = u * 256 + tid;
            int nl = unit >> 6, fp = (unit & 63) * 8;
            *(uint4*)(outp + (size_t)(n0 + nl) * HD + fp) = *(uint4*)&t1[nl][fp];
        }
    }
    if (outT) {
        int b = n0 >> 12, nl0 = n0 & 4095;
        #pragma unroll
        for (int u = 0; u < 8; u++) {
            int unit = u * 256 + tid;
            int f = unit >> 2, np = (unit & 3) * 8;
            unsigned short arr[8];
            #pragma unroll
            for (int j = 0; j < 8; j++) arr[j] = (unsigned short)t1[np + j][f];
            *(uint4*)(outT + ((size_t)b * HD + f) * NPG + nl0 + np) = *(uint4*)arr;
        }
    }
}

// ---------------------------------------------------------------- degree
__global__ void deg_kernel(const int* __restrict__ row, int* __restrict__ deg) {
    int e = blockIdx.x * 256 + threadIdx.x;
    if (e < NEDGE) atomicAdd(&deg[row[e]], 1);
}

__global__ void dis_kernel(const int* __restrict__ deg, float* __restrict__ dis) {
    int i = blockIdx.x * 256 + threadIdx.x;
    if (i < NTOT) {
        int d = deg[i];
        dis[i] = d > 0 ? rsqrtf((float)d) : 0.f;
    }
}

// ---------------------------------------------------------------- multi-block exclusive scan
__global__ __launch_bounds__(1024) void scan1_kernel(const int* __restrict__ deg,
                                                     int* __restrict__ row_ptr, int* __restrict__ bsum) {
    __shared__ int buf[1024];
    int g = blockIdx.x, t = threadIdx.x;
    int v = deg[g * 1024 + t];
    buf[t] = v;
    __syncthreads();
    for (int off = 1; off < 1024; off <<= 1) {
        int add = (t >= off) ? buf[t - off] : 0;
        __syncthreads();
        buf[t] += add;
        __syncthreads();
    }
    row_ptr[g * 1024 + t] = buf[t] - v;
    if (t == 1023) bsum[g] = buf[1023];
}

__global__ void scan2_kernel(const int* __restrict__ bsum, int* __restrict__ boff, int* __restrict__ row_ptr) {
    int run = 0;
    for (int g = 0; g < 32; g++) { boff[g] = run; run += bsum[g]; }
    row_ptr[NTOT] = run;
}

__global__ __launch_bounds__(1024) void scan3_kernel(int* __restrict__ row_ptr, const int* __restrict__ boff) {
    row_ptr[blockIdx.x * 1024 + threadIdx.x] += boff[blockIdx.x];
}

// ---------------------------------------------------------------- CSR scatter
__global__ void scatter_kernel(const int* __restrict__ row, const int* __restrict__ col,
                               const int* __restrict__ row_ptr, int* __restrict__ fill,
                               const float* __restrict__ dis,
                               int* __restrict__ col_idx, float* __restrict__ wcol) {
    int e = blockIdx.x * 256 + threadIdx.x;
    if (e < NEDGE) {
        int r = row[e], c = col[e];
        int pos = row_ptr[r] + atomicAdd(&fill[r], 1);
        col_idx[pos] = c;
        wcol[pos] = dis[c];
    }
}

// ---------------------------------------------------------------- row sums over transposed layout
__global__ __launch_bounds__(256) void rowsum_kernel(const bf16* __restrict__ T, float* __restrict__ out) {
    int row = blockIdx.x * 4 + (threadIdx.x >> 6);
    int lane = threadIdx.x & 63;
    const ushort4* p = (const ushort4*)(T + (size_t)row * NPG);
    float s = 0.f;
    #pragma unroll
    for (int wv = 0; wv < 16; wv++) {
        ushort4 u = p[lane + wv * 64];
        s += u2f(u.x) + u2f(u.y) + u2f(u.z) + u2f(u.w);
    }
    for (int off = 32; off > 0; off >>= 1) s += __shfl_down(s, off);
    if (lane == 0) out[row] = s;
}

// ---------------------------------------------------------------- rden = 1/(qs . ksum + n)
__global__ __launch_bounds__(256) void den_kernel(const bf16* __restrict__ qs, const float* __restrict__ ksum,
                                                  const int* __restrict__ n_nodes, float* __restrict__ rden) {
    int n = blockIdx.x;
    int b = n >> 12;
    int w = threadIdx.x >> 6, lane = threadIdx.x & 63;
    int base = w * DIN;
    float p = b2f(qs[(size_t)n * HD + base + lane])      * ksum[b * HD + base + lane]
            + b2f(qs[(size_t)n * HD + base + 64 + lane]) * ksum[b * HD + base + 64 + lane];
    for (int off = 32; off > 0; off >>= 1) p += __shfl_down(p, off);
    if (lane == 0) rden[n * NH + w] = 1.0f / (p + (float)n_nodes[b]);
}

// ---------------------------------------------------------------- init: cur + curT + acc (all bf16, from xbf)
__global__ __launch_bounds__(512) void init_kernel(const bf16* __restrict__ xbf, bf16* __restrict__ cur,
                                                   bf16* __restrict__ curT, bf16* __restrict__ acc) {
    int node0 = blockIdx.x * 8;
    int t = threadIdx.x;
    int d = t & 127;
    int b = node0 >> 12, nl = node0 & 4095;
    unsigned short arr[8];
    #pragma unroll
    for (int r = 0; r < 8; r++) {
        bf16 hb = xbf[(size_t)(node0 + r) * DIN + d];
        cur[(size_t)(node0 + r) * HD + t] = hb;
        acc[(size_t)(node0 + r) * HD + t] = hb;
        arr[r] = *(unsigned short*)&hb;
    }
    *(uint4*)(curT + ((size_t)b * HD + t) * NPG + nl) = *(uint4*)arr;
}

// ---------------------------------------------------------------- kv via MFMA: split-K partials (XCD-swizzled)
#define KVSPLIT 8
__global__ __launch_bounds__(512, 1) void kv_mfma_kernel(const bf16* __restrict__ ksT,
                                                         const bf16* __restrict__ curT,
                                                         float* __restrict__ partial) {
    __shared__ __align__(16) short kshT[128][72];
    __shared__ __align__(16) short vshT[128][72];
    int id = blockIdx.x;
    int b = id & 7;
    int u = id >> 3;
    int h = u >> 3;
    int s = u & 7;
    int bh = b * 4 + h;
    int blk = bh * KVSPLIT + s;
    int tid = threadIdx.x;
    int lane = tid & 63;
    int w = tid >> 6;
    int wr = w >> 1, wc = w & 1;
    int d0w = wr * 32, e0w = wc * 64;
    int l15 = lane & 15, quad = lane >> 4;

    f32x4 acc[2][4];
    #pragma unroll
    for (int i = 0; i < 2; i++)
        #pragma unroll
        for (int j = 0; j < 4; j++) acc[i][j] = f32x4{0.f, 0.f, 0.f, 0.f};

    const uint4* kg = (const uint4*)(ksT + ((size_t)bh * 128) * NPG);
    const uint4* vg = (const uint4*)(curT + ((size_t)bh * 128) * NPG);
    int n0 = s * (NPG / KVSPLIT);

    for (int c = 0; c < 8; c++) {
        int nb = n0 + c * 64;
        #pragma unroll
        for (int uu = 0; uu < 2; uu++) {
            int unit = uu * 512 + tid;
            int row = unit >> 3;
            int part = unit & 7;
            int gidx = row * (NPG / 8) + (nb >> 3) + part;
            uint4 kd = kg[gidx];
            uint4 vd = vg[gidx];
            *(uint4*)&kshT[row][part * 8] = kd;
            *(uint4*)&vshT[row][part * 8] = vd;
        }
        __syncthreads();
        #pragma unroll
        for (int kkstep = 0; kkstep < 2; kkstep++) {
            int kk = kkstep * 32 + quad * 8;
            short8 af[2], bfr[4];
            #pragma unroll
            for (int ti = 0; ti < 2; ti++)
                af[ti] = *(const short8*)&kshT[d0w + ti * 16 + l15][kk];
            #pragma unroll
            for (int tj = 0; tj < 4; tj++)
                bfr[tj] = *(const short8*)&vshT[e0w + tj * 16 + l15][kk];
            #pragma unroll
            for (int ti = 0; ti < 2; ti++)
                #pragma unroll
                for (int tj = 0; tj < 4; tj++)
                    acc[ti][tj] = __builtin_amdgcn_mfma_f32_16x16x32_bf16(af[ti], bfr[tj], acc[ti][tj], 0, 0, 0);
        }
        __syncthreads();
    }
    float* p = partial + (size_t)blk * (128 * 128);
    #pragma unroll
    for (int ti = 0; ti < 2; ti++)
        #pragma unroll
        for (int tj = 0; tj < 4; tj++)
            #pragma unroll
            for (int r = 0; r < 4; r++) {
                int row = d0w + ti * 16 + quad * 4 + r;
                int col = e0w + tj * 16 + l15;
                p[row * 128 + col] = acc[ti][tj][r];
            }
}

// ---------------------------------------------------------------- reduce split-K partials -> kvB[bh][e][d] (bf16)
__global__ __launch_bounds__(256) void kvredB_kernel(const float* __restrict__ partial, bf16* __restrict__ kvB) {
    __shared__ __align__(16) short t[16][136];
    int blk = blockIdx.x;
    int bh = blk >> 3;
    int e0 = (blk & 7) * 16;
    int tid = threadIdx.x;
    int el = tid & 15;
    int dc = tid >> 4;
    const float* p = partial + (size_t)bh * (KVSPLIT * 16384);
    #pragma unroll
    for (int j = 0; j < 8; j++) {
        int d = dc * 8 + j;
        int idx = d * 128 + e0 + el;
        float s = 0.f;
        #pragma unroll
        for (int sl = 0; sl < KVSPLIT; sl++) s += p[sl * 16384 + idx];
        t[el][d] = (short)f2u(s);
    }
    __syncthreads();
    int e = tid >> 4, dp = (tid & 15) * 8;
    *(uint4*)((unsigned short*)kvB + (size_t)bh * 16384 + (e0 + e) * 128 + dp) = *(uint4*)&t[e][dp];
}

// ---------------------------------------------------------------- fused GCN-gather + attn MFMA + combine + epilogue
// grid: 1024 blocks (b=id&7 XCD-local, h, m), 512 threads
__global__ __launch_bounds__(512, 2) void gcn_attn_kernel(const bf16* __restrict__ qs,
                                                          const bf16* __restrict__ kvB,
                                                          const bf16* __restrict__ cur,     // state A node-major
                                                          const int* __restrict__ row_ptr,
                                                          const int* __restrict__ col_idx,
                                                          const float* __restrict__ wcol,
                                                          const float* __restrict__ dis,
                                                          const float* __restrict__ vsum,
                                                          const float* __restrict__ rden,
                                                          bf16* __restrict__ curN,          // state B node-major
                                                          bf16* __restrict__ curTN,         // state B dim-major
                                                          bf16* __restrict__ accb) {
    __shared__ __align__(16) short t1[128][136];
    int id = blockIdx.x;
    int b = id & 7;
    int u = id >> 3;
    int h = u >> 5;
    int m = u & 31;
    int bh = b * 4 + h;
    int n0 = b * NPG + m * 128;
    int tid = threadIdx.x;
    int lane = tid & 63, w = tid >> 6;
    int wr = w >> 1, wc = w & 1;
    int e0w = wc * 64;
    int l15 = lane & 15, quad = lane >> 4;

    // phase A: GCN gather for this block's 128 nodes, head-slice [h*128, h*128+128)
    {
        int nl = tid >> 2;         // 0..127
        int sub = tid & 3;         // 32 dims each
        int n = n0 + nl;
        int start = row_ptr[n], end = row_ptr[n + 1];
        float g[32];
        #pragma unroll
        for (int i = 0; i < 32; i++) g[i] = 0.f;
        const bf16* gbase = cur + (size_t)h * DIN + sub * 32;
        for (int j = start; j < end; j++) {
            int c = col_idx[j];
            float wv = wcol[j];
            const uint4* p = (const uint4*)(gbase + (size_t)c * HD);
            #pragma unroll
            for (int q = 0; q < 4; q++) {
                uint4 v = p[q];
                unsigned short* sv = (unsigned short*)&v;
                #pragma unroll
                for (int k = 0; k < 8; k++) g[q * 8 + k] += wv * u2f(sv[k]);
            }
        }
        float dn = dis[n];
        int sw = (nl >> 3) & 7;
        #pragma unroll
        for (int q = 0; q < 4; q++) {
            unsigned short arr[8];
            #pragma unroll
            for (int k = 0; k < 8; k++) arr[k] = f2u(g[q * 8 + k] * dn);
            int fb = (sub * 4 + q) ^ sw;
            *(uint4*)&t1[nl][fb * 8] = *(uint4*)arr;
        }
    }

    // phase B: MFMA q . kv (independent of t1)
    f32x4 acc[2][4];
    #pragma unroll
    for (int i = 0; i < 2; i++)
        #pragma unroll
        for (int j = 0; j < 4; j++) acc[i][j] = f32x4{0.f, 0.f, 0.f, 0.f};

    const bf16* Aq = qs + (size_t)n0 * HD + h * DIN;
    const unsigned short* Bk = (const unsigned short*)kvB + (size_t)bh * 16384;
    #pragma unroll
    for (int ks = 0; ks < 4; ks++) {
        int kk = ks * 32 + quad * 8;
        short8 af[2], bfr[4];
        #pragma unroll
        for (int ti = 0; ti < 2; ti++)
            af[ti] = *(const short8*)(Aq + (size_t)(wr * 32 + ti * 16 + l15) * HD + kk);
        #pragma unroll
        for (int tj = 0; tj < 4; tj++)
            bfr[tj] = *(const short8*)(Bk + (e0w + tj * 16 + l15) * 128 + kk);
        #pragma unroll
        for (int ti = 0; ti < 2; ti++)
            #pragma unroll
            for (int tj = 0; tj < 4; tj++)
                acc[ti][tj] = __builtin_amdgcn_mfma_f32_16x16x32_bf16(af[ti], bfr[tj], acc[ti][tj], 0, 0, 0);
    }
    __syncthreads();   // gather results visible to all

    // phase C: combine (swizzled scalar access)
    #pragma unroll
    for (int tj = 0; tj < 4; tj++) {
        int el = e0w + tj * 16 + l15;
        float vs = vsum[b * HD + h * DIN + el];
        #pragma unroll
        for (int ti = 0; ti < 2; ti++) {
            int nlb = wr * 32 + ti * 16 + quad * 4;
            #pragma unroll
            for (int r = 0; r < 4; r++) {
                int nl = nlb + r;
                int sw = (nl >> 3) & 7;
                int pc = (((el >> 3) ^ sw) * 8) | (el & 7);
                float attnv = (acc[ti][tj][r] + vs) * rden[(size_t)(n0 + nl) * NH + h];
                float g = u2f((unsigned short)t1[nl][pc]);
                float val = 0.5f * g + 0.5f * attnv;
                t1[nl][pc] = (short)f2u(val);
            }
        }
    }
    __syncthreads();

    // phase D: curN store + accb bf16 RMW (node-major, coalesced)
    {
        bf16* dstn = curN + (size_t)n0 * HD + h * DIN;
        bf16* dsta = accb + (size_t)n0 * HD + h * DIN;
        #pragma unroll
        for (int uu = 0; uu < 4; uu++) {
            int unit = uu * 512 + tid;
            int nl = unit >> 4, fb = unit & 15;
            int sw = (nl >> 3) & 7;
            uint4 v = *(uint4*)&t1[nl][(fb ^ sw) * 8];
            *(uint4*)(dstn + (size_t)nl * HD + fb * 8) = v;
            unsigned short* sv = (unsigned short*)&v;
            unsigned short* ap = (unsigned short*)(dsta + (size_t)nl * HD + fb * 8);
            uint4 a = *(uint4*)ap;
            unsigned short* av = (unsigned short*)&a;
            unsigned short res[8];
            #pragma unroll
            for (int j = 0; j < 8; j++) res[j] = f2u(u2f(av[j]) + u2f(sv[j]));
            *(uint4*)ap = *(uint4*)res;
        }
    }
    // phase E: curTN store (transpose via swizzled LDS)
    {
        bf16* dstT = curTN + ((size_t)b * HD + h * DIN) * NPG + m * 128;
        #pragma unroll
        for (int uu = 0; uu < 4; uu++) {
            int unit = uu * 512 + tid;
            int fl = unit >> 4, np = (unit & 15) * 8;
            unsigned short arr[8];
            #pragma unroll
            for (int j = 0; j < 8; j++) {
                int row = np + j;
                int sw = (row >> 3) & 7;
                int pc = (((fl >> 3) ^ sw) * 8) | (fl & 7);
                arr[j] = (unsigned short)t1[row][pc];
            }
            *(uint4*)(dstT + (size_t)fl * NPG + np) = *(uint4*)arr;
        }
    }
}

// ---------------------------------------------------------------- output projection via MFMA (bf16 inputs)
__global__ __launch_bounds__(512) void out_mfma_kernel(const bf16* __restrict__ accb,
                                                       const bf16* __restrict__ Wobf,   // [128][512] row-major
                                                       const float* __restrict__ Wo_b,
                                                       float* __restrict__ out) {
    int n0 = blockIdx.x * 128;
    int tid = threadIdx.x;
    int lane = tid & 63, w = tid >> 6;
    int wr = w >> 1, wc = w & 1;
    int l15 = lane & 15, quad = lane >> 4;

    f32x4 acc[2][4];
    #pragma unroll
    for (int i = 0; i < 2; i++)
        #pragma unroll
        for (int j = 0; j < 4; j++) acc[i][j] = f32x4{0.f, 0.f, 0.f, 0.f};

    for (int ks = 0; ks < 16; ks++) {
        int kk = ks * 32 + quad * 8;
        short8 af[2], bfr[4];
        #pragma unroll
        for (int ti = 0; ti < 2; ti++)
            af[ti] = *(const short8*)(accb + (size_t)(n0 + wr * 32 + ti * 16 + l15) * HD + kk);
        #pragma unroll
        for (int tj = 0; tj < 4; tj++)
            bfr[tj] = *(const short8*)(Wobf + (size_t)(wc * 64 + tj * 16 + l15) * HD + kk);
        #pragma unroll
        for (int ti = 0; ti < 2; ti++)
            #pragma unroll
            for (int tj = 0; tj < 4; tj++)
                acc[ti][tj] = __builtin_amdgcn_mfma_f32_16x16x32_bf16(af[ti], bfr[tj], acc[ti][tj], 0, 0, 0);
    }

    #pragma unroll
    for (int tj = 0; tj < 4; tj++) {
        int col = wc * 64 + tj * 16 + l15;
        float bv = Wo_b[col];
        #pragma unroll
        for (int ti = 0; ti < 2; ti++) {
            int rowb = wr * 32 + ti * 16 + quad * 4;
            #pragma unroll
            for (int r = 0; r < 4; r++)
                out[(size_t)(n0 + rowb + r) * DOUTF + col] = (acc[ti][tj][r] + bv) * 0.25f;
        }
    }
}

// ================================================================ launch
extern "C" void kernel_launch(void* const* d_in, const int* in_sizes, int n_in,
                              void* d_out, int out_size, void* d_ws, size_t ws_size,
                              hipStream_t stream) {
    const float* x     = (const float*)d_in[0];
    const float* Wq_w  = (const float*)d_in[1];
    const float* Wq_b  = (const float*)d_in[2];
    const float* Wk_w  = (const float*)d_in[3];
    const float* Wk_b  = (const float*)d_in[4];
    const float* Wo_w  = (const float*)d_in[5];
    const float* Wo_b  = (const float*)d_in[6];
    const int*   edge  = (const int*)d_in[7];
    const int*   n_nod = (const int*)d_in[8];
    float* out = (float*)d_out;
    const int* erow = edge;
    const int* ecol = edge + NEDGE;

    char* w = (char*)d_ws;
    auto alloc = [&](size_t bytes) -> char* {
        char* p = w;
        w += (bytes + 255) & ~(size_t)255;
        return p;
    };
    bf16*  qs      = (bf16*) alloc((size_t)NTOT * HD * 2);            // 32 MiB
    bf16*  ksT     = (bf16*) alloc((size_t)NTOT * HD * 2);            // 32 MiB
    bf16*  curA    = (bf16*) alloc((size_t)NTOT * HD * 2);            // 32 MiB
    bf16*  curB    = (bf16*) alloc((size_t)NTOT * HD * 2);            // 32 MiB
    bf16*  curTA   = (bf16*) alloc((size_t)NTOT * HD * 2);            // 32 MiB
    bf16*  curTB   = (bf16*) alloc((size_t)NTOT * HD * 2);            // 32 MiB
    bf16*  accb    = (bf16*) alloc((size_t)NTOT * HD * 2);            // 32 MiB
    float* partial = (float*)alloc((size_t)32 * KVSPLIT * 16384 * 4); // 16 MiB (aliased below in setup)
    bf16*  kvB     = (bf16*) alloc((size_t)32 * 16384 * 2);           // 1 MiB
    bf16*  Wobf    = (bf16*) alloc(DOUTF * HD * 2);                   // 128 KiB
    int*   degfill = (int*)  alloc(2 * NTOT * 4);
    float* dis     = (float*)alloc(NTOT * 4);
    int*   row_ptr = (int*)  alloc((NTOT + 1) * 4);
    int*   col_idx = (int*)  alloc(NEDGE * 4);
    float* wcol    = (float*)alloc(NEDGE * 4);
    float* ksum    = (float*)alloc(BATCH * HD * 4);
    float* vsum    = (float*)alloc(BATCH * HD * 4);
    float* rden    = (float*)alloc((size_t)NTOT * NH * 4);
    int*   bsum    = (int*)  alloc(32 * 4);
    int*   boff    = (int*)  alloc(32 * 4);
    int* deg  = degfill;
    int* fill = degfill + NTOT;
    // setup-only buffers aliased onto partial (dead before first kv_mfma)
    bf16* xbf  = (bf16*)partial;                                      // 8 MiB
    bf16* Wqbf = (bf16*)((char*)partial + (8 << 20));                 // 128 KiB
    bf16* Wkbf = Wqbf + (size_t)HD * DIN;                             // 128 KiB
    // total ~245 MiB

    zero_kernel<<<64, 256, 0, stream>>>((uint4*)degfill, 2 * NTOT / 4);

    cvtbf_kernel<<<NTOT * DIN / 8 / 256, 256, 0, stream>>>(x, xbf, NTOT * DIN);
    cvtbf_kernel<<<HD * DIN / 8 / 256, 256, 0, stream>>>(Wq_w, Wqbf, HD * DIN);
    cvtbf_kernel<<<HD * DIN / 8 / 256, 256, 0, stream>>>(Wk_w, Wkbf, HD * DIN);
    cvtbf_kernel<<<DOUTF * HD / 8 / 256, 256, 0, stream>>>(Wo_w, Wobf, DOUTF * HD);

    proj_mfma_kernel<<<NTOT / 32, 256, 0, stream>>>(xbf, Wqbf, Wq_b, qs, (bf16*)nullptr);
    proj_mfma_kernel<<<NTOT / 32, 256, 0, stream>>>(xbf, Wkbf, Wk_b, (bf16*)nullptr, ksT);

    deg_kernel<<<NEDGE / 256, 256, 0, stream>>>(erow, deg);
    dis_kernel<<<NTOT / 256, 256, 0, stream>>>(deg, dis);
    scan1_kernel<<<32, 1024, 0, stream>>>(deg, row_ptr, bsum);
    scan2_kernel<<<1, 1, 0, stream>>>(bsum, boff, row_ptr);
    scan3_kernel<<<32, 1024, 0, stream>>>(row_ptr, boff);
    scatter_kernel<<<NEDGE / 256, 256, 0, stream>>>(erow, ecol, row_ptr, fill, dis, col_idx, wcol);

    rowsum_kernel<<<BATCH * HD / 4, 256, 0, stream>>>(ksT, ksum);
    den_kernel<<<NTOT, 256, 0, stream>>>(qs, ksum, n_nod, rden);

    init_kernel<<<NTOT / 8, 512, 0, stream>>>(xbf, curA, curTA, accb);

    bf16* c = curA;  bf16* cT = curTA;
    bf16* cn = curB; bf16* cnT = curTB;
    for (int it = 0; it < KORDER; it++) {
        kv_mfma_kernel<<<32 * KVSPLIT, 512, 0, stream>>>(ksT, cT, partial);
        kvredB_kernel<<<256, 256, 0, stream>>>(partial, kvB);
        rowsum_kernel<<<BATCH * HD / 4, 256, 0, stream>>>(cT, vsum);
        gcn_attn_kernel<<<32 * 32, 512, 0, stream>>>(qs, kvB, c, row_ptr, col_idx, wcol, dis,
                                                     vsum, rden, cn, cnT, accb);
        bf16* t;
        t = c; c = cn; cn = t;
        t = cT; cT = cnT; cnT = t;
    }

    out_mfma_kernel<<<NTOT / 128, 512, 0, stream>>>(accb, Wobf, Wo_b, out);

    (void)in_sizes; (void)n_in; (void)out_size; (void)ws_size;
}

// Round 10
// 629.024 us; speedup vs baseline: 4.8261x; 1.0215x over previous
//
#include <hip/hip_runtime.h>
#include <hip/hip_bf16.h>
#include <stdint.h>

typedef __hip_bfloat16 bf16;

#define BATCH  8
#define NPG    4096
#define DIN    128
#define NH     4
#define NEDGE  262144
#define DOUTF  128
#define KORDER 4
#define NTOT   (BATCH*NPG)   // 32768
#define HD     (NH*DIN)      // 512

typedef __attribute__((ext_vector_type(8))) short short8;
typedef __attribute__((ext_vector_type(4))) float f32x4;

static __device__ __forceinline__ float b2f(bf16 v) { return __bfloat162float(v); }
static __device__ __forceinline__ float u2f(unsigned short u) {
    union { float f; unsigned int i; } c; c.i = ((unsigned int)u) << 16; return c.f;
}
static __device__ __forceinline__ unsigned short f2u(float f) {
    bf16 hb = __float2bfloat16(f);
    return *(unsigned short*)&hb;
}

// ---------------------------------------------------------------- zero
__global__ void zero_kernel(uint4* p, int n) {
    int i = blockIdx.x * 256 + threadIdx.x;
    if (i < n) p[i] = uint4{0u, 0u, 0u, 0u};
}

// ---------------------------------------------------------------- fp32 -> bf16 bulk convert
__global__ void cvtbf_kernel(const float* __restrict__ in, bf16* __restrict__ out, int n) {
    int i = (blockIdx.x * 256 + threadIdx.x) * 8;
    if (i < n) {
        float4 a = *(const float4*)(in + i);
        float4 b = *(const float4*)(in + i + 4);
        unsigned short u[8] = { f2u(a.x), f2u(a.y), f2u(a.z), f2u(a.w),
                                f2u(b.x), f2u(b.y), f2u(b.z), f2u(b.w) };
        *(uint4*)(out + i) = *(uint4*)u;
    }
}

// ---------------------------------------------------------------- projection + per-head normalize via MFMA
__global__ __launch_bounds__(256) void proj_mfma_kernel(const bf16* __restrict__ xbf,
                                                        const bf16* __restrict__ Wbf,
                                                        const float* __restrict__ bias,
                                                        bf16* __restrict__ outp,
                                                        bf16* __restrict__ outT) {
    __shared__ __align__(16) short t1[32][520];
    int n0 = blockIdx.x * 32;
    int tid = threadIdx.x;
    int lane = tid & 63, wc = tid >> 6;
    int l15 = lane & 15, quad = lane >> 4;

    f32x4 acc[2][8];
    #pragma unroll
    for (int i = 0; i < 2; i++)
        #pragma unroll
        for (int j = 0; j < 8; j++) acc[i][j] = f32x4{0.f, 0.f, 0.f, 0.f};

    #pragma unroll
    for (int ks = 0; ks < 4; ks++) {
        int kk = ks * 32 + quad * 8;
        short8 af[2];
        #pragma unroll
        for (int ti = 0; ti < 2; ti++)
            af[ti] = *(const short8*)(xbf + (size_t)(n0 + ti * 16 + l15) * DIN + kk);
        #pragma unroll
        for (int tj = 0; tj < 8; tj++) {
            short8 bfr = *(const short8*)(Wbf + (size_t)(wc * 128 + tj * 16 + l15) * DIN + kk);
            acc[0][tj] = __builtin_amdgcn_mfma_f32_16x16x32_bf16(af[0], bfr, acc[0][tj], 0, 0, 0);
            acc[1][tj] = __builtin_amdgcn_mfma_f32_16x16x32_bf16(af[1], bfr, acc[1][tj], 0, 0, 0);
        }
    }

    float bias_v[8];
    #pragma unroll
    for (int tj = 0; tj < 8; tj++) bias_v[tj] = bias[wc * 128 + tj * 16 + l15];

    #pragma unroll
    for (int ti = 0; ti < 2; ti++) {
        #pragma unroll
        for (int r = 0; r < 4; r++) {
            float s = 0.f;
            #pragma unroll
            for (int tj = 0; tj < 8; tj++) {
                float v = acc[ti][tj][r] + bias_v[tj];
                acc[ti][tj][r] = v;
                s += v * v;
            }
            s += __shfl_xor(s, 1); s += __shfl_xor(s, 2);
            s += __shfl_xor(s, 4); s += __shfl_xor(s, 8);
            float rs = rsqrtf(s);
            int node = ti * 16 + quad * 4 + r;
            #pragma unroll
            for (int tj = 0; tj < 8; tj++)
                t1[node][wc * 128 + tj * 16 + l15] = (short)f2u(acc[ti][tj][r] * rs);
        }
    }
    __syncthreads();

    if (outp) {
        #pragma unroll
        for (int u = 0; u < 8; u++) {
            int unit = u * 256 + tid;
            int nl = unit >> 6, fp = (unit & 63) * 8;
            *(uint4*)(outp + (size_t)(n0 + nl) * HD + fp) = *(uint4*)&t1[nl][fp];
        }
    }
    if (outT) {
        int b = n0 >> 12, nl0 = n0 & 4095;
        #pragma unroll
        for (int u = 0; u < 8; u++) {
            int unit = u * 256 + tid;
            int f = unit >> 2, np = (unit & 3) * 8;
            unsigned short arr[8];
            #pragma unroll
            for (int j = 0; j < 8; j++) arr[j] = (unsigned short)t1[np + j][f];
            *(uint4*)(outT + ((size_t)b * HD + f) * NPG + nl0 + np) = *(uint4*)arr;
        }
    }
}

// ---------------------------------------------------------------- degree
__global__ void deg_kernel(const int* __restrict__ row, int* __restrict__ deg) {
    int e = blockIdx.x * 256 + threadIdx.x;
    if (e < NEDGE) atomicAdd(&deg[row[e]], 1);
}

__global__ void dis_kernel(const int* __restrict__ deg, float* __restrict__ dis) {
    int i = blockIdx.x * 256 + threadIdx.x;
    if (i < NTOT) {
        int d = deg[i];
        dis[i] = d > 0 ? rsqrtf((float)d) : 0.f;
    }
}

// ---------------------------------------------------------------- per-tile degree sort -> perm
__global__ __launch_bounds__(128) void rank_kernel(const int* __restrict__ deg, int* __restrict__ perm) {
    __shared__ int k[128];
    int tile = blockIdx.x;
    int t = threadIdx.x;
    int key = deg[tile * 128 + t] * 128 + t;
    k[t] = key;
    __syncthreads();
    int rank = 0;
    #pragma unroll 8
    for (int u = 0; u < 128; u++) rank += (k[u] < key) ? 1 : 0;
    perm[tile * 128 + rank] = t;
}

// ---------------------------------------------------------------- multi-block exclusive scan
__global__ __launch_bounds__(1024) void scan1_kernel(const int* __restrict__ deg,
                                                     int* __restrict__ row_ptr, int* __restrict__ bsum) {
    __shared__ int buf[1024];
    int g = blockIdx.x, t = threadIdx.x;
    int v = deg[g * 1024 + t];
    buf[t] = v;
    __syncthreads();
    for (int off = 1; off < 1024; off <<= 1) {
        int add = (t >= off) ? buf[t - off] : 0;
        __syncthreads();
        buf[t] += add;
        __syncthreads();
    }
    row_ptr[g * 1024 + t] = buf[t] - v;
    if (t == 1023) bsum[g] = buf[1023];
}

__global__ void scan2_kernel(const int* __restrict__ bsum, int* __restrict__ boff, int* __restrict__ row_ptr) {
    int run = 0;
    for (int g = 0; g < 32; g++) { boff[g] = run; run += bsum[g]; }
    row_ptr[NTOT] = run;
}

__global__ __launch_bounds__(1024) void scan3_kernel(int* __restrict__ row_ptr, const int* __restrict__ boff) {
    row_ptr[blockIdx.x * 1024 + threadIdx.x] += boff[blockIdx.x];
}

// ---------------------------------------------------------------- CSR scatter
__global__ void scatter_kernel(const int* __restrict__ row, const int* __restrict__ col,
                               const int* __restrict__ row_ptr, int* __restrict__ fill,
                               const float* __restrict__ dis,
                               int* __restrict__ col_idx, float* __restrict__ wcol) {
    int e = blockIdx.x * 256 + threadIdx.x;
    if (e < NEDGE) {
        int r = row[e], c = col[e];
        int pos = row_ptr[r] + atomicAdd(&fill[r], 1);
        col_idx[pos] = c;
        wcol[pos] = dis[c];
    }
}

// ---------------------------------------------------------------- row sums over transposed layout
__global__ __launch_bounds__(256) void rowsum_kernel(const bf16* __restrict__ T, float* __restrict__ out) {
    int row = blockIdx.x * 4 + (threadIdx.x >> 6);
    int lane = threadIdx.x & 63;
    const ushort4* p = (const ushort4*)(T + (size_t)row * NPG);
    float s = 0.f;
    #pragma unroll
    for (int wv = 0; wv < 16; wv++) {
        ushort4 u = p[lane + wv * 64];
        s += u2f(u.x) + u2f(u.y) + u2f(u.z) + u2f(u.w);
    }
    for (int off = 32; off > 0; off >>= 1) s += __shfl_down(s, off);
    if (lane == 0) out[row] = s;
}

// ---------------------------------------------------------------- rden = 1/(qs . ksum + n)
__global__ __launch_bounds__(256) void den_kernel(const bf16* __restrict__ qs, const float* __restrict__ ksum,
                                                  const int* __restrict__ n_nodes, float* __restrict__ rden) {
    int n = blockIdx.x;
    int b = n >> 12;
    int w = threadIdx.x >> 6, lane = threadIdx.x & 63;
    int base = w * DIN;
    float p = b2f(qs[(size_t)n * HD + base + lane])      * ksum[b * HD + base + lane]
            + b2f(qs[(size_t)n * HD + base + 64 + lane]) * ksum[b * HD + base + 64 + lane];
    for (int off = 32; off > 0; off >>= 1) p += __shfl_down(p, off);
    if (lane == 0) rden[n * NH + w] = 1.0f / (p + (float)n_nodes[b]);
}

// ---------------------------------------------------------------- init
__global__ __launch_bounds__(512) void init_kernel(const bf16* __restrict__ xbf, bf16* __restrict__ cur,
                                                   bf16* __restrict__ curT, bf16* __restrict__ acc) {
    int node0 = blockIdx.x * 8;
    int t = threadIdx.x;
    int d = t & 127;
    int b = node0 >> 12, nl = node0 & 4095;
    unsigned short arr[8];
    #pragma unroll
    for (int r = 0; r < 8; r++) {
        bf16 hb = xbf[(size_t)(node0 + r) * DIN + d];
        cur[(size_t)(node0 + r) * HD + t] = hb;
        acc[(size_t)(node0 + r) * HD + t] = hb;
        arr[r] = *(unsigned short*)&hb;
    }
    *(uint4*)(curT + ((size_t)b * HD + t) * NPG + nl) = *(uint4*)arr;
}

// ---------------------------------------------------------------- kv via MFMA: split-K partials (XCD-swizzled)
#define KVSPLIT 8
__global__ __launch_bounds__(512, 1) void kv_mfma_kernel(const bf16* __restrict__ ksT,
                                                         const bf16* __restrict__ curT,
                                                         float* __restrict__ partial) {
    __shared__ __align__(16) short kshT[128][72];
    __shared__ __align__(16) short vshT[128][72];
    int id = blockIdx.x;
    int b = id & 7;
    int u = id >> 3;
    int h = u >> 3;
    int s = u & 7;
    int bh = b * 4 + h;
    int blk = bh * KVSPLIT + s;
    int tid = threadIdx.x;
    int lane = tid & 63;
    int w = tid >> 6;
    int wr = w >> 1, wc = w & 1;
    int d0w = wr * 32, e0w = wc * 64;
    int l15 = lane & 15, quad = lane >> 4;

    f32x4 acc[2][4];
    #pragma unroll
    for (int i = 0; i < 2; i++)
        #pragma unroll
        for (int j = 0; j < 4; j++) acc[i][j] = f32x4{0.f, 0.f, 0.f, 0.f};

    const uint4* kg = (const uint4*)(ksT + ((size_t)bh * 128) * NPG);
    const uint4* vg = (const uint4*)(curT + ((size_t)bh * 128) * NPG);
    int n0 = s * (NPG / KVSPLIT);

    for (int c = 0; c < 8; c++) {
        int nb = n0 + c * 64;
        #pragma unroll
        for (int uu = 0; uu < 2; uu++) {
            int unit = uu * 512 + tid;
            int row = unit >> 3;
            int part = unit & 7;
            int gidx = row * (NPG / 8) + (nb >> 3) + part;
            uint4 kd = kg[gidx];
            uint4 vd = vg[gidx];
            *(uint4*)&kshT[row][part * 8] = kd;
            *(uint4*)&vshT[row][part * 8] = vd;
        }
        __syncthreads();
        #pragma unroll
        for (int kkstep = 0; kkstep < 2; kkstep++) {
            int kk = kkstep * 32 + quad * 8;
            short8 af[2], bfr[4];
            #pragma unroll
            for (int ti = 0; ti < 2; ti++)
                af[ti] = *(const short8*)&kshT[d0w + ti * 16 + l15][kk];
            #pragma unroll
            for (int tj = 0; tj < 4; tj++)
                bfr[tj] = *(const short8*)&vshT[e0w + tj * 16 + l15][kk];
            #pragma unroll
            for (int ti = 0; ti < 2; ti++)
                #pragma unroll
                for (int tj = 0; tj < 4; tj++)
                    acc[ti][tj] = __builtin_amdgcn_mfma_f32_16x16x32_bf16(af[ti], bfr[tj], acc[ti][tj], 0, 0, 0);
        }
        __syncthreads();
    }
    float* p = partial + (size_t)blk * (128 * 128);
    #pragma unroll
    for (int ti = 0; ti < 2; ti++)
        #pragma unroll
        for (int tj = 0; tj < 4; tj++)
            #pragma unroll
            for (int r = 0; r < 4; r++) {
                int row = d0w + ti * 16 + quad * 4 + r;
                int col = e0w + tj * 16 + l15;
                p[row * 128 + col] = acc[ti][tj][r];
            }
}

// ---------------------------------------------------------------- reduce split-K partials -> kvB[bh][e][d] (bf16)
__global__ __launch_bounds__(256) void kvredB_kernel(const float* __restrict__ partial, bf16* __restrict__ kvB) {
    __shared__ __align__(16) short t[16][136];
    int blk = blockIdx.x;
    int bh = blk >> 3;
    int e0 = (blk & 7) * 16;
    int tid = threadIdx.x;
    int el = tid & 15;
    int dc = tid >> 4;
    const float* p = partial + (size_t)bh * (KVSPLIT * 16384);
    #pragma unroll
    for (int j = 0; j < 8; j++) {
        int d = dc * 8 + j;
        int idx = d * 128 + e0 + el;
        float s = 0.f;
        #pragma unroll
        for (int sl = 0; sl < KVSPLIT; sl++) s += p[sl * 16384 + idx];
        t[el][d] = (short)f2u(s);
    }
    __syncthreads();
    int e = tid >> 4, dp = (tid & 15) * 8;
    *(uint4*)((unsigned short*)kvB + (size_t)bh * 16384 + (e0 + e) * 128 + dp) = *(uint4*)&t[e][dp];
}

// ---------------------------------------------------------------- fused GCN-gather + attn MFMA + combine + epilogue
// degree-balanced gather (perm), fused next-iter vsum accumulation
__global__ __launch_bounds__(512, 2) void gcn_attn_kernel(const bf16* __restrict__ qs,
                                                          const bf16* __restrict__ kvB,
                                                          const bf16* __restrict__ cur,
                                                          const int* __restrict__ row_ptr,
                                                          const int* __restrict__ col_idx,
                                                          const float* __restrict__ wcol,
                                                          const float* __restrict__ dis,
                                                          const int* __restrict__ perm,
                                                          const float* __restrict__ vsum,   // current iter
                                                          const float* __restrict__ rden,
                                                          bf16* __restrict__ curN,
                                                          bf16* __restrict__ curTN,
                                                          bf16* __restrict__ accb,
                                                          float* __restrict__ vsumN) {      // next iter (atomic)
    __shared__ __align__(16) short t1[128][136];
    int id = blockIdx.x;
    int b = id & 7;
    int u = id >> 3;
    int h = u >> 5;
    int m = u & 31;
    int bh = b * 4 + h;
    int n0 = b * NPG + m * 128;
    int tid = threadIdx.x;
    int lane = tid & 63, w = tid >> 6;
    int wr = w >> 1, wc = w & 1;
    int e0w = wc * 64;
    int l15 = lane & 15, quad = lane >> 4;

    // phase A: degree-balanced GCN gather (waves get similar-degree nodes via perm)
    {
        int rank = tid >> 2;
        int sub = tid & 3;
        int nl = perm[(n0 >> 7) * 128 + rank];
        int n = n0 + nl;
        int start = row_ptr[n], end = row_ptr[n + 1];
        float g[32];
        #pragma unroll
        for (int i = 0; i < 32; i++) g[i] = 0.f;
        const bf16* gbase = cur + (size_t)h * DIN + sub * 32;
        int c0 = 0; float w0 = 0.f;
        if (start < end) { c0 = col_idx[start]; w0 = wcol[start]; }
        for (int j = start; j < end; j++) {
            int c1 = 0; float w1 = 0.f;
            if (j + 1 < end) { c1 = col_idx[j + 1]; w1 = wcol[j + 1]; }
            const uint4* p = (const uint4*)(gbase + (size_t)c0 * HD);
            #pragma unroll
            for (int q = 0; q < 4; q++) {
                uint4 v = p[q];
                unsigned short* sv = (unsigned short*)&v;
                #pragma unroll
                for (int k = 0; k < 8; k++) g[q * 8 + k] += w0 * u2f(sv[k]);
            }
            c0 = c1; w0 = w1;
        }
        float dn = dis[n];
        int sw = (nl >> 3) & 7;
        #pragma unroll
        for (int q = 0; q < 4; q++) {
            unsigned short arr[8];
            #pragma unroll
            for (int k = 0; k < 8; k++) arr[k] = f2u(g[q * 8 + k] * dn);
            int fb = (sub * 4 + q) ^ sw;
            *(uint4*)&t1[nl][fb * 8] = *(uint4*)arr;
        }
    }

    // phase B: MFMA q . kv (independent of t1)
    f32x4 acc[2][4];
    #pragma unroll
    for (int i = 0; i < 2; i++)
        #pragma unroll
        for (int j = 0; j < 4; j++) acc[i][j] = f32x4{0.f, 0.f, 0.f, 0.f};

    const bf16* Aq = qs + (size_t)n0 * HD + h * DIN;
    const unsigned short* Bk = (const unsigned short*)kvB + (size_t)bh * 16384;
    #pragma unroll
    for (int ks = 0; ks < 4; ks++) {
        int kk = ks * 32 + quad * 8;
        short8 af[2], bfr[4];
        #pragma unroll
        for (int ti = 0; ti < 2; ti++)
            af[ti] = *(const short8*)(Aq + (size_t)(wr * 32 + ti * 16 + l15) * HD + kk);
        #pragma unroll
        for (int tj = 0; tj < 4; tj++)
            bfr[tj] = *(const short8*)(Bk + (e0w + tj * 16 + l15) * 128 + kk);
        #pragma unroll
        for (int ti = 0; ti < 2; ti++)
            #pragma unroll
            for (int tj = 0; tj < 4; tj++)
                acc[ti][tj] = __builtin_amdgcn_mfma_f32_16x16x32_bf16(af[ti], bfr[tj], acc[ti][tj], 0, 0, 0);
    }
    __syncthreads();

    // phase C: combine
    #pragma unroll
    for (int tj = 0; tj < 4; tj++) {
        int el = e0w + tj * 16 + l15;
        float vs = vsum[b * HD + h * DIN + el];
        #pragma unroll
        for (int ti = 0; ti < 2; ti++) {
            int nlb = wr * 32 + ti * 16 + quad * 4;
            #pragma unroll
            for (int r = 0; r < 4; r++) {
                int nl = nlb + r;
                int sw = (nl >> 3) & 7;
                int pc = (((el >> 3) ^ sw) * 8) | (el & 7);
                float attnv = (acc[ti][tj][r] + vs) * rden[(size_t)(n0 + nl) * NH + h];
                float g = u2f((unsigned short)t1[nl][pc]);
                float val = 0.5f * g + 0.5f * attnv;
                t1[nl][pc] = (short)f2u(val);
            }
        }
    }
    __syncthreads();

    // phase C2: column-sum tile -> vsumN (next-iteration vsum)
    {
        int f = tid >> 2;
        int r0 = (tid & 3) * 32;
        float s = 0.f;
        #pragma unroll
        for (int r = 0; r < 32; r++) {
            int row = r0 + r;
            int sw = (row >> 3) & 7;
            int pc = (((f >> 3) ^ sw) * 8) | (f & 7);
            s += u2f((unsigned short)t1[row][pc]);
        }
        s += __shfl_xor(s, 1);
        s += __shfl_xor(s, 2);
        if ((tid & 3) == 0) atomicAdd(&vsumN[b * HD + h * DIN + f], s);
    }

    // phase D: curN store + accb bf16 RMW
    {
        bf16* dstn = curN + (size_t)n0 * HD + h * DIN;
        bf16* dsta = accb + (size_t)n0 * HD + h * DIN;
        #pragma unroll
        for (int uu = 0; uu < 4; uu++) {
            int unit = uu * 512 + tid;
            int nl = unit >> 4, fb = unit & 15;
            int sw = (nl >> 3) & 7;
            uint4 v = *(uint4*)&t1[nl][(fb ^ sw) * 8];
            *(uint4*)(dstn + (size_t)nl * HD + fb * 8) = v;
            unsigned short* sv = (unsigned short*)&v;
            unsigned short* ap = (unsigned short*)(dsta + (size_t)nl * HD + fb * 8);
            uint4 a = *(uint4*)ap;
            unsigned short* av = (unsigned short*)&a;
            unsigned short res[8];
            #pragma unroll
            for (int j = 0; j < 8; j++) res[j] = f2u(u2f(av[j]) + u2f(sv[j]));
            *(uint4*)ap = *(uint4*)res;
        }
    }
    // phase E: curTN store (transpose via swizzled LDS)
    {
        bf16* dstT = curTN + ((size_t)b * HD + h * DIN) * NPG + m * 128;
        #pragma unroll
        for (int uu = 0; uu < 4; uu++) {
            int unit = uu * 512 + tid;
            int fl = unit >> 4, np = (unit & 15) * 8;
            unsigned short arr[8];
            #pragma unroll
            for (int j = 0; j < 8; j++) {
                int row = np + j;
                int sw = (row >> 3) & 7;
                int pc = (((fl >> 3) ^ sw) * 8) | (fl & 7);
                arr[j] = (unsigned short)t1[row][pc];
            }
            *(uint4*)(dstT + (size_t)fl * NPG + np) = *(uint4*)arr;
        }
    }
}

// ---------------------------------------------------------------- output projection via MFMA
__global__ __launch_bounds__(512) void out_mfma_kernel(const bf16* __restrict__ accb,
                                                       const bf16* __restrict__ Wobf,
                                                       const float* __restrict__ Wo_b,
                                                       float* __restrict__ out) {
    int n0 = blockIdx.x * 128;
    int tid = threadIdx.x;
    int lane = tid & 63, w = tid >> 6;
    int wr = w >> 1, wc = w & 1;
    int l15 = lane & 15, quad = lane >> 4;

    f32x4 acc[2][4];
    #pragma unroll
    for (int i = 0; i < 2; i++)
        #pragma unroll
        for (int j = 0; j < 4; j++) acc[i][j] = f32x4{0.f, 0.f, 0.f, 0.f};

    for (int ks = 0; ks < 16; ks++) {
        int kk = ks * 32 + quad * 8;
        short8 af[2], bfr[4];
        #pragma unroll
        for (int ti = 0; ti < 2; ti++)
            af[ti] = *(const short8*)(accb + (size_t)(n0 + wr * 32 + ti * 16 + l15) * HD + kk);
        #pragma unroll
        for (int tj = 0; tj < 4; tj++)
            bfr[tj] = *(const short8*)(Wobf + (size_t)(wc * 64 + tj * 16 + l15) * HD + kk);
        #pragma unroll
        for (int ti = 0; ti < 2; ti++)
            #pragma unroll
            for (int tj = 0; tj < 4; tj++)
                acc[ti][tj] = __builtin_amdgcn_mfma_f32_16x16x32_bf16(af[ti], bfr[tj], acc[ti][tj], 0, 0, 0);
    }

    #pragma unroll
    for (int tj = 0; tj < 4; tj++) {
        int col = wc * 64 + tj * 16 + l15;
        float bv = Wo_b[col];
        #pragma unroll
        for (int ti = 0; ti < 2; ti++) {
            int rowb = wr * 32 + ti * 16 + quad * 4;
            #pragma unroll
            for (int r = 0; r < 4; r++)
                out[(size_t)(n0 + rowb + r) * DOUTF + col] = (acc[ti][tj][r] + bv) * 0.25f;
        }
    }
}

// ================================================================ launch
extern "C" void kernel_launch(void* const* d_in, const int* in_sizes, int n_in,
                              void* d_out, int out_size, void* d_ws, size_t ws_size,
                              hipStream_t stream) {
    const float* x     = (const float*)d_in[0];
    const float* Wq_w  = (const float*)d_in[1];
    const float* Wq_b  = (const float*)d_in[2];
    const float* Wk_w  = (const float*)d_in[3];
    const float* Wk_b  = (const float*)d_in[4];
    const float* Wo_w  = (const float*)d_in[5];
    const float* Wo_b  = (const float*)d_in[6];
    const int*   edge  = (const int*)d_in[7];
    const int*   n_nod = (const int*)d_in[8];
    float* out = (float*)d_out;
    const int* erow = edge;
    const int* ecol = edge + NEDGE;

    char* w = (char*)d_ws;
    auto alloc = [&](size_t bytes) -> char* {
        char* p = w;
        w += (bytes + 255) & ~(size_t)255;
        return p;
    };
    bf16*  qs      = (bf16*) alloc((size_t)NTOT * HD * 2);            // 32 MiB
    bf16*  ksT     = (bf16*) alloc((size_t)NTOT * HD * 2);            // 32 MiB
    bf16*  curA    = (bf16*) alloc((size_t)NTOT * HD * 2);            // 32 MiB
    bf16*  curB    = (bf16*) alloc((size_t)NTOT * HD * 2);            // 32 MiB
    bf16*  curTA   = (bf16*) alloc((size_t)NTOT * HD * 2);            // 32 MiB
    bf16*  curTB   = (bf16*) alloc((size_t)NTOT * HD * 2);            // 32 MiB
    bf16*  accb    = (bf16*) alloc((size_t)NTOT * HD * 2);            // 32 MiB
    float* partial = (float*)alloc((size_t)32 * KVSPLIT * 16384 * 4); // 16 MiB (aliased in setup)
    bf16*  kvB     = (bf16*) alloc((size_t)32 * 16384 * 2);           // 1 MiB
    bf16*  Wobf    = (bf16*) alloc(DOUTF * HD * 2);                   // 128 KiB
    int*   degfill = (int*)  alloc(2 * NTOT * 4);
    int*   perm    = (int*)  alloc(NTOT * 4);
    float* dis     = (float*)alloc(NTOT * 4);
    int*   row_ptr = (int*)  alloc((NTOT + 1) * 4);
    int*   col_idx = (int*)  alloc(NEDGE * 4);
    float* wcol    = (float*)alloc(NEDGE * 4);
    float* ksum    = (float*)alloc(BATCH * HD * 4);
    float* vsumA   = (float*)alloc(BATCH * HD * 4);
    float* vsumB   = (float*)alloc(BATCH * HD * 4);
    float* rden    = (float*)alloc((size_t)NTOT * NH * 4);
    int*   bsum    = (int*)  alloc(32 * 4);
    int*   boff    = (int*)  alloc(32 * 4);
    int* deg  = degfill;
    int* fill = degfill + NTOT;
    // setup-only buffers aliased onto partial (dead before first kv_mfma)
    bf16* xbf  = (bf16*)partial;
    bf16* Wqbf = (bf16*)((char*)partial + (8 << 20));
    bf16* Wkbf = Wqbf + (size_t)HD * DIN;
    // total ~245.5 MiB

    zero_kernel<<<64, 256, 0, stream>>>((uint4*)degfill, 2 * NTOT / 4);

    cvtbf_kernel<<<NTOT * DIN / 8 / 256, 256, 0, stream>>>(x, xbf, NTOT * DIN);
    cvtbf_kernel<<<HD * DIN / 8 / 256, 256, 0, stream>>>(Wq_w, Wqbf, HD * DIN);
    cvtbf_kernel<<<HD * DIN / 8 / 256, 256, 0, stream>>>(Wk_w, Wkbf, HD * DIN);
    cvtbf_kernel<<<DOUTF * HD / 8 / 256, 256, 0, stream>>>(Wo_w, Wobf, DOUTF * HD);

    proj_mfma_kernel<<<NTOT / 32, 256, 0, stream>>>(xbf, Wqbf, Wq_b, qs, (bf16*)nullptr);
    proj_mfma_kernel<<<NTOT / 32, 256, 0, stream>>>(xbf, Wkbf, Wk_b, (bf16*)nullptr, ksT);

    deg_kernel<<<NEDGE / 256, 256, 0, stream>>>(erow, deg);
    dis_kernel<<<NTOT / 256, 256, 0, stream>>>(deg, dis);
    rank_kernel<<<NTOT / 128, 128, 0, stream>>>(deg, perm);
    scan1_kernel<<<32, 1024, 0, stream>>>(deg, row_ptr, bsum);
    scan2_kernel<<<1, 1, 0, stream>>>(bsum, boff, row_ptr);
    scan3_kernel<<<32, 1024, 0, stream>>>(row_ptr, boff);
    scatter_kernel<<<NEDGE / 256, 256, 0, stream>>>(erow, ecol, row_ptr, fill, dis, col_idx, wcol);

    rowsum_kernel<<<BATCH * HD / 4, 256, 0, stream>>>(ksT, ksum);
    den_kernel<<<NTOT, 256, 0, stream>>>(qs, ksum, n_nod, rden);

    init_kernel<<<NTOT / 8, 512, 0, stream>>>(xbf, curA, curTA, accb);
    rowsum_kernel<<<BATCH * HD / 4, 256, 0, stream>>>(curTA, vsumA);

    bf16* c = curA;  bf16* cT = curTA;
    bf16* cn = curB; bf16* cnT = curTB;
    float* vs = vsumA;
    float* vsN = vsumB;
    for (int it = 0; it < KORDER; it++) {
        kv_mfma_kernel<<<32 * KVSPLIT, 512, 0, stream>>>(ksT, cT, partial);
        kvredB_kernel<<<256, 256, 0, stream>>>(partial, kvB);
        zero_kernel<<<4, 256, 0, stream>>>((uint4*)vsN, BATCH * HD / 4);
        gcn_attn_kernel<<<32 * 32, 512, 0, stream>>>(qs, kvB, c, row_ptr, col_idx, wcol, dis,
                                                     perm, vs, rden, cn, cnT, accb, vsN);
        bf16* t;
        t = c; c = cn; cn = t;
        t = cT; cT = cnT; cnT = t;
        float* tf = vs; vs = vsN; vsN = tf;
    }

    out_mfma_kernel<<<NTOT / 128, 512, 0, stream>>>(accb, Wobf, Wo_b, out);

    (void)in_sizes; (void)n_in; (void)out_size; (void)ws_size;
}

// Round 11
// 621.750 us; speedup vs baseline: 4.8826x; 1.0117x over previous
//
#include <hip/hip_runtime.h>
#include <hip/hip_bf16.h>
#include <stdint.h>

typedef __hip_bfloat16 bf16;

#define BATCH  8
#define NPG    4096
#define DIN    128
#define NH     4
#define NEDGE  262144
#define DOUTF  128
#define KORDER 4
#define NTOT   (BATCH*NPG)   // 32768
#define HD     (NH*DIN)      // 512

typedef __attribute__((ext_vector_type(8))) short short8;
typedef __attribute__((ext_vector_type(4))) float f32x4;

static __device__ __forceinline__ float b2f(bf16 v) { return __bfloat162float(v); }
static __device__ __forceinline__ float u2f(unsigned short u) {
    union { float f; unsigned int i; } c; c.i = ((unsigned int)u) << 16; return c.f;
}
static __device__ __forceinline__ unsigned short f2u(float f) {
    bf16 hb = __float2bfloat16(f);
    return *(unsigned short*)&hb;
}

// ---------------------------------------------------------------- zero
__global__ void zero_kernel(uint4* p, int n) {
    int i = blockIdx.x * 256 + threadIdx.x;
    if (i < n) p[i] = uint4{0u, 0u, 0u, 0u};
}

// ---------------------------------------------------------------- fp32 -> bf16 bulk convert
__global__ void cvtbf_kernel(const float* __restrict__ in, bf16* __restrict__ out, int n) {
    int i = (blockIdx.x * 256 + threadIdx.x) * 8;
    if (i < n) {
        float4 a = *(const float4*)(in + i);
        float4 b = *(const float4*)(in + i + 4);
        unsigned short u[8] = { f2u(a.x), f2u(a.y), f2u(a.z), f2u(a.w),
                                f2u(b.x), f2u(b.y), f2u(b.z), f2u(b.w) };
        *(uint4*)(out + i) = *(uint4*)u;
    }
}

// ---------------------------------------------------------------- projection + per-head normalize via MFMA
__global__ __launch_bounds__(256) void proj_mfma_kernel(const bf16* __restrict__ xbf,
                                                        const bf16* __restrict__ Wbf,
                                                        const float* __restrict__ bias,
                                                        bf16* __restrict__ outp,
                                                        bf16* __restrict__ outT) {
    __shared__ __align__(16) short t1[32][520];
    int n0 = blockIdx.x * 32;
    int tid = threadIdx.x;
    int lane = tid & 63, wc = tid >> 6;
    int l15 = lane & 15, quad = lane >> 4;

    f32x4 acc[2][8];
    #pragma unroll
    for (int i = 0; i < 2; i++)
        #pragma unroll
        for (int j = 0; j < 8; j++) acc[i][j] = f32x4{0.f, 0.f, 0.f, 0.f};

    #pragma unroll
    for (int ks = 0; ks < 4; ks++) {
        int kk = ks * 32 + quad * 8;
        short8 af[2];
        #pragma unroll
        for (int ti = 0; ti < 2; ti++)
            af[ti] = *(const short8*)(xbf + (size_t)(n0 + ti * 16 + l15) * DIN + kk);
        #pragma unroll
        for (int tj = 0; tj < 8; tj++) {
            short8 bfr = *(const short8*)(Wbf + (size_t)(wc * 128 + tj * 16 + l15) * DIN + kk);
            acc[0][tj] = __builtin_amdgcn_mfma_f32_16x16x32_bf16(af[0], bfr, acc[0][tj], 0, 0, 0);
            acc[1][tj] = __builtin_amdgcn_mfma_f32_16x16x32_bf16(af[1], bfr, acc[1][tj], 0, 0, 0);
        }
    }

    float bias_v[8];
    #pragma unroll
    for (int tj = 0; tj < 8; tj++) bias_v[tj] = bias[wc * 128 + tj * 16 + l15];

    #pragma unroll
    for (int ti = 0; ti < 2; ti++) {
        #pragma unroll
        for (int r = 0; r < 4; r++) {
            float s = 0.f;
            #pragma unroll
            for (int tj = 0; tj < 8; tj++) {
                float v = acc[ti][tj][r] + bias_v[tj];
                acc[ti][tj][r] = v;
                s += v * v;
            }
            s += __shfl_xor(s, 1); s += __shfl_xor(s, 2);
            s += __shfl_xor(s, 4); s += __shfl_xor(s, 8);
            float rs = rsqrtf(s);
            int node = ti * 16 + quad * 4 + r;
            #pragma unroll
            for (int tj = 0; tj < 8; tj++)
                t1[node][wc * 128 + tj * 16 + l15] = (short)f2u(acc[ti][tj][r] * rs);
        }
    }
    __syncthreads();

    if (outp) {
        #pragma unroll
        for (int u = 0; u < 8; u++) {
            int unit = u * 256 + tid;
            int nl = unit >> 6, fp = (unit & 63) * 8;
            *(uint4*)(outp + (size_t)(n0 + nl) * HD + fp) = *(uint4*)&t1[nl][fp];
        }
    }
    if (outT) {
        int b = n0 >> 12, nl0 = n0 & 4095;
        #pragma unroll
        for (int u = 0; u < 8; u++) {
            int unit = u * 256 + tid;
            int f = unit >> 2, np = (unit & 3) * 8;
            unsigned short arr[8];
            #pragma unroll
            for (int j = 0; j < 8; j++) arr[j] = (unsigned short)t1[np + j][f];
            *(uint4*)(outT + ((size_t)b * HD + f) * NPG + nl0 + np) = *(uint4*)arr;
        }
    }
}

// ---------------------------------------------------------------- degree
__global__ void deg_kernel(const int* __restrict__ row, int* __restrict__ deg) {
    int e = blockIdx.x * 256 + threadIdx.x;
    if (e < NEDGE) atomicAdd(&deg[row[e]], 1);
}

__global__ void dis_kernel(const int* __restrict__ deg, float* __restrict__ dis) {
    int i = blockIdx.x * 256 + threadIdx.x;
    if (i < NTOT) {
        int d = deg[i];
        dis[i] = d > 0 ? rsqrtf((float)d) : 0.f;
    }
}

// ---------------------------------------------------------------- multi-block exclusive scan
__global__ __launch_bounds__(1024) void scan1_kernel(const int* __restrict__ deg,
                                                     int* __restrict__ row_ptr, int* __restrict__ bsum) {
    __shared__ int buf[1024];
    int g = blockIdx.x, t = threadIdx.x;
    int v = deg[g * 1024 + t];
    buf[t] = v;
    __syncthreads();
    for (int off = 1; off < 1024; off <<= 1) {
        int add = (t >= off) ? buf[t - off] : 0;
        __syncthreads();
        buf[t] += add;
        __syncthreads();
    }
    row_ptr[g * 1024 + t] = buf[t] - v;
    if (t == 1023) bsum[g] = buf[1023];
}

__global__ void scan2_kernel(const int* __restrict__ bsum, int* __restrict__ boff, int* __restrict__ row_ptr) {
    int run = 0;
    for (int g = 0; g < 32; g++) { boff[g] = run; run += bsum[g]; }
    row_ptr[NTOT] = run;
}

__global__ __launch_bounds__(1024) void scan3_kernel(int* __restrict__ row_ptr, const int* __restrict__ boff) {
    row_ptr[blockIdx.x * 1024 + threadIdx.x] += boff[blockIdx.x];
}

// ---------------------------------------------------------------- CSR scatter
__global__ void scatter_kernel(const int* __restrict__ row, const int* __restrict__ col,
                               const int* __restrict__ row_ptr, int* __restrict__ fill,
                               const float* __restrict__ dis,
                               int* __restrict__ col_idx, float* __restrict__ wcol) {
    int e = blockIdx.x * 256 + threadIdx.x;
    if (e < NEDGE) {
        int r = row[e], c = col[e];
        int pos = row_ptr[r] + atomicAdd(&fill[r], 1);
        col_idx[pos] = c;
        wcol[pos] = dis[c];
    }
}

// ---------------------------------------------------------------- row sums over transposed layout
__global__ __launch_bounds__(256) void rowsum_kernel(const bf16* __restrict__ T, float* __restrict__ out) {
    int row = blockIdx.x * 4 + (threadIdx.x >> 6);
    int lane = threadIdx.x & 63;
    const ushort4* p = (const ushort4*)(T + (size_t)row * NPG);
    float s = 0.f;
    #pragma unroll
    for (int wv = 0; wv < 16; wv++) {
        ushort4 u = p[lane + wv * 64];
        s += u2f(u.x) + u2f(u.y) + u2f(u.z) + u2f(u.w);
    }
    for (int off = 32; off > 0; off >>= 1) s += __shfl_down(s, off);
    if (lane == 0) out[row] = s;
}

// ---------------------------------------------------------------- rden = 1/(qs . ksum + n)
__global__ __launch_bounds__(256) void den_kernel(const bf16* __restrict__ qs, const float* __restrict__ ksum,
                                                  const int* __restrict__ n_nodes, float* __restrict__ rden) {
    int n = blockIdx.x;
    int b = n >> 12;
    int w = threadIdx.x >> 6, lane = threadIdx.x & 63;
    int base = w * DIN;
    float p = b2f(qs[(size_t)n * HD + base + lane])      * ksum[b * HD + base + lane]
            + b2f(qs[(size_t)n * HD + base + 64 + lane]) * ksum[b * HD + base + 64 + lane];
    for (int off = 32; off > 0; off >>= 1) p += __shfl_down(p, off);
    if (lane == 0) rden[n * NH + w] = 1.0f / (p + (float)n_nodes[b]);
}

// ---------------------------------------------------------------- init
__global__ __launch_bounds__(512) void init_kernel(const bf16* __restrict__ xbf, bf16* __restrict__ cur,
                                                   bf16* __restrict__ curT, bf16* __restrict__ acc) {
    int node0 = blockIdx.x * 8;
    int t = threadIdx.x;
    int d = t & 127;
    int b = node0 >> 12, nl = node0 & 4095;
    unsigned short arr[8];
    #pragma unroll
    for (int r = 0; r < 8; r++) {
        bf16 hb = xbf[(size_t)(node0 + r) * DIN + d];
        cur[(size_t)(node0 + r) * HD + t] = hb;
        acc[(size_t)(node0 + r) * HD + t] = hb;
        arr[r] = *(unsigned short*)&hb;
    }
    *(uint4*)(curT + ((size_t)b * HD + t) * NPG + nl) = *(uint4*)arr;
}

// ---------------------------------------------------------------- kv via MFMA: split-K partials (XCD-swizzled)
#define KVSPLIT 8
__global__ __launch_bounds__(512, 1) void kv_mfma_kernel(const bf16* __restrict__ ksT,
                                                         const bf16* __restrict__ curT,
                                                         float* __restrict__ partial) {
    __shared__ __align__(16) short kshT[128][72];
    __shared__ __align__(16) short vshT[128][72];
    int id = blockIdx.x;
    int b = id & 7;
    int u = id >> 3;
    int h = u >> 3;
    int s = u & 7;
    int bh = b * 4 + h;
    int blk = bh * KVSPLIT + s;
    int tid = threadIdx.x;
    int lane = tid & 63;
    int w = tid >> 6;
    int wr = w >> 1, wc = w & 1;
    int d0w = wr * 32, e0w = wc * 64;
    int l15 = lane & 15, quad = lane >> 4;

    f32x4 acc[2][4];
    #pragma unroll
    for (int i = 0; i < 2; i++)
        #pragma unroll
        for (int j = 0; j < 4; j++) acc[i][j] = f32x4{0.f, 0.f, 0.f, 0.f};

    const uint4* kg = (const uint4*)(ksT + ((size_t)bh * 128) * NPG);
    const uint4* vg = (const uint4*)(curT + ((size_t)bh * 128) * NPG);
    int n0 = s * (NPG / KVSPLIT);

    for (int c = 0; c < 8; c++) {
        int nb = n0 + c * 64;
        #pragma unroll
        for (int uu = 0; uu < 2; uu++) {
            int unit = uu * 512 + tid;
            int row = unit >> 3;
            int part = unit & 7;
            int gidx = row * (NPG / 8) + (nb >> 3) + part;
            uint4 kd = kg[gidx];
            uint4 vd = vg[gidx];
            *(uint4*)&kshT[row][part * 8] = kd;
            *(uint4*)&vshT[row][part * 8] = vd;
        }
        __syncthreads();
        #pragma unroll
        for (int kkstep = 0; kkstep < 2; kkstep++) {
            int kk = kkstep * 32 + quad * 8;
            short8 af[2], bfr[4];
            #pragma unroll
            for (int ti = 0; ti < 2; ti++)
                af[ti] = *(const short8*)&kshT[d0w + ti * 16 + l15][kk];
            #pragma unroll
            for (int tj = 0; tj < 4; tj++)
                bfr[tj] = *(const short8*)&vshT[e0w + tj * 16 + l15][kk];
            #pragma unroll
            for (int ti = 0; ti < 2; ti++)
                #pragma unroll
                for (int tj = 0; tj < 4; tj++)
                    acc[ti][tj] = __builtin_amdgcn_mfma_f32_16x16x32_bf16(af[ti], bfr[tj], acc[ti][tj], 0, 0, 0);
        }
        __syncthreads();
    }
    float* p = partial + (size_t)blk * (128 * 128);
    #pragma unroll
    for (int ti = 0; ti < 2; ti++)
        #pragma unroll
        for (int tj = 0; tj < 4; tj++)
            #pragma unroll
            for (int r = 0; r < 4; r++) {
                int row = d0w + ti * 16 + quad * 4 + r;
                int col = e0w + tj * 16 + l15;
                p[row * 128 + col] = acc[ti][tj][r];
            }
}

// ---------------------------------------------------------------- reduce split-K partials -> kvB[bh][e][d] (bf16)
__global__ __launch_bounds__(256) void kvredB_kernel(const float* __restrict__ partial, bf16* __restrict__ kvB) {
    __shared__ __align__(16) short t[16][136];
    int blk = blockIdx.x;
    int bh = blk >> 3;
    int e0 = (blk & 7) * 16;
    int tid = threadIdx.x;
    int el = tid & 15;
    int dc = tid >> 4;
    const float* p = partial + (size_t)bh * (KVSPLIT * 16384);
    #pragma unroll
    for (int j = 0; j < 8; j++) {
        int d = dc * 8 + j;
        int idx = d * 128 + e0 + el;
        float s = 0.f;
        #pragma unroll
        for (int sl = 0; sl < KVSPLIT; sl++) s += p[sl * 16384 + idx];
        t[el][d] = (short)f2u(s);
    }
    __syncthreads();
    int e = tid >> 4, dp = (tid & 15) * 8;
    *(uint4*)((unsigned short*)kvB + (size_t)bh * 16384 + (e0 + e) * 128 + dp) = *(uint4*)&t[e][dp];
}

// ---------------------------------------------------------------- fused GCN-gather + attn MFMA + combine + epilogue
// pipelined gather (double-buffered edge data), register-fused next-iter vsum
__global__ __launch_bounds__(512, 2) void gcn_attn_kernel(const bf16* __restrict__ qs,
                                                          const bf16* __restrict__ kvB,
                                                          const bf16* __restrict__ cur,
                                                          const int* __restrict__ row_ptr,
                                                          const int* __restrict__ col_idx,
                                                          const float* __restrict__ wcol,
                                                          const float* __restrict__ dis,
                                                          const float* __restrict__ vsum,   // current iter
                                                          const float* __restrict__ rden,
                                                          bf16* __restrict__ curN,
                                                          bf16* __restrict__ curTN,
                                                          bf16* __restrict__ accb,
                                                          float* __restrict__ vsumN) {      // next iter (atomic)
    __shared__ __align__(16) short t1[128][136];
    int id = blockIdx.x;
    int b = id & 7;
    int u = id >> 3;
    int h = u >> 5;
    int m = u & 31;
    int bh = b * 4 + h;
    int n0 = b * NPG + m * 128;
    int tid = threadIdx.x;
    int lane = tid & 63, w = tid >> 6;
    int wr = w >> 1, wc = w & 1;
    int e0w = wc * 64;
    int l15 = lane & 15, quad = lane >> 4;

    // phase A: GCN gather, software-pipelined (load edge j+1 data before FMAs of edge j)
    {
        int nl = tid >> 2;
        int sub = tid & 3;
        int n = n0 + nl;
        int start = row_ptr[n], end = row_ptr[n + 1];
        float g[32];
        #pragma unroll
        for (int i = 0; i < 32; i++) g[i] = 0.f;
        const bf16* gbase = cur + (size_t)h * DIN + sub * 32;
        int c0 = 0; float w0 = 0.f;
        if (start < end) { c0 = col_idx[start]; w0 = wcol[start]; }
        uint4 vb[4];
        {
            const uint4* p = (const uint4*)(gbase + (size_t)c0 * HD);
            vb[0] = p[0]; vb[1] = p[1]; vb[2] = p[2]; vb[3] = p[3];
        }
        for (int j = start; j < end; j++) {
            int c1 = c0; float w1 = 0.f;
            if (j + 1 < end) { c1 = col_idx[j + 1]; w1 = wcol[j + 1]; }
            const uint4* p = (const uint4*)(gbase + (size_t)c1 * HD);
            uint4 vn0 = p[0], vn1 = p[1], vn2 = p[2], vn3 = p[3];
            #pragma unroll
            for (int q = 0; q < 4; q++) {
                unsigned short* sv = (unsigned short*)&vb[q];
                #pragma unroll
                for (int k = 0; k < 8; k++) g[q * 8 + k] += w0 * u2f(sv[k]);
            }
            vb[0] = vn0; vb[1] = vn1; vb[2] = vn2; vb[3] = vn3;
            w0 = w1;
        }
        float dn = dis[n];
        int sw = (nl >> 3) & 7;
        #pragma unroll
        for (int q = 0; q < 4; q++) {
            unsigned short arr[8];
            #pragma unroll
            for (int k = 0; k < 8; k++) arr[k] = f2u(g[q * 8 + k] * dn);
            int fb = (sub * 4 + q) ^ sw;
            *(uint4*)&t1[nl][fb * 8] = *(uint4*)arr;
        }
    }

    // phase B: MFMA q . kv (independent of t1)
    f32x4 acc[2][4];
    #pragma unroll
    for (int i = 0; i < 2; i++)
        #pragma unroll
        for (int j = 0; j < 4; j++) acc[i][j] = f32x4{0.f, 0.f, 0.f, 0.f};

    const bf16* Aq = qs + (size_t)n0 * HD + h * DIN;
    const unsigned short* Bk = (const unsigned short*)kvB + (size_t)bh * 16384;
    #pragma unroll
    for (int ks = 0; ks < 4; ks++) {
        int kk = ks * 32 + quad * 8;
        short8 af[2], bfr[4];
        #pragma unroll
        for (int ti = 0; ti < 2; ti++)
            af[ti] = *(const short8*)(Aq + (size_t)(wr * 32 + ti * 16 + l15) * HD + kk);
        #pragma unroll
        for (int tj = 0; tj < 4; tj++)
            bfr[tj] = *(const short8*)(Bk + (e0w + tj * 16 + l15) * 128 + kk);
        #pragma unroll
        for (int ti = 0; ti < 2; ti++)
            #pragma unroll
            for (int tj = 0; tj < 4; tj++)
                acc[ti][tj] = __builtin_amdgcn_mfma_f32_16x16x32_bf16(af[ti], bfr[tj], acc[ti][tj], 0, 0, 0);
    }
    __syncthreads();

    // phase C: combine + register-level column sums for next-iter vsum
    #pragma unroll
    for (int tj = 0; tj < 4; tj++) {
        int el = e0w + tj * 16 + l15;
        float vs = vsum[b * HD + h * DIN + el];
        float cs = 0.f;
        #pragma unroll
        for (int ti = 0; ti < 2; ti++) {
            int nlb = wr * 32 + ti * 16 + quad * 4;
            #pragma unroll
            for (int r = 0; r < 4; r++) {
                int nl = nlb + r;
                int sw = (nl >> 3) & 7;
                int pc = (((el >> 3) ^ sw) * 8) | (el & 7);
                float attnv = (acc[ti][tj][r] + vs) * rden[(size_t)(n0 + nl) * NH + h];
                float g = u2f((unsigned short)t1[nl][pc]);
                float val = 0.5f * g + 0.5f * attnv;
                t1[nl][pc] = (short)f2u(val);
                cs += val;
            }
        }
        cs += __shfl_xor(cs, 16);
        cs += __shfl_xor(cs, 32);
        if (quad == 0) atomicAdd(&vsumN[b * HD + h * DIN + el], cs);
    }
    __syncthreads();

    // phase D: curN store + accb bf16 RMW
    {
        bf16* dstn = curN + (size_t)n0 * HD + h * DIN;
        bf16* dsta = accb + (size_t)n0 * HD + h * DIN;
        #pragma unroll
        for (int uu = 0; uu < 4; uu++) {
            int unit = uu * 512 + tid;
            int nl = unit >> 4, fb = unit & 15;
            int sw = (nl >> 3) & 7;
            uint4 v = *(uint4*)&t1[nl][(fb ^ sw) * 8];
            *(uint4*)(dstn + (size_t)nl * HD + fb * 8) = v;
            unsigned short* sv = (unsigned short*)&v;
            unsigned short* ap = (unsigned short*)(dsta + (size_t)nl * HD + fb * 8);
            uint4 a = *(uint4*)ap;
            unsigned short* av = (unsigned short*)&a;
            unsigned short res[8];
            #pragma unroll
            for (int j = 0; j < 8; j++) res[j] = f2u(u2f(av[j]) + u2f(sv[j]));
            *(uint4*)ap = *(uint4*)res;
        }
    }
    // phase E: curTN store (transpose via swizzled LDS)
    {
        bf16* dstT = curTN + ((size_t)b * HD + h * DIN) * NPG + m * 128;
        #pragma unroll
        for (int uu = 0; uu < 4; uu++) {
            int unit = uu * 512 + tid;
            int fl = unit >> 4, np = (unit & 15) * 8;
            unsigned short arr[8];
            #pragma unroll
            for (int j = 0; j < 8; j++) {
                int row = np + j;
                int sw = (row >> 3) & 7;
                int pc = (((fl >> 3) ^ sw) * 8) | (fl & 7);
                arr[j] = (unsigned short)t1[row][pc];
            }
            *(uint4*)(dstT + (size_t)fl * NPG + np) = *(uint4*)arr;
        }
    }
}

// ---------------------------------------------------------------- output projection via MFMA
__global__ __launch_bounds__(512) void out_mfma_kernel(const bf16* __restrict__ accb,
                                                       const bf16* __restrict__ Wobf,
                                                       const float* __restrict__ Wo_b,
                                                       float* __restrict__ out) {
    int n0 = blockIdx.x * 128;
    int tid = threadIdx.x;
    int lane = tid & 63, w = tid >> 6;
    int wr = w >> 1, wc = w & 1;
    int l15 = lane & 15, quad = lane >> 4;

    f32x4 acc[2][4];
    #pragma unroll
    for (int i = 0; i < 2; i++)
        #pragma unroll
        for (int j = 0; j < 4; j++) acc[i][j] = f32x4{0.f, 0.f, 0.f, 0.f};

    for (int ks = 0; ks < 16; ks++) {
        int kk = ks * 32 + quad * 8;
        short8 af[2], bfr[4];
        #pragma unroll
        for (int ti = 0; ti < 2; ti++)
            af[ti] = *(const short8*)(accb + (size_t)(n0 + wr * 32 + ti * 16 + l15) * HD + kk);
        #pragma unroll
        for (int tj = 0; tj < 4; tj++)
            bfr[tj] = *(const short8*)(Wobf + (size_t)(wc * 64 + tj * 16 + l15) * HD + kk);
        #pragma unroll
        for (int ti = 0; ti < 2; ti++)
            #pragma unroll
            for (int tj = 0; tj < 4; tj++)
                acc[ti][tj] = __builtin_amdgcn_mfma_f32_16x16x32_bf16(af[ti], bfr[tj], acc[ti][tj], 0, 0, 0);
    }

    #pragma unroll
    for (int tj = 0; tj < 4; tj++) {
        int col = wc * 64 + tj * 16 + l15;
        float bv = Wo_b[col];
        #pragma unroll
        for (int ti = 0; ti < 2; ti++) {
            int rowb = wr * 32 + ti * 16 + quad * 4;
            #pragma unroll
            for (int r = 0; r < 4; r++)
                out[(size_t)(n0 + rowb + r) * DOUTF + col] = (acc[ti][tj][r] + bv) * 0.25f;
        }
    }
}

// ================================================================ launch
extern "C" void kernel_launch(void* const* d_in, const int* in_sizes, int n_in,
                              void* d_out, int out_size, void* d_ws, size_t ws_size,
                              hipStream_t stream) {
    const float* x     = (const float*)d_in[0];
    const float* Wq_w  = (const float*)d_in[1];
    const float* Wq_b  = (const float*)d_in[2];
    const float* Wk_w  = (const float*)d_in[3];
    const float* Wk_b  = (const float*)d_in[4];
    const float* Wo_w  = (const float*)d_in[5];
    const float* Wo_b  = (const float*)d_in[6];
    const int*   edge  = (const int*)d_in[7];
    const int*   n_nod = (const int*)d_in[8];
    float* out = (float*)d_out;
    const int* erow = edge;
    const int* ecol = edge + NEDGE;

    char* w = (char*)d_ws;
    auto alloc = [&](size_t bytes) -> char* {
        char* p = w;
        w += (bytes + 255) & ~(size_t)255;
        return p;
    };
    bf16*  qs      = (bf16*) alloc((size_t)NTOT * HD * 2);            // 32 MiB
    bf16*  ksT     = (bf16*) alloc((size_t)NTOT * HD * 2);            // 32 MiB
    bf16*  curA    = (bf16*) alloc((size_t)NTOT * HD * 2);            // 32 MiB
    bf16*  curB    = (bf16*) alloc((size_t)NTOT * HD * 2);            // 32 MiB
    bf16*  curTA   = (bf16*) alloc((size_t)NTOT * HD * 2);            // 32 MiB
    bf16*  curTB   = (bf16*) alloc((size_t)NTOT * HD * 2);            // 32 MiB
    bf16*  accb    = (bf16*) alloc((size_t)NTOT * HD * 2);            // 32 MiB
    float* partial = (float*)alloc((size_t)32 * KVSPLIT * 16384 * 4); // 16 MiB (aliased in setup)
    bf16*  kvB     = (bf16*) alloc((size_t)32 * 16384 * 2);           // 1 MiB
    bf16*  Wobf    = (bf16*) alloc(DOUTF * HD * 2);                   // 128 KiB
    int*   degfill = (int*)  alloc(2 * NTOT * 4);
    float* dis     = (float*)alloc(NTOT * 4);
    int*   row_ptr = (int*)  alloc((NTOT + 1) * 4);
    int*   col_idx = (int*)  alloc(NEDGE * 4);
    float* wcol    = (float*)alloc(NEDGE * 4);
    float* ksum    = (float*)alloc(BATCH * HD * 4);
    float* vsumA   = (float*)alloc(BATCH * HD * 4);
    float* vsumB   = (float*)alloc(BATCH * HD * 4);
    float* rden    = (float*)alloc((size_t)NTOT * NH * 4);
    int*   bsum    = (int*)  alloc(32 * 4);
    int*   boff    = (int*)  alloc(32 * 4);
    int* deg  = degfill;
    int* fill = degfill + NTOT;
    // setup-only buffers aliased onto partial (dead before first kv_mfma)
    bf16* xbf  = (bf16*)partial;
    bf16* Wqbf = (bf16*)((char*)partial + (8 << 20));
    bf16* Wkbf = Wqbf + (size_t)HD * DIN;
    // total ~245 MiB

    zero_kernel<<<64, 256, 0, stream>>>((uint4*)degfill, 2 * NTOT / 4);

    cvtbf_kernel<<<NTOT * DIN / 8 / 256, 256, 0, stream>>>(x, xbf, NTOT * DIN);
    cvtbf_kernel<<<HD * DIN / 8 / 256, 256, 0, stream>>>(Wq_w, Wqbf, HD * DIN);
    cvtbf_kernel<<<HD * DIN / 8 / 256, 256, 0, stream>>>(Wk_w, Wkbf, HD * DIN);
    cvtbf_kernel<<<DOUTF * HD / 8 / 256, 256, 0, stream>>>(Wo_w, Wobf, DOUTF * HD);

    proj_mfma_kernel<<<NTOT / 32, 256, 0, stream>>>(xbf, Wqbf, Wq_b, qs, (bf16*)nullptr);
    proj_mfma_kernel<<<NTOT / 32, 256, 0, stream>>>(xbf, Wkbf, Wk_b, (bf16*)nullptr, ksT);

    deg_kernel<<<NEDGE / 256, 256, 0, stream>>>(erow, deg);
    dis_kernel<<<NTOT / 256, 256, 0, stream>>>(deg, dis);
    scan1_kernel<<<32, 1024, 0, stream>>>(deg, row_ptr, bsum);
    scan2_kernel<<<1, 1, 0, stream>>>(bsum, boff, row_ptr);
    scan3_kernel<<<32, 1024, 0, stream>>>(row_ptr, boff);
    scatter_kernel<<<NEDGE / 256, 256, 0, stream>>>(erow, ecol, row_ptr, fill, dis, col_idx, wcol);

    rowsum_kernel<<<BATCH * HD / 4, 256, 0, stream>>>(ksT, ksum);
    den_kernel<<<NTOT, 256, 0, stream>>>(qs, ksum, n_nod, rden);

    init_kernel<<<NTOT / 8, 512, 0, stream>>>(xbf, curA, curTA, accb);
    rowsum_kernel<<<BATCH * HD / 4, 256, 0, stream>>>(curTA, vsumA);

    bf16* c = curA;  bf16* cT = curTA;
    bf16* cn = curB; bf16* cnT = curTB;
    float* vs = vsumA;
    float* vsN = vsumB;
    for (int it = 0; it < KORDER; it++) {
        kv_mfma_kernel<<<32 * KVSPLIT, 512, 0, stream>>>(ksT, cT, partial);
        kvredB_kernel<<<256, 256, 0, stream>>>(partial, kvB);
        zero_kernel<<<4, 256, 0, stream>>>((uint4*)vsN, BATCH * HD / 4);
        gcn_attn_kernel<<<32 * 32, 512, 0, stream>>>(qs, kvB, c, row_ptr, col_idx, wcol, dis,
                                                     vs, rden, cn, cnT, accb, vsN);
        bf16* t;
        t = c; c = cn; cn = t;
        t = cT; cT = cnT; cnT = t;
        float* tf = vs; vs = vsN; vsN = tf;
    }

    out_mfma_kernel<<<NTOT / 128, 512, 0, stream>>>(accb, Wobf, Wo_b, out);

    (void)in_sizes; (void)n_in; (void)out_size; (void)ws_size;
}